// Round 2
// baseline (6764.053 us; speedup 1.0000x reference)
//
#include <hip/hip_runtime.h>
#include <hip/hip_bf16.h>
#include <math.h>

// ---- atomic max on float via int/uint ordering trick ----
__device__ __forceinline__ void atomicMaxF(float* a, float v) {
    if (v >= 0.f) atomicMax((int*)a, __float_as_int(v));
    else          atomicMin((unsigned int*)a, __float_as_uint(v));
}

// ---- detect whether edge_index is int64 (odd int32 words all zero) ----
__global__ void detect64_k(const int* __restrict__ ei, int n_check, int* __restrict__ flag) {
    if (blockIdx.x == 0 && threadIdx.x == 0) {
        int zeros = 0;
        for (int i = 0; i < n_check; ++i) zeros += (ei[2 * i + 1] == 0) ? 1 : 0;
        *flag = (zeros >= n_check - 2) ? 1 : 0;
    }
}

__device__ __forceinline__ void edge_sd(const int* __restrict__ ei, int e, int E,
                                        int is64, int N, int& s_, int& d_) {
    if (e >= E) { s_ = d_ = e - E; return; }   // self-loops appended
    int s, d;
    if (is64) { s = ei[2 * e]; d = ei[2 * (E + e)]; }
    else      { s = ei[e];     d = ei[E + e]; }
    // clamp for safety (avoids OOB crash if dtype guess is ever wrong)
    s_ = ((unsigned)s < (unsigned)N) ? s : 0;
    d_ = ((unsigned)d < (unsigned)N) ? d : 0;
}

// ---- simple 64x64 tiled GEMM, fp32 accumulate: C[N,M] = A[N,K] * B[K,M] ----
__global__ __launch_bounds__(256) void gemm_k(const float* __restrict__ A,
                                              const float* __restrict__ B,
                                              float* __restrict__ C,
                                              int N, int K, int M) {
    __shared__ float As[16][65];  // [k][row]
    __shared__ float Bs[16][65];  // [k][col]
    const int tx = threadIdx.x;
    const int br = blockIdx.y * 64, bc = blockIdx.x * 64;
    const int tr = (tx >> 4) << 2, tc = (tx & 15) << 2;
    float acc[4][4] = {};
    for (int k0 = 0; k0 < K; k0 += 16) {
        #pragma unroll
        for (int i = tx; i < 1024; i += 256) {
            int r = i >> 4, kk = i & 15;
            int gr = br + r;
            As[kk][r] = (gr < N) ? A[(size_t)gr * K + k0 + kk] : 0.f;
        }
        #pragma unroll
        for (int i = tx; i < 1024; i += 256) {
            int kk = i >> 6, c = i & 63;
            int gc = bc + c;
            Bs[kk][c] = (gc < M) ? B[(size_t)(k0 + kk) * M + gc] : 0.f;
        }
        __syncthreads();
        #pragma unroll
        for (int kk = 0; kk < 16; ++kk) {
            float a[4], b[4];
            #pragma unroll
            for (int i = 0; i < 4; ++i) a[i] = As[kk][tr + i];
            #pragma unroll
            for (int j = 0; j < 4; ++j) b[j] = Bs[kk][tc + j];
            #pragma unroll
            for (int i = 0; i < 4; ++i)
                #pragma unroll
                for (int j = 0; j < 4; ++j) acc[i][j] += a[i] * b[j];
        }
        __syncthreads();
    }
    #pragma unroll
    for (int i = 0; i < 4; ++i) {
        int gr = br + tr + i;
        if (gr >= N) continue;
        #pragma unroll
        for (int j = 0; j < 4; ++j) {
            int gc = bc + tc + j;
            if (gc < M) C[(size_t)gr * M + gc] = acc[i][j];
        }
    }
}

// ---- per-node attention logits: al_src/al_dst [N,H] ----
__global__ void al_k(const float* __restrict__ x, const float* __restrict__ a_s,
                     const float* __restrict__ a_d, float* __restrict__ alS,
                     float* __restrict__ alD, int N, int H, int C) {
    int idx = blockIdx.x * 256 + threadIdx.x;
    if (idx >= N * H) return;
    int n = idx / H, h = idx - n * H;
    const float* xp = x + (size_t)n * H * C + (size_t)h * C;
    float s1 = 0.f, s2 = 0.f;
    for (int c = 0; c < C; ++c) {
        float v = xp[c];
        s1 += v * a_s[h * C + c];
        s2 += v * a_d[h * C + c];
    }
    alS[idx] = s1;
    alD[idx] = s2;
}

__global__ void fill_k(float* __restrict__ p, float v, int n) {
    int i = blockIdx.x * 256 + threadIdx.x;
    if (i < n) p[i] = v;
}

// ---- pass 1: segment max over dst ----
__global__ void edge_max_k(const int* __restrict__ ei, const int* __restrict__ flag,
                           const float* __restrict__ alS, const float* __restrict__ alD,
                           float* __restrict__ m, int E, int Etot, int H, int N) {
    int e = blockIdx.x * 256 + threadIdx.x;
    if (e >= Etot) return;
    int s_, d_;
    edge_sd(ei, e, E, *flag, N, s_, d_);
    for (int h = 0; h < H; ++h) {
        float ev = alS[s_ * H + h] + alD[d_ * H + h];
        ev = ev > 0.f ? ev : 0.2f * ev;
        atomicMaxF(&m[d_ * H + h], ev);
    }
}

// ---- pass 2: segment sum of exp(e - m) ----
__global__ void edge_sum_k(const int* __restrict__ ei, const int* __restrict__ flag,
                           const float* __restrict__ alS, const float* __restrict__ alD,
                           const float* __restrict__ m, float* __restrict__ ssum,
                           int E, int Etot, int H, int N) {
    int e = blockIdx.x * 256 + threadIdx.x;
    if (e >= Etot) return;
    int s_, d_;
    edge_sd(ei, e, E, *flag, N, s_, d_);
    for (int h = 0; h < H; ++h) {
        float ev = alS[s_ * H + h] + alD[d_ * H + h];
        ev = ev > 0.f ? ev : 0.2f * ev;
        atomicAdd(&ssum[d_ * H + h], expf(ev - m[d_ * H + h]));
    }
}

// ---- pass 3: weighted aggregation, one wave (64 lanes) per edge ----
__global__ __launch_bounds__(256) void edge_aggr_k(const int* __restrict__ ei,
                                                   const int* __restrict__ flag,
                                                   const float* __restrict__ alS,
                                                   const float* __restrict__ alD,
                                                   const float* __restrict__ m,
                                                   const float* __restrict__ ssum,
                                                   const float* __restrict__ x,
                                                   float* __restrict__ acc,
                                                   int E, int Etot, int H, int C, int N) {
    int wid = (blockIdx.x * 256 + threadIdx.x) >> 6;
    int lane = threadIdx.x & 63;
    if (wid >= Etot) return;
    int s_, d_;
    edge_sd(ei, wid, E, *flag, N, s_, d_);
    const int HC = H * C;
    float alpha_l = 0.f;
    if (lane < H) {
        float ev = alS[s_ * H + lane] + alD[d_ * H + lane];
        ev = ev > 0.f ? ev : 0.2f * ev;
        alpha_l = expf(ev - m[d_ * H + lane]) / ssum[d_ * H + lane];
    }
    for (int c = lane; c < HC; c += 64) {
        int h = c / C;
        float alpha = __shfl(alpha_l, h, 64);
        atomicAdd(&acc[(size_t)d_ * HC + c], x[(size_t)s_ * HC + c] * alpha);
    }
}

// ---- epilogue: out = elu(acc + b) (fp32 out) ----
__global__ void epi_elu_k(const float* __restrict__ acc, const float* __restrict__ b,
                          float* __restrict__ out, int N, int HC) {
    int i = blockIdx.x * 256 + threadIdx.x;
    if (i >= N * HC) return;
    int c = i % HC;
    float v = acc[i] + b[c];
    out[i] = v > 0.f ? v : expm1f(v);
}

// ---- final: fp32 out = acc + b ----
__global__ void final_k(const float* __restrict__ acc, const float* __restrict__ b,
                        float* __restrict__ out, int N, int M) {
    int i = blockIdx.x * 256 + threadIdx.x;
    if (i >= N * M) return;
    int c = i % M;
    out[i] = acc[i] + b[c];
}

extern "C" void kernel_launch(void* const* d_in, const int* in_sizes, int n_in,
                              void* d_out, int out_size, void* d_ws, size_t ws_size,
                              hipStream_t stream) {
    const float* feat = (const float*)d_in[0];
    const int*   ei   = (const int*)d_in[1];
    const float* W0   = (const float*)d_in[2];
    const float* a0s  = (const float*)d_in[3];
    const float* a0d  = (const float*)d_in[4];
    const float* b0   = (const float*)d_in[5];
    const float* W1   = (const float*)d_in[6];
    const float* a1s  = (const float*)d_in[7];
    const float* a1d  = (const float*)d_in[8];
    const float* b1   = (const float*)d_in[9];
    const float* W2   = (const float*)d_in[10];
    const float* a2s  = (const float*)d_in[11];
    const float* a2d  = (const float*)d_in[12];
    const float* b2   = (const float*)d_in[13];
    float* out = (float*)d_out;

    const int N = in_sizes[0] / 128;   // 100000
    const int E = in_sizes[1] / 2;     // 1600000
    const int Etot = E + N;

    // workspace layout (fp32)
    float* xbuf = (float*)d_ws;                 // N*256
    float* abuf = xbuf + (size_t)N * 256;       // N*256
    float* alS  = abuf + (size_t)N * 256;       // N*8
    float* alD  = alS + (size_t)N * 8;          // N*8
    float* mbuf = alD + (size_t)N * 8;          // N*8
    float* sbuf = mbuf + (size_t)N * 8;         // N*8
    float* cbuf = sbuf + (size_t)N * 8;         // N*40
    int*   flag = (int*)(cbuf + (size_t)N * 40);

    detect64_k<<<1, 1, 0, stream>>>(ei, 512, flag);

    const int nb_nh8 = (N * 8 + 255) / 256;
    const int nb_e   = (Etot + 255) / 256;
    const int nb_ew  = (Etot + 3) / 4;          // wave-per-edge, 4 waves/block
    dim3 g256((256 + 63) / 64, (N + 63) / 64);
    dim3 g40(1, (N + 63) / 64);

    // ---------- Layer 0: Fin=128, H=8, C=32 ----------
    gemm_k<<<g256, 256, 0, stream>>>(feat, W0, xbuf, N, 128, 256);
    al_k<<<nb_nh8, 256, 0, stream>>>(xbuf, a0s, a0d, alS, alD, N, 8, 32);
    fill_k<<<nb_nh8, 256, 0, stream>>>(mbuf, -INFINITY, N * 8);
    hipMemsetAsync(sbuf, 0, (size_t)N * 8 * 4, stream);
    hipMemsetAsync(abuf, 0, (size_t)N * 256 * 4, stream);
    edge_max_k<<<nb_e, 256, 0, stream>>>(ei, flag, alS, alD, mbuf, E, Etot, 8, N);
    edge_sum_k<<<nb_e, 256, 0, stream>>>(ei, flag, alS, alD, mbuf, sbuf, E, Etot, 8, N);
    edge_aggr_k<<<nb_ew, 256, 0, stream>>>(ei, flag, alS, alD, mbuf, sbuf, xbuf, abuf,
                                           E, Etot, 8, 32, N);
    epi_elu_k<<<(N * 256 + 255) / 256, 256, 0, stream>>>(abuf, b0, xbuf, N, 256); // h1 -> xbuf

    // ---------- Layer 1: Fin=256, H=8, C=32 ----------
    gemm_k<<<g256, 256, 0, stream>>>(xbuf, W1, abuf, N, 256, 256); // x1 -> abuf
    al_k<<<nb_nh8, 256, 0, stream>>>(abuf, a1s, a1d, alS, alD, N, 8, 32);
    fill_k<<<nb_nh8, 256, 0, stream>>>(mbuf, -INFINITY, N * 8);
    hipMemsetAsync(sbuf, 0, (size_t)N * 8 * 4, stream);
    hipMemsetAsync(xbuf, 0, (size_t)N * 256 * 4, stream);   // xbuf is now the accum target
    edge_max_k<<<nb_e, 256, 0, stream>>>(ei, flag, alS, alD, mbuf, E, Etot, 8, N);
    edge_sum_k<<<nb_e, 256, 0, stream>>>(ei, flag, alS, alD, mbuf, sbuf, E, Etot, 8, N);
    edge_aggr_k<<<nb_ew, 256, 0, stream>>>(ei, flag, alS, alD, mbuf, sbuf, abuf, xbuf,
                                           E, Etot, 8, 32, N);
    epi_elu_k<<<(N * 256 + 255) / 256, 256, 0, stream>>>(xbuf, b1, xbuf, N, 256); // h2 in-place

    // ---------- Layer 2: Fin=256, H=1, C=40 ----------
    gemm_k<<<g40, 256, 0, stream>>>(xbuf, W2, abuf, N, 256, 40); // x2 -> abuf
    al_k<<<(N + 255) / 256, 256, 0, stream>>>(abuf, a2s, a2d, alS, alD, N, 1, 40);
    fill_k<<<(N + 255) / 256, 256, 0, stream>>>(mbuf, -INFINITY, N);
    hipMemsetAsync(sbuf, 0, (size_t)N * 4, stream);
    hipMemsetAsync(cbuf, 0, (size_t)N * 40 * 4, stream);
    edge_max_k<<<nb_e, 256, 0, stream>>>(ei, flag, alS, alD, mbuf, E, Etot, 1, N);
    edge_sum_k<<<nb_e, 256, 0, stream>>>(ei, flag, alS, alD, mbuf, sbuf, E, Etot, 1, N);
    edge_aggr_k<<<nb_ew, 256, 0, stream>>>(ei, flag, alS, alD, mbuf, sbuf, abuf, cbuf,
                                           E, Etot, 1, 40, N);
    final_k<<<(N * 40 + 255) / 256, 256, 0, stream>>>(cbuf, b2, out, N, 40);
}

// Round 3
// 1909.538 us; speedup vs baseline: 3.5422x; 3.5422x over previous
//
#include <hip/hip_runtime.h>
#include <hip/hip_bf16.h>
#include <math.h>

// ---- detect whether edge_index is int64 (odd int32 words all zero) ----
__global__ void detect64_k(const int* __restrict__ ei, int n_check, int* __restrict__ flag) {
    if (blockIdx.x == 0 && threadIdx.x == 0) {
        int zeros = 0;
        for (int i = 0; i < n_check; ++i) zeros += (ei[2 * i + 1] == 0) ? 1 : 0;
        *flag = (zeros >= n_check - 2) ? 1 : 0;
    }
}

__device__ __forceinline__ void edge_sd(const int* __restrict__ ei, int e, int E,
                                        int is64, int N, int& s_, int& d_) {
    if (e >= E) { s_ = d_ = e - E; return; }   // self-loops appended
    int s, d;
    if (is64) { s = ei[2 * e]; d = ei[2 * (E + e)]; }
    else      { s = ei[e];     d = ei[E + e]; }
    s_ = ((unsigned)s < (unsigned)N) ? s : 0;
    d_ = ((unsigned)d < (unsigned)N) ? d : 0;
}

// ================= CSR construction =================
__global__ void deg_k(const int* __restrict__ ei, const int* __restrict__ flag,
                      int* __restrict__ deg, int E, int Etot, int N) {
    int e = blockIdx.x * 256 + threadIdx.x;
    if (e >= Etot) return;
    int s_, d_;
    edge_sd(ei, e, E, *flag, N, s_, d_);
    atomicAdd(&deg[d_], 1);
}

__global__ void scan1_k(const int* __restrict__ deg, int* __restrict__ rowptr,
                        int* __restrict__ partials, int N) {
    __shared__ int tmp[256];
    int tx = threadIdx.x, i = blockIdx.x * 256 + tx;
    int v = (i < N) ? deg[i] : 0;
    tmp[tx] = v;
    __syncthreads();
    for (int off = 1; off < 256; off <<= 1) {
        int t = (tx >= off) ? tmp[tx - off] : 0;
        __syncthreads();
        tmp[tx] += t;
        __syncthreads();
    }
    if (i < N) rowptr[i] = tmp[tx] - v;              // exclusive within block
    if (tx == 255) partials[blockIdx.x] = tmp[255];  // block total
}

__global__ void scan2_k(int* __restrict__ partials, int nb) {
    __shared__ int tmp[512];
    int tx = threadIdx.x;
    int v = (tx < nb) ? partials[tx] : 0;
    tmp[tx] = v;
    __syncthreads();
    for (int off = 1; off < 512; off <<= 1) {
        int t = (tx >= off) ? tmp[tx - off] : 0;
        __syncthreads();
        tmp[tx] += t;
        __syncthreads();
    }
    if (tx < nb) partials[tx] = tmp[tx];  // inclusive
}

__global__ void scan3_k(int* __restrict__ rowptr, int* __restrict__ cursor,
                        const int* __restrict__ partials, int N, int Etot) {
    int i = blockIdx.x * 256 + threadIdx.x;
    if (i < N) {
        int off = (blockIdx.x > 0) ? partials[blockIdx.x - 1] : 0;
        int v = rowptr[i] + off;
        rowptr[i] = v;
        cursor[i] = v;
    }
    if (i == 0) rowptr[N] = Etot;
}

__global__ void scatter_k(const int* __restrict__ ei, const int* __restrict__ flag,
                          int* __restrict__ cursor, int* __restrict__ csr_src,
                          int E, int Etot, int N) {
    int e = blockIdx.x * 256 + threadIdx.x;
    if (e >= Etot) return;
    int s_, d_;
    edge_sd(ei, e, E, *flag, N, s_, d_);
    int pos = atomicAdd(&cursor[d_], 1);
    csr_src[pos] = s_;
}

// ---- simple 64x64 tiled GEMM, fp32 accumulate: C[N,M] = A[N,K] * B[K,M] ----
__global__ __launch_bounds__(256) void gemm_k(const float* __restrict__ A,
                                              const float* __restrict__ B,
                                              float* __restrict__ C,
                                              int N, int K, int M) {
    __shared__ float As[16][65];
    __shared__ float Bs[16][65];
    const int tx = threadIdx.x;
    const int br = blockIdx.y * 64, bc = blockIdx.x * 64;
    const int tr = (tx >> 4) << 2, tc = (tx & 15) << 2;
    float acc[4][4] = {};
    for (int k0 = 0; k0 < K; k0 += 16) {
        #pragma unroll
        for (int i = tx; i < 1024; i += 256) {
            int r = i >> 4, kk = i & 15;
            int gr = br + r;
            As[kk][r] = (gr < N) ? A[(size_t)gr * K + k0 + kk] : 0.f;
        }
        #pragma unroll
        for (int i = tx; i < 1024; i += 256) {
            int kk = i >> 6, c = i & 63;
            int gc = bc + c;
            Bs[kk][c] = (gc < M) ? B[(size_t)(k0 + kk) * M + gc] : 0.f;
        }
        __syncthreads();
        #pragma unroll
        for (int kk = 0; kk < 16; ++kk) {
            float a[4], b[4];
            #pragma unroll
            for (int i = 0; i < 4; ++i) a[i] = As[kk][tr + i];
            #pragma unroll
            for (int j = 0; j < 4; ++j) b[j] = Bs[kk][tc + j];
            #pragma unroll
            for (int i = 0; i < 4; ++i)
                #pragma unroll
                for (int j = 0; j < 4; ++j) acc[i][j] += a[i] * b[j];
        }
        __syncthreads();
    }
    #pragma unroll
    for (int i = 0; i < 4; ++i) {
        int gr = br + tr + i;
        if (gr >= N) continue;
        #pragma unroll
        for (int j = 0; j < 4; ++j) {
            int gc = bc + tc + j;
            if (gc < M) C[(size_t)gr * M + gc] = acc[i][j];
        }
    }
}

// ---- per-node attention logits: al_src/al_dst [N,H] ----
__global__ void al_k(const float* __restrict__ x, const float* __restrict__ a_s,
                     const float* __restrict__ a_d, float* __restrict__ alS,
                     float* __restrict__ alD, int N, int H, int C) {
    int idx = blockIdx.x * 256 + threadIdx.x;
    if (idx >= N * H) return;
    int n = idx / H, h = idx - n * H;
    const float* xp = x + (size_t)n * H * C + (size_t)h * C;
    float s1 = 0.f, s2 = 0.f;
    for (int c = 0; c < C; ++c) {
        float v = xp[c];
        s1 += v * a_s[h * C + c];
        s2 += v * a_d[h * C + c];
    }
    alS[idx] = s1;
    alD[idx] = s2;
}

// ================= fused per-node softmax + aggregation =================
// H=8, C=32 (HC=256). One wave (64 lanes) per destination node.
__global__ __launch_bounds__(256) void node_aggr8_k(
    const int* __restrict__ rowptr, const int* __restrict__ csr_src,
    const float* __restrict__ alS, const float* __restrict__ alD,
    const float* __restrict__ x, const float* __restrict__ bias,
    float* __restrict__ out, int N, int do_elu) {
    int wid = (blockIdx.x * 256 + threadIdx.x) >> 6;
    int lane = threadIdx.x & 63;
    if (wid >= N) return;
    const int d = wid;
    const int beg = rowptr[d], end = rowptr[d + 1];

    // sweep 1: online softmax stats per head. lane = esub*8 + h
    const int h = lane & 7, esub = lane >> 3;
    const float aDh = alD[d * 8 + h];
    float m = -INFINITY, s = 0.f;
    for (int e = beg + esub; e < end; e += 8) {
        int src = csr_src[e];
        float ev = alS[src * 8 + h] + aDh;
        ev = ev > 0.f ? ev : 0.2f * ev;
        float mn = fmaxf(m, ev);
        s = s * expf(m - mn) + expf(ev - mn);
        m = mn;
    }
    // merge across esub (lane bits 3..5)
    #pragma unroll
    for (int off = 8; off < 64; off <<= 1) {
        float m2 = __shfl_xor(m, off);
        float s2 = __shfl_xor(s, off);
        float mn = fmaxf(m, m2);
        if (mn != -INFINITY) {
            s = s * expf(m - mn) + s2 * expf(m2 - mn);
            m = mn;
        }
    }

    // sweep 2: each lane owns channels c = lane*4 .. lane*4+3 ; head hh = lane>>3
    const int hh = lane >> 3;
    const float mh = __shfl(m, hh);
    const float rs = 1.f / __shfl(s, hh);
    const float aDhh = alD[d * 8 + hh];
    float4 acc = {0.f, 0.f, 0.f, 0.f};
    for (int e = beg; e < end; ++e) {
        int src = csr_src[e];
        float ev = alS[src * 8 + hh] + aDhh;
        ev = ev > 0.f ? ev : 0.2f * ev;
        float alpha = expf(ev - mh) * rs;
        const float4 xv = *(const float4*)&x[(size_t)src * 256 + lane * 4];
        acc.x += xv.x * alpha;
        acc.y += xv.y * alpha;
        acc.z += xv.z * alpha;
        acc.w += xv.w * alpha;
    }
    const float4 bv = *(const float4*)&bias[lane * 4];
    float4 o;
    o.x = acc.x + bv.x; o.y = acc.y + bv.y; o.z = acc.z + bv.z; o.w = acc.w + bv.w;
    if (do_elu) {
        o.x = o.x > 0.f ? o.x : expm1f(o.x);
        o.y = o.y > 0.f ? o.y : expm1f(o.y);
        o.z = o.z > 0.f ? o.z : expm1f(o.z);
        o.w = o.w > 0.f ? o.w : expm1f(o.w);
    }
    *(float4*)&out[(size_t)d * 256 + lane * 4] = o;
}

// H=1, C=40. One wave per destination node.
__global__ __launch_bounds__(256) void node_aggr1_k(
    const int* __restrict__ rowptr, const int* __restrict__ csr_src,
    const float* __restrict__ alS, const float* __restrict__ alD,
    const float* __restrict__ x, const float* __restrict__ bias,
    float* __restrict__ out, int N) {
    int wid = (blockIdx.x * 256 + threadIdx.x) >> 6;
    int lane = threadIdx.x & 63;
    if (wid >= N) return;
    const int d = wid;
    const int beg = rowptr[d], end = rowptr[d + 1];
    const float aD = alD[d];

    float m = -INFINITY, s = 0.f;
    for (int e = beg + lane; e < end; e += 64) {
        int src = csr_src[e];
        float ev = alS[src] + aD;
        ev = ev > 0.f ? ev : 0.2f * ev;
        float mn = fmaxf(m, ev);
        s = s * expf(m - mn) + expf(ev - mn);
        m = mn;
    }
    #pragma unroll
    for (int off = 1; off < 64; off <<= 1) {
        float m2 = __shfl_xor(m, off);
        float s2 = __shfl_xor(s, off);
        float mn = fmaxf(m, m2);
        if (mn != -INFINITY) {
            s = s * expf(m - mn) + s2 * expf(m2 - mn);
            m = mn;
        }
    }
    const float rs = 1.f / s;
    float acc = 0.f;
    for (int e = beg; e < end; ++e) {
        int src = csr_src[e];
        float ev = alS[src] + aD;
        ev = ev > 0.f ? ev : 0.2f * ev;
        float alpha = expf(ev - m) * rs;
        if (lane < 40) acc += x[(size_t)src * 40 + lane] * alpha;
    }
    if (lane < 40) out[(size_t)d * 40 + lane] = acc + bias[lane];
}

extern "C" void kernel_launch(void* const* d_in, const int* in_sizes, int n_in,
                              void* d_out, int out_size, void* d_ws, size_t ws_size,
                              hipStream_t stream) {
    const float* feat = (const float*)d_in[0];
    const int*   ei   = (const int*)d_in[1];
    const float* W0   = (const float*)d_in[2];
    const float* a0s  = (const float*)d_in[3];
    const float* a0d  = (const float*)d_in[4];
    const float* b0   = (const float*)d_in[5];
    const float* W1   = (const float*)d_in[6];
    const float* a1s  = (const float*)d_in[7];
    const float* a1d  = (const float*)d_in[8];
    const float* b1   = (const float*)d_in[9];
    const float* W2   = (const float*)d_in[10];
    const float* a2s  = (const float*)d_in[11];
    const float* a2d  = (const float*)d_in[12];
    const float* b2   = (const float*)d_in[13];
    float* out = (float*)d_out;

    const int N = in_sizes[0] / 128;   // 100000
    const int E = in_sizes[1] / 2;     // 1600000
    const int Etot = E + N;

    // workspace layout
    float* xbuf = (float*)d_ws;                   // N*256
    float* abuf = xbuf + (size_t)N * 256;         // N*256
    float* alS  = abuf + (size_t)N * 256;         // N*8
    float* alD  = alS + (size_t)N * 8;            // N*8
    int* deg      = (int*)(alD + (size_t)N * 8);  // N
    int* rowptr   = deg + N;                      // N+1
    int* cursor   = rowptr + N + 1;               // N
    int* partials = cursor + N;                   // 512
    int* csr_src  = partials + 512;               // Etot
    int* flag     = csr_src + Etot;               // 1

    const int nbN   = (N + 255) / 256;            // blocks over nodes
    const int nb_e  = (Etot + 255) / 256;         // blocks over edges
    const int nb_nw = (N + 3) / 4;                // wave-per-node, 4 waves/block
    const int nb_nh8 = (N * 8 + 255) / 256;

    // ---- CSR build (once, reused by all 3 layers) ----
    detect64_k<<<1, 1, 0, stream>>>(ei, 512, flag);
    hipMemsetAsync(deg, 0, (size_t)N * 4, stream);
    deg_k<<<nb_e, 256, 0, stream>>>(ei, flag, deg, E, Etot, N);
    scan1_k<<<nbN, 256, 0, stream>>>(deg, rowptr, partials, N);
    scan2_k<<<1, 512, 0, stream>>>(partials, nbN);
    scan3_k<<<nbN, 256, 0, stream>>>(rowptr, cursor, partials, N, Etot);
    scatter_k<<<nb_e, 256, 0, stream>>>(ei, flag, cursor, csr_src, E, Etot, N);

    dim3 g256((256 + 63) / 64, (N + 63) / 64);
    dim3 g40(1, (N + 63) / 64);

    // ---------- Layer 0: Fin=128, H=8, C=32 ----------
    gemm_k<<<g256, 256, 0, stream>>>(feat, W0, xbuf, N, 128, 256);
    al_k<<<nb_nh8, 256, 0, stream>>>(xbuf, a0s, a0d, alS, alD, N, 8, 32);
    node_aggr8_k<<<nb_nw, 256, 0, stream>>>(rowptr, csr_src, alS, alD, xbuf, b0,
                                            abuf, N, 1);   // h1 -> abuf (ELU fused)

    // ---------- Layer 1: Fin=256, H=8, C=32 ----------
    gemm_k<<<g256, 256, 0, stream>>>(abuf, W1, xbuf, N, 256, 256);  // x1 -> xbuf
    al_k<<<nb_nh8, 256, 0, stream>>>(xbuf, a1s, a1d, alS, alD, N, 8, 32);
    node_aggr8_k<<<nb_nw, 256, 0, stream>>>(rowptr, csr_src, alS, alD, xbuf, b1,
                                            abuf, N, 1);   // h2 -> abuf (ELU fused)

    // ---------- Layer 2: Fin=256, H=1, C=40 ----------
    gemm_k<<<g40, 256, 0, stream>>>(abuf, W2, xbuf, N, 256, 40);    // x2 -> xbuf[0..N*40)
    al_k<<<nbN, 256, 0, stream>>>(xbuf, a2s, a2d, alS, alD, N, 1, 40);
    node_aggr1_k<<<nb_nw, 256, 0, stream>>>(rowptr, csr_src, alS, alD, xbuf, b2,
                                            out, N);       // bias fused, direct to out
}

// Round 4
// 1562.736 us; speedup vs baseline: 4.3283x; 1.2219x over previous
//
#include <hip/hip_runtime.h>
#include <hip/hip_bf16.h>
#include <math.h>

typedef __attribute__((ext_vector_type(8))) short short8;
typedef __attribute__((ext_vector_type(4))) float f32x4;
typedef unsigned short ushort_t;
struct __align__(8) us4 { ushort_t x, y, z, w; };

// round-to-nearest-even fp32 -> bf16 (no NaN handling needed here)
__device__ __forceinline__ ushort_t f2bf(float f) {
    unsigned u = __float_as_uint(f);
    u += 0x7FFFu + ((u >> 16) & 1u);
    return (ushort_t)(u >> 16);
}
__device__ __forceinline__ float bf2f(ushort_t h) {
    return __uint_as_float(((unsigned)h) << 16);
}

// ---- detect whether edge_index is int64 (odd int32 words all zero) ----
__global__ void detect64_k(const int* __restrict__ ei, int n_check, int* __restrict__ flag) {
    if (blockIdx.x == 0 && threadIdx.x == 0) {
        int zeros = 0;
        for (int i = 0; i < n_check; ++i) zeros += (ei[2 * i + 1] == 0) ? 1 : 0;
        *flag = (zeros >= n_check - 2) ? 1 : 0;
    }
}

__device__ __forceinline__ void edge_sd(const int* __restrict__ ei, int e, int E,
                                        int is64, int N, int& s_, int& d_) {
    if (e >= E) { s_ = d_ = e - E; return; }   // self-loops appended
    int s, d;
    if (is64) { s = ei[2 * e]; d = ei[2 * (E + e)]; }
    else      { s = ei[e];     d = ei[E + e]; }
    s_ = ((unsigned)s < (unsigned)N) ? s : 0;
    d_ = ((unsigned)d < (unsigned)N) ? d : 0;
}

// ================= CSR construction =================
__global__ void deg_k(const int* __restrict__ ei, const int* __restrict__ flag,
                      int* __restrict__ deg, int E, int Etot, int N) {
    int e = blockIdx.x * 256 + threadIdx.x;
    if (e >= Etot) return;
    int s_, d_;
    edge_sd(ei, e, E, *flag, N, s_, d_);
    atomicAdd(&deg[d_], 1);
}

__global__ void scan1_k(const int* __restrict__ deg, int* __restrict__ rowptr,
                        int* __restrict__ partials, int N) {
    __shared__ int tmp[256];
    int tx = threadIdx.x, i = blockIdx.x * 256 + tx;
    int v = (i < N) ? deg[i] : 0;
    tmp[tx] = v;
    __syncthreads();
    for (int off = 1; off < 256; off <<= 1) {
        int t = (tx >= off) ? tmp[tx - off] : 0;
        __syncthreads();
        tmp[tx] += t;
        __syncthreads();
    }
    if (i < N) rowptr[i] = tmp[tx] - v;
    if (tx == 255) partials[blockIdx.x] = tmp[255];
}

__global__ void scan2_k(int* __restrict__ partials, int nb) {
    __shared__ int tmp[512];
    int tx = threadIdx.x;
    int v = (tx < nb) ? partials[tx] : 0;
    tmp[tx] = v;
    __syncthreads();
    for (int off = 1; off < 512; off <<= 1) {
        int t = (tx >= off) ? tmp[tx - off] : 0;
        __syncthreads();
        tmp[tx] += t;
        __syncthreads();
    }
    if (tx < nb) partials[tx] = tmp[tx];
}

__global__ void scan3_k(int* __restrict__ rowptr, int* __restrict__ cursor,
                        const int* __restrict__ partials, int N, int Etot) {
    int i = blockIdx.x * 256 + threadIdx.x;
    if (i < N) {
        int off = (blockIdx.x > 0) ? partials[blockIdx.x - 1] : 0;
        int v = rowptr[i] + off;
        rowptr[i] = v;
        cursor[i] = v;
    }
    if (i == 0) rowptr[N] = Etot;
}

__global__ void scatter_k(const int* __restrict__ ei, const int* __restrict__ flag,
                          int* __restrict__ cursor, int* __restrict__ csr_src,
                          int E, int Etot, int N) {
    int e = blockIdx.x * 256 + threadIdx.x;
    if (e >= Etot) return;
    int s_, d_;
    edge_sd(ei, e, E, *flag, N, s_, d_);
    int pos = atomicAdd(&cursor[d_], 1);
    csr_src[pos] = s_;
}

// ================= split-bf16 MFMA GEMM =================
// C[N,M] = A[N,K] * B[K,M], fp32 in/out, internally hi/lo bf16 (3-pass Markidis).
// BM=128 rows; BN columns per block; 4 waves arranged WMCNT x WNCNT.
template <int BN, int WMCNT, int WNCNT>
__global__ __launch_bounds__(256) void mfma_gemm_k(const float* __restrict__ A,
                                                   const float* __restrict__ B,
                                                   float* __restrict__ C,
                                                   int N, int K, int M) {
    constexpr int BM = 128;
    constexpr int PAD = 40;                 // ushorts per LDS row (32 data + 8 pad)
    constexpr int WMX = BM / WMCNT;         // wave m-extent
    constexpr int WNX = BN / WNCNT;         // wave n-extent
    constexpr int FM = WMX / 16, FN = WNX / 16;

    __shared__ ushort_t Ah[BM * PAD], Al[BM * PAD];
    __shared__ ushort_t Bh[BN * PAD], Bl[BN * PAD];

    const int tx = threadIdx.x;
    const int wave = tx >> 6, lane = tx & 63;
    const int quad = lane >> 4, l16 = lane & 15;
    const int br = blockIdx.y * BM, bc = blockIdx.x * BN;
    const int wm = (wave / WNCNT) * WMX;
    const int wn = (wave % WNCNT) * WNX;

    f32x4 acc[FM][FN] = {};

    for (int k0 = 0; k0 < K; k0 += 32) {
        // ---- stage A: 128x32 fp32, thread t round r loads A[m][k4..k4+3] ----
        #pragma unroll
        for (int r = 0; r < 4; ++r) {
            int i = r * 256 + tx;
            int m = i >> 3, k4 = (i & 7) * 4;
            int gr = br + m;
            float4 v = make_float4(0.f, 0.f, 0.f, 0.f);
            if (gr < N) v = *(const float4*)&A[(size_t)gr * K + k0 + k4];
            us4 h, l;
            h.x = f2bf(v.x); l.x = f2bf(v.x - bf2f(h.x));
            h.y = f2bf(v.y); l.y = f2bf(v.y - bf2f(h.y));
            h.z = f2bf(v.z); l.z = f2bf(v.z - bf2f(h.z));
            h.w = f2bf(v.w); l.w = f2bf(v.w - bf2f(h.w));
            *(us4*)&Ah[m * PAD + k4] = h;
            *(us4*)&Al[m * PAD + k4] = l;
        }
        // ---- stage B (transposed to [n][k]): lane-k-major mapping ----
        #pragma unroll
        for (int r = 0; r < BN / 32; ++r) {
            int i = r * 256 + tx;
            int k = i & 31;
            int n4 = (i >> 5) * 4;
            const float* bp = &B[(size_t)(k0 + k) * M + bc + n4];
            float4 v = make_float4(0.f, 0.f, 0.f, 0.f);
            if (bc + n4 + 3 < M) {
                v = *(const float4*)bp;
            } else {
                if (bc + n4 + 0 < M) v.x = bp[0];
                if (bc + n4 + 1 < M) v.y = bp[1];
                if (bc + n4 + 2 < M) v.z = bp[2];
                if (bc + n4 + 3 < M) v.w = bp[3];
            }
            ushort_t h0 = f2bf(v.x), h1 = f2bf(v.y), h2 = f2bf(v.z), h3 = f2bf(v.w);
            Bh[(n4 + 0) * PAD + k] = h0;  Bl[(n4 + 0) * PAD + k] = f2bf(v.x - bf2f(h0));
            Bh[(n4 + 1) * PAD + k] = h1;  Bl[(n4 + 1) * PAD + k] = f2bf(v.y - bf2f(h1));
            Bh[(n4 + 2) * PAD + k] = h2;  Bl[(n4 + 2) * PAD + k] = f2bf(v.z - bf2f(h2));
            Bh[(n4 + 3) * PAD + k] = h3;  Bl[(n4 + 3) * PAD + k] = f2bf(v.w - bf2f(h3));
        }
        __syncthreads();

        // ---- compute: 3 MFMA passes (hi*hi, hi*lo, lo*hi) ----
        short8 afh[FM], afl[FM];
        #pragma unroll
        for (int mi = 0; mi < FM; ++mi) {
            int row = wm + mi * 16 + l16;
            afh[mi] = *(const short8*)&Ah[row * PAD + quad * 8];
            afl[mi] = *(const short8*)&Al[row * PAD + quad * 8];
        }
        #pragma unroll
        for (int ni = 0; ni < FN; ++ni) {
            int row = wn + ni * 16 + l16;
            short8 bfh = *(const short8*)&Bh[row * PAD + quad * 8];
            short8 bfl = *(const short8*)&Bl[row * PAD + quad * 8];
            #pragma unroll
            for (int mi = 0; mi < FM; ++mi) {
                acc[mi][ni] = __builtin_amdgcn_mfma_f32_16x16x32_bf16(afh[mi], bfh, acc[mi][ni], 0, 0, 0);
                acc[mi][ni] = __builtin_amdgcn_mfma_f32_16x16x32_bf16(afh[mi], bfl, acc[mi][ni], 0, 0, 0);
                acc[mi][ni] = __builtin_amdgcn_mfma_f32_16x16x32_bf16(afl[mi], bfh, acc[mi][ni], 0, 0, 0);
            }
        }
        __syncthreads();
    }

    // ---- epilogue: D frag mapping col=lane&15, row=quad*4+r ----
    #pragma unroll
    for (int mi = 0; mi < FM; ++mi) {
        #pragma unroll
        for (int ni = 0; ni < FN; ++ni) {
            int gc = bc + wn + ni * 16 + l16;
            if (gc >= M) continue;
            #pragma unroll
            for (int r = 0; r < 4; ++r) {
                int gr = br + wm + mi * 16 + quad * 4 + r;
                if (gr < N) C[(size_t)gr * M + gc] = acc[mi][ni][r];
            }
        }
    }
}

// ---- per-node attention logits: al_src/al_dst [N,H] ----
__global__ void al_k(const float* __restrict__ x, const float* __restrict__ a_s,
                     const float* __restrict__ a_d, float* __restrict__ alS,
                     float* __restrict__ alD, int N, int H, int C) {
    int idx = blockIdx.x * 256 + threadIdx.x;
    if (idx >= N * H) return;
    int n = idx / H, h = idx - n * H;
    const float* xp = x + (size_t)n * H * C + (size_t)h * C;
    float s1 = 0.f, s2 = 0.f;
    for (int c = 0; c < C; ++c) {
        float v = xp[c];
        s1 += v * a_s[h * C + c];
        s2 += v * a_d[h * C + c];
    }
    alS[idx] = s1;
    alD[idx] = s2;
}

// ================= fused per-node softmax + aggregation =================
// H=8, C=32 (HC=256). One wave per destination node.
__global__ __launch_bounds__(256) void node_aggr8_k(
    const int* __restrict__ rowptr, const int* __restrict__ csr_src,
    const float* __restrict__ alS, const float* __restrict__ alD,
    const float* __restrict__ x, const float* __restrict__ bias,
    float* __restrict__ out, int N, int do_elu) {
    int wid = (blockIdx.x * 256 + threadIdx.x) >> 6;
    int lane = threadIdx.x & 63;
    if (wid >= N) return;
    const int d = wid;
    const int beg = rowptr[d], end = rowptr[d + 1];

    const int h = lane & 7, esub = lane >> 3;
    const float aDh = alD[d * 8 + h];
    float m = -INFINITY, s = 0.f;
    for (int e = beg + esub; e < end; e += 8) {
        int src = csr_src[e];
        float ev = alS[src * 8 + h] + aDh;
        ev = ev > 0.f ? ev : 0.2f * ev;
        float mn = fmaxf(m, ev);
        s = s * expf(m - mn) + expf(ev - mn);
        m = mn;
    }
    #pragma unroll
    for (int off = 8; off < 64; off <<= 1) {
        float m2 = __shfl_xor(m, off);
        float s2 = __shfl_xor(s, off);
        float mn = fmaxf(m, m2);
        if (mn != -INFINITY) {
            s = s * expf(m - mn) + s2 * expf(m2 - mn);
            m = mn;
        }
    }

    const int hh = lane >> 3;
    const float mh = __shfl(m, hh);
    const float rs = 1.f / __shfl(s, hh);
    const float aDhh = alD[d * 8 + hh];
    float4 acc = {0.f, 0.f, 0.f, 0.f};
    for (int e = beg; e < end; ++e) {
        int src = csr_src[e];
        float ev = alS[src * 8 + hh] + aDhh;
        ev = ev > 0.f ? ev : 0.2f * ev;
        float alpha = expf(ev - mh) * rs;
        const float4 xv = *(const float4*)&x[(size_t)src * 256 + lane * 4];
        acc.x += xv.x * alpha;
        acc.y += xv.y * alpha;
        acc.z += xv.z * alpha;
        acc.w += xv.w * alpha;
    }
    const float4 bv = *(const float4*)&bias[lane * 4];
    float4 o;
    o.x = acc.x + bv.x; o.y = acc.y + bv.y; o.z = acc.z + bv.z; o.w = acc.w + bv.w;
    if (do_elu) {
        o.x = o.x > 0.f ? o.x : expm1f(o.x);
        o.y = o.y > 0.f ? o.y : expm1f(o.y);
        o.z = o.z > 0.f ? o.z : expm1f(o.z);
        o.w = o.w > 0.f ? o.w : expm1f(o.w);
    }
    *(float4*)&out[(size_t)d * 256 + lane * 4] = o;
}

// H=1, C=40. One wave per destination node.
__global__ __launch_bounds__(256) void node_aggr1_k(
    const int* __restrict__ rowptr, const int* __restrict__ csr_src,
    const float* __restrict__ alS, const float* __restrict__ alD,
    const float* __restrict__ x, const float* __restrict__ bias,
    float* __restrict__ out, int N) {
    int wid = (blockIdx.x * 256 + threadIdx.x) >> 6;
    int lane = threadIdx.x & 63;
    if (wid >= N) return;
    const int d = wid;
    const int beg = rowptr[d], end = rowptr[d + 1];
    const float aD = alD[d];

    float m = -INFINITY, s = 0.f;
    for (int e = beg + lane; e < end; e += 64) {
        int src = csr_src[e];
        float ev = alS[src] + aD;
        ev = ev > 0.f ? ev : 0.2f * ev;
        float mn = fmaxf(m, ev);
        s = s * expf(m - mn) + expf(ev - mn);
        m = mn;
    }
    #pragma unroll
    for (int off = 1; off < 64; off <<= 1) {
        float m2 = __shfl_xor(m, off);
        float s2 = __shfl_xor(s, off);
        float mn = fmaxf(m, m2);
        if (mn != -INFINITY) {
            s = s * expf(m - mn) + s2 * expf(m2 - mn);
            m = mn;
        }
    }
    const float rs = 1.f / s;
    float acc = 0.f;
    for (int e = beg; e < end; ++e) {
        int src = csr_src[e];
        float ev = alS[src] + aD;
        ev = ev > 0.f ? ev : 0.2f * ev;
        float alpha = expf(ev - m) * rs;
        if (lane < 40) acc += x[(size_t)src * 40 + lane] * alpha;
    }
    if (lane < 40) out[(size_t)d * 40 + lane] = acc + bias[lane];
}

extern "C" void kernel_launch(void* const* d_in, const int* in_sizes, int n_in,
                              void* d_out, int out_size, void* d_ws, size_t ws_size,
                              hipStream_t stream) {
    const float* feat = (const float*)d_in[0];
    const int*   ei   = (const int*)d_in[1];
    const float* W0   = (const float*)d_in[2];
    const float* a0s  = (const float*)d_in[3];
    const float* a0d  = (const float*)d_in[4];
    const float* b0   = (const float*)d_in[5];
    const float* W1   = (const float*)d_in[6];
    const float* a1s  = (const float*)d_in[7];
    const float* a1d  = (const float*)d_in[8];
    const float* b1   = (const float*)d_in[9];
    const float* W2   = (const float*)d_in[10];
    const float* a2s  = (const float*)d_in[11];
    const float* a2d  = (const float*)d_in[12];
    const float* b2   = (const float*)d_in[13];
    float* out = (float*)d_out;

    const int N = in_sizes[0] / 128;   // 100000
    const int E = in_sizes[1] / 2;     // 1600000
    const int Etot = E + N;

    // workspace layout
    float* xbuf = (float*)d_ws;                   // N*256
    float* abuf = xbuf + (size_t)N * 256;         // N*256
    float* alS  = abuf + (size_t)N * 256;         // N*8
    float* alD  = alS + (size_t)N * 8;            // N*8
    int* deg      = (int*)(alD + (size_t)N * 8);  // N
    int* rowptr   = deg + N;                      // N+1
    int* cursor   = rowptr + N + 1;               // N
    int* partials = cursor + N;                   // 512
    int* csr_src  = partials + 512;               // Etot
    int* flag     = csr_src + Etot;               // 1

    const int nbN    = (N + 255) / 256;
    const int nb_e   = (Etot + 255) / 256;
    const int nb_nw  = (N + 3) / 4;
    const int nb_nh8 = (N * 8 + 255) / 256;

    // ---- CSR build (once, reused by all 3 layers) ----
    detect64_k<<<1, 1, 0, stream>>>(ei, 512, flag);
    hipMemsetAsync(deg, 0, (size_t)N * 4, stream);
    deg_k<<<nb_e, 256, 0, stream>>>(ei, flag, deg, E, Etot, N);
    scan1_k<<<nbN, 256, 0, stream>>>(deg, rowptr, partials, N);
    scan2_k<<<1, 512, 0, stream>>>(partials, nbN);
    scan3_k<<<nbN, 256, 0, stream>>>(rowptr, cursor, partials, N, Etot);
    scatter_k<<<nb_e, 256, 0, stream>>>(ei, flag, cursor, csr_src, E, Etot, N);

    const int mb = (N + 127) / 128;   // 782 row-blocks

    // ---------- Layer 0: Fin=128, H=8, C=32 ----------
    mfma_gemm_k<128, 2, 2><<<dim3(2, mb), 256, 0, stream>>>(feat, W0, xbuf, N, 128, 256);
    al_k<<<nb_nh8, 256, 0, stream>>>(xbuf, a0s, a0d, alS, alD, N, 8, 32);
    node_aggr8_k<<<nb_nw, 256, 0, stream>>>(rowptr, csr_src, alS, alD, xbuf, b0,
                                            abuf, N, 1);   // h1 -> abuf (ELU fused)

    // ---------- Layer 1: Fin=256, H=8, C=32 ----------
    mfma_gemm_k<128, 2, 2><<<dim3(2, mb), 256, 0, stream>>>(abuf, W1, xbuf, N, 256, 256);
    al_k<<<nb_nh8, 256, 0, stream>>>(xbuf, a1s, a1d, alS, alD, N, 8, 32);
    node_aggr8_k<<<nb_nw, 256, 0, stream>>>(rowptr, csr_src, alS, alD, xbuf, b1,
                                            abuf, N, 1);   // h2 -> abuf (ELU fused)

    // ---------- Layer 2: Fin=256, H=1, C=40 ----------
    mfma_gemm_k<64, 4, 1><<<dim3(1, mb), 256, 0, stream>>>(abuf, W2, xbuf, N, 256, 40);
    al_k<<<nbN, 256, 0, stream>>>(xbuf, a2s, a2d, alS, alD, N, 1, 40);
    node_aggr1_k<<<nb_nw, 256, 0, stream>>>(rowptr, csr_src, alS, alD, xbuf, b2,
                                            out, N);       // bias fused, direct to out
}

// Round 6
// 1162.384 us; speedup vs baseline: 5.8191x; 1.3444x over previous
//
#include <hip/hip_runtime.h>
#include <hip/hip_bf16.h>
#include <hip/hip_fp16.h>
#include <math.h>

typedef __attribute__((ext_vector_type(8))) short short8;
typedef __attribute__((ext_vector_type(4))) float f32x4;
typedef unsigned short ushort_t;
struct __align__(8) us4 { ushort_t x, y, z, w; };

// round-to-nearest-even fp32 -> bf16
__device__ __forceinline__ ushort_t f2bf(float f) {
    unsigned u = __float_as_uint(f);
    u += 0x7FFFu + ((u >> 16) & 1u);
    return (ushort_t)(u >> 16);
}
__device__ __forceinline__ float bf2f(ushort_t h) {
    return __uint_as_float(((unsigned)h) << 16);
}

__device__ __forceinline__ void store_out(float* p, float v) { *p = v; }
__device__ __forceinline__ void store_out(__half* p, float v) { *p = __float2half(v); }

// ---- detect whether edge_index is int64 (odd int32 words all zero) ----
__global__ void detect64_k(const int* __restrict__ ei, int n_check, int* __restrict__ flag) {
    if (blockIdx.x == 0 && threadIdx.x == 0) {
        int zeros = 0;
        for (int i = 0; i < n_check; ++i) zeros += (ei[2 * i + 1] == 0) ? 1 : 0;
        *flag = (zeros >= n_check - 2) ? 1 : 0;
    }
}

__device__ __forceinline__ void edge_sd(const int* __restrict__ ei, int e, int E,
                                        int is64, int N, int& s_, int& d_) {
    if (e >= E) { s_ = d_ = e - E; return; }   // self-loops appended
    int s, d;
    if (is64) { s = ei[2 * e]; d = ei[2 * (E + e)]; }
    else      { s = ei[e];     d = ei[E + e]; }
    s_ = ((unsigned)s < (unsigned)N) ? s : 0;
    d_ = ((unsigned)d < (unsigned)N) ? d : 0;
}

// ================= CSR construction =================
__global__ void deg_k(const int* __restrict__ ei, const int* __restrict__ flag,
                      int* __restrict__ deg, int E, int Etot, int N) {
    int e = blockIdx.x * 256 + threadIdx.x;
    if (e >= Etot) return;
    int s_, d_;
    edge_sd(ei, e, E, *flag, N, s_, d_);
    atomicAdd(&deg[d_], 1);
}

__global__ void scan1_k(const int* __restrict__ deg, int* __restrict__ rowptr,
                        int* __restrict__ partials, int N) {
    __shared__ int tmp[256];
    int tx = threadIdx.x, i = blockIdx.x * 256 + tx;
    int v = (i < N) ? deg[i] : 0;
    tmp[tx] = v;
    __syncthreads();
    for (int off = 1; off < 256; off <<= 1) {
        int t = (tx >= off) ? tmp[tx - off] : 0;
        __syncthreads();
        tmp[tx] += t;
        __syncthreads();
    }
    if (i < N) rowptr[i] = tmp[tx] - v;
    if (tx == 255) partials[blockIdx.x] = tmp[255];
}

__global__ void scan2_k(int* __restrict__ partials, int nb) {
    __shared__ int tmp[512];
    int tx = threadIdx.x;
    int v = (tx < nb) ? partials[tx] : 0;
    tmp[tx] = v;
    __syncthreads();
    for (int off = 1; off < 512; off <<= 1) {
        int t = (tx >= off) ? tmp[tx - off] : 0;
        __syncthreads();
        tmp[tx] += t;
        __syncthreads();
    }
    if (tx < nb) partials[tx] = tmp[tx];
}

__global__ void scan3_k(int* __restrict__ rowptr, int* __restrict__ cursor,
                        const int* __restrict__ partials, int N, int Etot) {
    int i = blockIdx.x * 256 + threadIdx.x;
    if (i < N) {
        int off = (blockIdx.x > 0) ? partials[blockIdx.x - 1] : 0;
        int v = rowptr[i] + off;
        rowptr[i] = v;
        cursor[i] = v;
    }
    if (i == 0) rowptr[N] = Etot;
}

__global__ void scatter_k(const int* __restrict__ ei, const int* __restrict__ flag,
                          int* __restrict__ cursor, int* __restrict__ csr_src,
                          int E, int Etot, int N) {
    int e = blockIdx.x * 256 + threadIdx.x;
    if (e >= Etot) return;
    int s_, d_;
    edge_sd(ei, e, E, *flag, N, s_, d_);
    int pos = atomicAdd(&cursor[d_], 1);
    csr_src[pos] = s_;
}

// ================= split-bf16 MFMA GEMM =================
// C[N,M] = A[N,K]*B[K,M]; fp32 math via hi/lo bf16 3-pass; TOUT = float or __half.
template <int BN, int WMCNT, int WNCNT, typename TOUT>
__global__ __launch_bounds__(256) void mfma_gemm_k(const float* __restrict__ A,
                                                   const float* __restrict__ B,
                                                   TOUT* __restrict__ C,
                                                   int N, int K, int M) {
    constexpr int BM = 128;
    constexpr int PAD = 40;
    constexpr int WMX = BM / WMCNT;
    constexpr int WNX = BN / WNCNT;
    constexpr int FM = WMX / 16, FN = WNX / 16;

    __shared__ ushort_t Ah[BM * PAD], Al[BM * PAD];
    __shared__ ushort_t Bh[BN * PAD], Bl[BN * PAD];

    const int tx = threadIdx.x;
    const int wave = tx >> 6, lane = tx & 63;
    const int quad = lane >> 4, l16 = lane & 15;
    const int br = blockIdx.y * BM, bc = blockIdx.x * BN;
    const int wm = (wave / WNCNT) * WMX;
    const int wn = (wave % WNCNT) * WNX;

    f32x4 acc[FM][FN] = {};

    for (int k0 = 0; k0 < K; k0 += 32) {
        #pragma unroll
        for (int r = 0; r < 4; ++r) {
            int i = r * 256 + tx;
            int m = i >> 3, k4 = (i & 7) * 4;
            int gr = br + m;
            float4 v = make_float4(0.f, 0.f, 0.f, 0.f);
            if (gr < N) v = *(const float4*)&A[(size_t)gr * K + k0 + k4];
            us4 h, l;
            h.x = f2bf(v.x); l.x = f2bf(v.x - bf2f(h.x));
            h.y = f2bf(v.y); l.y = f2bf(v.y - bf2f(h.y));
            h.z = f2bf(v.z); l.z = f2bf(v.z - bf2f(h.z));
            h.w = f2bf(v.w); l.w = f2bf(v.w - bf2f(h.w));
            *(us4*)&Ah[m * PAD + k4] = h;
            *(us4*)&Al[m * PAD + k4] = l;
        }
        #pragma unroll
        for (int r = 0; r < BN / 32; ++r) {
            int i = r * 256 + tx;
            int k = i & 31;
            int n4 = (i >> 5) * 4;
            const float* bp = &B[(size_t)(k0 + k) * M + bc + n4];
            float4 v = make_float4(0.f, 0.f, 0.f, 0.f);
            if (bc + n4 + 3 < M) {
                v = *(const float4*)bp;
            } else {
                if (bc + n4 + 0 < M) v.x = bp[0];
                if (bc + n4 + 1 < M) v.y = bp[1];
                if (bc + n4 + 2 < M) v.z = bp[2];
                if (bc + n4 + 3 < M) v.w = bp[3];
            }
            ushort_t h0 = f2bf(v.x), h1 = f2bf(v.y), h2 = f2bf(v.z), h3 = f2bf(v.w);
            Bh[(n4 + 0) * PAD + k] = h0;  Bl[(n4 + 0) * PAD + k] = f2bf(v.x - bf2f(h0));
            Bh[(n4 + 1) * PAD + k] = h1;  Bl[(n4 + 1) * PAD + k] = f2bf(v.y - bf2f(h1));
            Bh[(n4 + 2) * PAD + k] = h2;  Bl[(n4 + 2) * PAD + k] = f2bf(v.z - bf2f(h2));
            Bh[(n4 + 3) * PAD + k] = h3;  Bl[(n4 + 3) * PAD + k] = f2bf(v.w - bf2f(h3));
        }
        __syncthreads();

        short8 afh[FM], afl[FM];
        #pragma unroll
        for (int mi = 0; mi < FM; ++mi) {
            int row = wm + mi * 16 + l16;
            afh[mi] = *(const short8*)&Ah[row * PAD + quad * 8];
            afl[mi] = *(const short8*)&Al[row * PAD + quad * 8];
        }
        #pragma unroll
        for (int ni = 0; ni < FN; ++ni) {
            int row = wn + ni * 16 + l16;
            short8 bfh = *(const short8*)&Bh[row * PAD + quad * 8];
            short8 bfl = *(const short8*)&Bl[row * PAD + quad * 8];
            #pragma unroll
            for (int mi = 0; mi < FM; ++mi) {
                acc[mi][ni] = __builtin_amdgcn_mfma_f32_16x16x32_bf16(afh[mi], bfh, acc[mi][ni], 0, 0, 0);
                acc[mi][ni] = __builtin_amdgcn_mfma_f32_16x16x32_bf16(afh[mi], bfl, acc[mi][ni], 0, 0, 0);
                acc[mi][ni] = __builtin_amdgcn_mfma_f32_16x16x32_bf16(afl[mi], bfh, acc[mi][ni], 0, 0, 0);
            }
        }
        __syncthreads();
    }

    #pragma unroll
    for (int mi = 0; mi < FM; ++mi) {
        #pragma unroll
        for (int ni = 0; ni < FN; ++ni) {
            int gc = bc + wn + ni * 16 + l16;
            if (gc >= M) continue;
            #pragma unroll
            for (int r = 0; r < 4; ++r) {
                int gr = br + wm + mi * 16 + quad * 4 + r;
                if (gr < N) store_out(&C[(size_t)gr * M + gc], acc[mi][ni][r]);
            }
        }
    }
}

// ---- per-node attention logits from fp16 x (H=8, C=32) ----
__global__ void al8_f16_k(const __half* __restrict__ xh, const float* __restrict__ a_s,
                          const float* __restrict__ a_d, float* __restrict__ alS,
                          float* __restrict__ alD, int N) {
    int idx = blockIdx.x * 256 + threadIdx.x;
    if (idx >= N * 8) return;
    int n = idx >> 3, h = idx & 7;
    const __half2* hp = (const __half2*)(xh + (size_t)n * 256 + h * 32);
    const float* as = a_s + h * 32;
    const float* ad = a_d + h * 32;
    float s1 = 0.f, s2 = 0.f;
    #pragma unroll
    for (int c2 = 0; c2 < 16; ++c2) {
        float2 f = __half22float2(hp[c2]);
        s1 += f.x * as[2 * c2] + f.y * as[2 * c2 + 1];
        s2 += f.x * ad[2 * c2] + f.y * ad[2 * c2 + 1];
    }
    alS[idx] = s1;
    alD[idx] = s2;
}

// ---- fp32 logits (layer 2, H=1, C=40) ----
__global__ void al1_k(const float* __restrict__ x, const float* __restrict__ a_s,
                      const float* __restrict__ a_d, float* __restrict__ alS,
                      float* __restrict__ alD, int N) {
    int n = blockIdx.x * 256 + threadIdx.x;
    if (n >= N) return;
    const float* xp = x + (size_t)n * 40;
    float s1 = 0.f, s2 = 0.f;
    for (int c = 0; c < 40; ++c) {
        float v = xp[c];
        s1 += v * a_s[c];
        s2 += v * a_d[c];
    }
    alS[n] = s1;
    alD[n] = s2;
}

// ================= fused per-node softmax + aggregation =================
// H=8, C=32 (HC=256). One wave per destination node. fp16 gather source.
// Direct exp (no max-subtraction): logits here are |ev| <~ 6; clamp at 30 as
// infinity insurance.
__global__ __launch_bounds__(256) void node_aggr8_k(
    const int* __restrict__ rowptr, const int* __restrict__ csr_src,
    const float* __restrict__ alS, const float* __restrict__ alD,
    const __half* __restrict__ xh, const float* __restrict__ bias,
    float* __restrict__ out, int N, int do_elu) {
    int wid = (blockIdx.x * 256 + threadIdx.x) >> 6;
    int lane = threadIdx.x & 63;
    if (wid >= N) return;
    const int d = wid;
    const int beg = rowptr[d], end = rowptr[d + 1];

    // lane = esub*8 + h
    const int h = lane & 7, esub = lane >> 3;
    const float aDh = alD[d * 8 + h];

    // sweep 1: s = sum exp(leaky(ev)) per head, 8 edges in parallel
    float s = 0.f;
    for (int e = beg + esub; e < end; e += 8) {
        int src = csr_src[e];
        float ev = alS[src * 8 + h] + aDh;
        ev = ev > 0.f ? ev : 0.2f * ev;
        s += __expf(fminf(ev, 30.f));
    }
    #pragma unroll
    for (int off = 8; off < 64; off <<= 1) s += __shfl_xor(s, off);
    const float rs = 1.f / s;   // per-head reciprocal

    // sweep 2: chunks of 8 edges; alphas computed once across lanes then broadcast
    const int hh = lane >> 3;   // head owned in gather phase
    float4 acc = {0.f, 0.f, 0.f, 0.f};
    for (int eb = beg; eb < end; eb += 8) {
        int e = eb + esub;
        int src_l = 0;
        float alpha_l = 0.f;
        if (e < end) {
            src_l = csr_src[e];
            float ev = alS[src_l * 8 + h] + aDh;
            ev = ev > 0.f ? ev : 0.2f * ev;
            alpha_l = __expf(fminf(ev, 30.f)) * rs;
        }
        int cnt = end - eb; if (cnt > 8) cnt = 8;
        for (int j = 0; j < cnt; ++j) {
            int src = __shfl(src_l, j * 8);
            float alpha = __shfl(alpha_l, j * 8 + hh);
            const __half2* hp = (const __half2*)(xh + ((size_t)src << 8) + lane * 4);
            float2 f0 = __half22float2(hp[0]);
            float2 f1 = __half22float2(hp[1]);
            acc.x += f0.x * alpha;
            acc.y += f0.y * alpha;
            acc.z += f1.x * alpha;
            acc.w += f1.y * alpha;
        }
    }
    const float4 bv = *(const float4*)&bias[lane * 4];
    float4 o;
    o.x = acc.x + bv.x; o.y = acc.y + bv.y; o.z = acc.z + bv.z; o.w = acc.w + bv.w;
    if (do_elu) {
        o.x = o.x > 0.f ? o.x : expm1f(o.x);
        o.y = o.y > 0.f ? o.y : expm1f(o.y);
        o.z = o.z > 0.f ? o.z : expm1f(o.z);
        o.w = o.w > 0.f ? o.w : expm1f(o.w);
    }
    *(float4*)&out[(size_t)d * 256 + lane * 4] = o;
}

// H=1, C=40. One wave per destination node (fp32, stable-max kept: cheap).
__global__ __launch_bounds__(256) void node_aggr1_k(
    const int* __restrict__ rowptr, const int* __restrict__ csr_src,
    const float* __restrict__ alS, const float* __restrict__ alD,
    const float* __restrict__ x, const float* __restrict__ bias,
    float* __restrict__ out, int N) {
    int wid = (blockIdx.x * 256 + threadIdx.x) >> 6;
    int lane = threadIdx.x & 63;
    if (wid >= N) return;
    const int d = wid;
    const int beg = rowptr[d], end = rowptr[d + 1];
    const float aD = alD[d];

    float m = -INFINITY, s = 0.f;
    for (int e = beg + lane; e < end; e += 64) {
        int src = csr_src[e];
        float ev = alS[src] + aD;
        ev = ev > 0.f ? ev : 0.2f * ev;
        float mn = fmaxf(m, ev);
        s = s * expf(m - mn) + expf(ev - mn);
        m = mn;
    }
    #pragma unroll
    for (int off = 1; off < 64; off <<= 1) {
        float m2 = __shfl_xor(m, off);
        float s2 = __shfl_xor(s, off);
        float mn = fmaxf(m, m2);
        if (mn != -INFINITY) {
            s = s * expf(m - mn) + s2 * expf(m2 - mn);
            m = mn;
        }
    }
    const float rs = 1.f / s;
    float acc = 0.f;
    for (int e = beg; e < end; ++e) {
        int src = csr_src[e];
        float ev = alS[src] + aD;
        ev = ev > 0.f ? ev : 0.2f * ev;
        float alpha = expf(ev - m) * rs;
        if (lane < 40) acc += x[(size_t)src * 40 + lane] * alpha;
    }
    if (lane < 40) out[(size_t)d * 40 + lane] = acc + bias[lane];
}

extern "C" void kernel_launch(void* const* d_in, const int* in_sizes, int n_in,
                              void* d_out, int out_size, void* d_ws, size_t ws_size,
                              hipStream_t stream) {
    const float* feat = (const float*)d_in[0];
    const int*   ei   = (const int*)d_in[1];
    const float* W0   = (const float*)d_in[2];
    const float* a0s  = (const float*)d_in[3];
    const float* a0d  = (const float*)d_in[4];
    const float* b0   = (const float*)d_in[5];
    const float* W1   = (const float*)d_in[6];
    const float* a1s  = (const float*)d_in[7];
    const float* a1d  = (const float*)d_in[8];
    const float* b1   = (const float*)d_in[9];
    const float* W2   = (const float*)d_in[10];
    const float* a2s  = (const float*)d_in[11];
    const float* a2d  = (const float*)d_in[12];
    const float* b2   = (const float*)d_in[13];
    float* out = (float*)d_out;

    const int N = in_sizes[0] / 128;   // 100000
    const int E = in_sizes[1] / 2;     // 1600000
    const int Etot = E + N;

    // workspace layout (~184 MB total; round-2 proved ws >= ~234 MB)
    float*  abuf = (float*)d_ws;                      // N*256 fp32 (aggr out / gemm in)
    __half* xh   = (__half*)(abuf + (size_t)N * 256); // N*256 fp16 (gemm out, layers 0/1)
    float*  x2   = (float*)(xh + (size_t)N * 256);    // N*40 fp32 (layer-2 gemm out)
    float*  alS  = x2 + (size_t)N * 40;               // N*8
    float*  alD  = alS + (size_t)N * 8;               // N*8
    int* deg      = (int*)(alD + (size_t)N * 8);      // N
    int* rowptr   = deg + N;                          // N+1
    int* cursor   = rowptr + N + 1;                   // N
    int* partials = cursor + N;                       // 512
    int* csr_src  = partials + 512;                   // Etot
    int* flag     = csr_src + Etot;                   // 1

    const int nbN    = (N + 255) / 256;
    const int nb_e   = (Etot + 255) / 256;
    const int nb_nw  = (N + 3) / 4;
    const int nb_nh8 = (N * 8 + 255) / 256;

    // ---- CSR build (once, reused by all 3 layers) ----
    detect64_k<<<1, 1, 0, stream>>>(ei, 512, flag);
    hipMemsetAsync(deg, 0, (size_t)N * 4, stream);
    deg_k<<<nb_e, 256, 0, stream>>>(ei, flag, deg, E, Etot, N);
    scan1_k<<<nbN, 256, 0, stream>>>(deg, rowptr, partials, N);
    scan2_k<<<1, 512, 0, stream>>>(partials, nbN);
    scan3_k<<<nbN, 256, 0, stream>>>(rowptr, cursor, partials, N, Etot);
    scatter_k<<<nb_e, 256, 0, stream>>>(ei, flag, cursor, csr_src, E, Etot, N);

    const int mb = (N + 127) / 128;

    // ---------- Layer 0: Fin=128, H=8, C=32 ----------
    mfma_gemm_k<128, 2, 2, __half><<<dim3(2, mb), 256, 0, stream>>>(feat, W0, xh, N, 128, 256);
    al8_f16_k<<<nb_nh8, 256, 0, stream>>>(xh, a0s, a0d, alS, alD, N);
    node_aggr8_k<<<nb_nw, 256, 0, stream>>>(rowptr, csr_src, alS, alD, xh, b0,
                                            abuf, N, 1);   // h1 -> abuf (ELU fused)

    // ---------- Layer 1: Fin=256, H=8, C=32 ----------
    mfma_gemm_k<128, 2, 2, __half><<<dim3(2, mb), 256, 0, stream>>>(abuf, W1, xh, N, 256, 256);
    al8_f16_k<<<nb_nh8, 256, 0, stream>>>(xh, a1s, a1d, alS, alD, N);
    node_aggr8_k<<<nb_nw, 256, 0, stream>>>(rowptr, csr_src, alS, alD, xh, b1,
                                            abuf, N, 1);   // h2 -> abuf (ELU fused)

    // ---------- Layer 2: Fin=256, H=1, C=40 ----------
    mfma_gemm_k<64, 4, 1, float><<<dim3(1, mb), 256, 0, stream>>>(abuf, W2, x2, N, 256, 40);
    al1_k<<<nbN, 256, 0, stream>>>(x2, a2s, a2d, alS, alD, N);
    node_aggr1_k<<<nb_nw, 256, 0, stream>>>(rowptr, csr_src, alS, alD, x2, b2,
                                            out, N);       // bias fused, direct to out
}

// Round 7
// 998.692 us; speedup vs baseline: 6.7729x; 1.1639x over previous
//
#include <hip/hip_runtime.h>
#include <hip/hip_bf16.h>
#include <hip/hip_fp16.h>
#include <math.h>

typedef __attribute__((ext_vector_type(8))) short short8;
typedef __attribute__((ext_vector_type(8))) _Float16 half8;
typedef __attribute__((ext_vector_type(4))) float f32x4;
typedef unsigned short ushort_t;
struct __align__(8) us4 { ushort_t x, y, z, w; };

// round-to-nearest-even fp32 -> bf16
__device__ __forceinline__ ushort_t f2bf(float f) {
    unsigned u = __float_as_uint(f);
    u += 0x7FFFu + ((u >> 16) & 1u);
    return (ushort_t)(u >> 16);
}
__device__ __forceinline__ float bf2f(ushort_t h) {
    return __uint_as_float(((unsigned)h) << 16);
}

__device__ __forceinline__ void store_out(float* p, float v) { *p = v; }
__device__ __forceinline__ void store_out(__half* p, float v) { *p = __float2half(v); }

// ---- detect whether edge_index is int64 (odd int32 words all zero) ----
__global__ void detect64_k(const int* __restrict__ ei, int n_check, int* __restrict__ flag) {
    if (blockIdx.x == 0 && threadIdx.x == 0) {
        int zeros = 0;
        for (int i = 0; i < n_check; ++i) zeros += (ei[2 * i + 1] == 0) ? 1 : 0;
        *flag = (zeros >= n_check - 2) ? 1 : 0;
    }
}

__device__ __forceinline__ void edge_sd(const int* __restrict__ ei, int e, int E,
                                        int is64, int N, int& s_, int& d_) {
    if (e >= E) { s_ = d_ = e - E; return; }   // self-loops appended
    int s, d;
    if (is64) { s = ei[2 * e]; d = ei[2 * (E + e)]; }
    else      { s = ei[e];     d = ei[E + e]; }
    s_ = ((unsigned)s < (unsigned)N) ? s : 0;
    d_ = ((unsigned)d < (unsigned)N) ? d : 0;
}

// ================= CSR construction =================
__global__ void deg_k(const int* __restrict__ ei, const int* __restrict__ flag,
                      int* __restrict__ deg, int E, int Etot, int N) {
    int e = blockIdx.x * 256 + threadIdx.x;
    if (e >= Etot) return;
    int s_, d_;
    edge_sd(ei, e, E, *flag, N, s_, d_);
    atomicAdd(&deg[d_], 1);
}

__global__ void scan1_k(const int* __restrict__ deg, int* __restrict__ rowptr,
                        int* __restrict__ partials, int N) {
    __shared__ int tmp[256];
    int tx = threadIdx.x, i = blockIdx.x * 256 + tx;
    int v = (i < N) ? deg[i] : 0;
    tmp[tx] = v;
    __syncthreads();
    for (int off = 1; off < 256; off <<= 1) {
        int t = (tx >= off) ? tmp[tx - off] : 0;
        __syncthreads();
        tmp[tx] += t;
        __syncthreads();
    }
    if (i < N) rowptr[i] = tmp[tx] - v;
    if (tx == 255) partials[blockIdx.x] = tmp[255];
}

__global__ void scan2_k(int* __restrict__ partials, int nb) {
    __shared__ int tmp[512];
    int tx = threadIdx.x;
    int v = (tx < nb) ? partials[tx] : 0;
    tmp[tx] = v;
    __syncthreads();
    for (int off = 1; off < 512; off <<= 1) {
        int t = (tx >= off) ? tmp[tx - off] : 0;
        __syncthreads();
        tmp[tx] += t;
        __syncthreads();
    }
    if (tx < nb) partials[tx] = tmp[tx];
}

__global__ void scan3_k(int* __restrict__ rowptr, int* __restrict__ cursor,
                        const int* __restrict__ partials, int N, int Etot) {
    int i = blockIdx.x * 256 + threadIdx.x;
    if (i < N) {
        int off = (blockIdx.x > 0) ? partials[blockIdx.x - 1] : 0;
        int v = rowptr[i] + off;
        rowptr[i] = v;
        cursor[i] = v;
    }
    if (i == 0) rowptr[N] = Etot;
}

__global__ void scatter_k(const int* __restrict__ ei, const int* __restrict__ flag,
                          int* __restrict__ cursor, int* __restrict__ csr_src,
                          int E, int Etot, int N) {
    int e = blockIdx.x * 256 + threadIdx.x;
    if (e >= Etot) return;
    int s_, d_;
    edge_sd(ei, e, E, *flag, N, s_, d_);
    int pos = atomicAdd(&cursor[d_], 1);
    csr_src[pos] = s_;
}

// ================= split-bf16 MFMA GEMM (fp32 A; layer 0) =================
template <int BN, int WMCNT, int WNCNT, typename TOUT>
__global__ __launch_bounds__(256) void mfma_gemm_k(const float* __restrict__ A,
                                                   const float* __restrict__ B,
                                                   TOUT* __restrict__ C,
                                                   int N, int K, int M) {
    constexpr int BM = 128;
    constexpr int PAD = 40;
    constexpr int WMX = BM / WMCNT;
    constexpr int WNX = BN / WNCNT;
    constexpr int FM = WMX / 16, FN = WNX / 16;

    __shared__ ushort_t Ah[BM * PAD], Al[BM * PAD];
    __shared__ ushort_t Bh[BN * PAD], Bl[BN * PAD];

    const int tx = threadIdx.x;
    const int wave = tx >> 6, lane = tx & 63;
    const int quad = lane >> 4, l16 = lane & 15;
    const int br = blockIdx.y * BM, bc = blockIdx.x * BN;
    const int wm = (wave / WNCNT) * WMX;
    const int wn = (wave % WNCNT) * WNX;

    f32x4 acc[FM][FN] = {};

    for (int k0 = 0; k0 < K; k0 += 32) {
        #pragma unroll
        for (int r = 0; r < 4; ++r) {
            int i = r * 256 + tx;
            int m = i >> 3, k4 = (i & 7) * 4;
            int gr = br + m;
            float4 v = make_float4(0.f, 0.f, 0.f, 0.f);
            if (gr < N) v = *(const float4*)&A[(size_t)gr * K + k0 + k4];
            us4 h, l;
            h.x = f2bf(v.x); l.x = f2bf(v.x - bf2f(h.x));
            h.y = f2bf(v.y); l.y = f2bf(v.y - bf2f(h.y));
            h.z = f2bf(v.z); l.z = f2bf(v.z - bf2f(h.z));
            h.w = f2bf(v.w); l.w = f2bf(v.w - bf2f(h.w));
            *(us4*)&Ah[m * PAD + k4] = h;
            *(us4*)&Al[m * PAD + k4] = l;
        }
        #pragma unroll
        for (int r = 0; r < BN / 32; ++r) {
            int i = r * 256 + tx;
            int k = i & 31;
            int n4 = (i >> 5) * 4;
            const float* bp = &B[(size_t)(k0 + k) * M + bc + n4];
            float4 v = *(const float4*)bp;
            ushort_t h0 = f2bf(v.x), h1 = f2bf(v.y), h2 = f2bf(v.z), h3 = f2bf(v.w);
            Bh[(n4 + 0) * PAD + k] = h0;  Bl[(n4 + 0) * PAD + k] = f2bf(v.x - bf2f(h0));
            Bh[(n4 + 1) * PAD + k] = h1;  Bl[(n4 + 1) * PAD + k] = f2bf(v.y - bf2f(h1));
            Bh[(n4 + 2) * PAD + k] = h2;  Bl[(n4 + 2) * PAD + k] = f2bf(v.z - bf2f(h2));
            Bh[(n4 + 3) * PAD + k] = h3;  Bl[(n4 + 3) * PAD + k] = f2bf(v.w - bf2f(h3));
        }
        __syncthreads();

        short8 afh[FM], afl[FM];
        #pragma unroll
        for (int mi = 0; mi < FM; ++mi) {
            int row = wm + mi * 16 + l16;
            afh[mi] = *(const short8*)&Ah[row * PAD + quad * 8];
            afl[mi] = *(const short8*)&Al[row * PAD + quad * 8];
        }
        #pragma unroll
        for (int ni = 0; ni < FN; ++ni) {
            int row = wn + ni * 16 + l16;
            short8 bfh = *(const short8*)&Bh[row * PAD + quad * 8];
            short8 bfl = *(const short8*)&Bl[row * PAD + quad * 8];
            #pragma unroll
            for (int mi = 0; mi < FM; ++mi) {
                acc[mi][ni] = __builtin_amdgcn_mfma_f32_16x16x32_bf16(afh[mi], bfh, acc[mi][ni], 0, 0, 0);
                acc[mi][ni] = __builtin_amdgcn_mfma_f32_16x16x32_bf16(afh[mi], bfl, acc[mi][ni], 0, 0, 0);
                acc[mi][ni] = __builtin_amdgcn_mfma_f32_16x16x32_bf16(afl[mi], bfh, acc[mi][ni], 0, 0, 0);
            }
        }
        __syncthreads();
    }

    #pragma unroll
    for (int mi = 0; mi < FM; ++mi) {
        #pragma unroll
        for (int ni = 0; ni < FN; ++ni) {
            int gc = bc + wn + ni * 16 + l16;
            if (gc >= M) continue;
            #pragma unroll
            for (int r = 0; r < 4; ++r) {
                int gr = br + wm + mi * 16 + quad * 4 + r;
                if (gr < N) store_out(&C[(size_t)gr * M + gc], acc[mi][ni][r]);
            }
        }
    }
}

// ======== fp16-A 2-pass MFMA GEMM (layers 1/2): A fp16 native, B fp16 hi/lo ========
template <int BN, int WMCNT, int WNCNT, typename TOUT>
__global__ __launch_bounds__(256) void mfma_gemm_f16_k(const __half* __restrict__ A,
                                                       const float* __restrict__ B,
                                                       TOUT* __restrict__ C,
                                                       int N, int K, int M) {
    constexpr int BM = 128;
    constexpr int PAD = 40;
    constexpr int WMX = BM / WMCNT;
    constexpr int WNX = BN / WNCNT;
    constexpr int FM = WMX / 16, FN = WNX / 16;

    __shared__ ushort_t Ah[BM * PAD];
    __shared__ ushort_t Bh[BN * PAD], Bl[BN * PAD];

    const int tx = threadIdx.x;
    const int wave = tx >> 6, lane = tx & 63;
    const int quad = lane >> 4, l16 = lane & 15;
    const int br = blockIdx.y * BM, bc = blockIdx.x * BN;
    const int wm = (wave / WNCNT) * WMX;
    const int wn = (wave % WNCNT) * WNX;

    f32x4 acc[FM][FN] = {};

    for (int k0 = 0; k0 < K; k0 += 32) {
        // ---- stage A: 128x32 fp16 = 4096 halves; 2 rounds x 8 halves/thread ----
        #pragma unroll
        for (int r = 0; r < 2; ++r) {
            int i = r * 256 + tx;
            int m = i >> 2, k8 = (i & 3) * 8;
            int gr = br + m;
            short8 v = {};
            if (gr < N) v = *(const short8*)&A[(size_t)gr * K + k0 + k8];
            *(short8*)&Ah[m * PAD + k8] = v;
        }
        // ---- stage B: fp16 hi/lo split ----
        #pragma unroll
        for (int r = 0; r < BN / 32; ++r) {
            int i = r * 256 + tx;
            int k = i & 31;
            int n4 = (i >> 5) * 4;
            const float* bp = &B[(size_t)(k0 + k) * M + bc + n4];
            float4 v = *(const float4*)bp;
            __half h0 = __float2half(v.x), h1 = __float2half(v.y);
            __half h2 = __float2half(v.z), h3 = __float2half(v.w);
            Bh[(n4 + 0) * PAD + k] = __half_as_ushort(h0);
            Bh[(n4 + 1) * PAD + k] = __half_as_ushort(h1);
            Bh[(n4 + 2) * PAD + k] = __half_as_ushort(h2);
            Bh[(n4 + 3) * PAD + k] = __half_as_ushort(h3);
            Bl[(n4 + 0) * PAD + k] = __half_as_ushort(__float2half(v.x - __half2float(h0)));
            Bl[(n4 + 1) * PAD + k] = __half_as_ushort(__float2half(v.y - __half2float(h1)));
            Bl[(n4 + 2) * PAD + k] = __half_as_ushort(__float2half(v.z - __half2float(h2)));
            Bl[(n4 + 3) * PAD + k] = __half_as_ushort(__float2half(v.w - __half2float(h3)));
        }
        __syncthreads();

        half8 af[FM];
        #pragma unroll
        for (int mi = 0; mi < FM; ++mi) {
            int row = wm + mi * 16 + l16;
            af[mi] = *(const half8*)&Ah[row * PAD + quad * 8];
        }
        #pragma unroll
        for (int ni = 0; ni < FN; ++ni) {
            int row = wn + ni * 16 + l16;
            half8 bfh = *(const half8*)&Bh[row * PAD + quad * 8];
            half8 bfl = *(const half8*)&Bl[row * PAD + quad * 8];
            #pragma unroll
            for (int mi = 0; mi < FM; ++mi) {
                acc[mi][ni] = __builtin_amdgcn_mfma_f32_16x16x32_f16(af[mi], bfh, acc[mi][ni], 0, 0, 0);
                acc[mi][ni] = __builtin_amdgcn_mfma_f32_16x16x32_f16(af[mi], bfl, acc[mi][ni], 0, 0, 0);
            }
        }
        __syncthreads();
    }

    #pragma unroll
    for (int mi = 0; mi < FM; ++mi) {
        #pragma unroll
        for (int ni = 0; ni < FN; ++ni) {
            int gc = bc + wn + ni * 16 + l16;
            if (gc >= M) continue;
            #pragma unroll
            for (int r = 0; r < 4; ++r) {
                int gr = br + wm + mi * 16 + quad * 4 + r;
                if (gr < N) store_out(&C[(size_t)gr * M + gc], acc[mi][ni][r]);
            }
        }
    }
}

// ---- per-node attention logits from fp16 x (H=8, C=32) ----
__global__ void al8_f16_k(const __half* __restrict__ xh, const float* __restrict__ a_s,
                          const float* __restrict__ a_d, float* __restrict__ alS,
                          float* __restrict__ alD, int N) {
    int idx = blockIdx.x * 256 + threadIdx.x;
    if (idx >= N * 8) return;
    int n = idx >> 3, h = idx & 7;
    const __half2* hp = (const __half2*)(xh + (size_t)n * 256 + h * 32);
    const float* as = a_s + h * 32;
    const float* ad = a_d + h * 32;
    float s1 = 0.f, s2 = 0.f;
    #pragma unroll
    for (int c2 = 0; c2 < 16; ++c2) {
        float2 f = __half22float2(hp[c2]);
        s1 += f.x * as[2 * c2] + f.y * as[2 * c2 + 1];
        s2 += f.x * ad[2 * c2] + f.y * ad[2 * c2 + 1];
    }
    alS[idx] = s1;
    alD[idx] = s2;
}

// ---- fp32 logits (layer 2, H=1, C=40) ----
__global__ void al1_k(const float* __restrict__ x, const float* __restrict__ a_s,
                      const float* __restrict__ a_d, float* __restrict__ alS,
                      float* __restrict__ alD, int N) {
    int n = blockIdx.x * 256 + threadIdx.x;
    if (n >= N) return;
    const float* xp = x + (size_t)n * 40;
    float s1 = 0.f, s2 = 0.f;
    for (int c = 0; c < 40; ++c) {
        float v = xp[c];
        s1 += v * a_s[c];
        s2 += v * a_d[c];
    }
    alS[n] = s1;
    alD[n] = s2;
}

// ================= fused per-node softmax + aggregation =================
// H=8, C=32 (HC=256). One wave per destination node. fp16 gather, fp16 out.
__global__ __launch_bounds__(256) void node_aggr8_k(
    const int* __restrict__ rowptr, const int* __restrict__ csr_src,
    const float* __restrict__ alS, const float* __restrict__ alD,
    const __half* __restrict__ xh, const float* __restrict__ bias,
    __half* __restrict__ out, int N, int do_elu) {
    int wid = (blockIdx.x * 256 + threadIdx.x) >> 6;
    int lane = threadIdx.x & 63;
    if (wid >= N) return;
    const int d = wid;
    const int beg = rowptr[d], end = rowptr[d + 1];

    // lane = esub*8 + h
    const int h = lane & 7, esub = lane >> 3;
    const float aDh = alD[d * 8 + h];

    float s = 0.f;
    for (int e = beg + esub; e < end; e += 8) {
        int src = csr_src[e];
        float ev = alS[src * 8 + h] + aDh;
        ev = ev > 0.f ? ev : 0.2f * ev;
        s += __expf(fminf(ev, 30.f));
    }
    #pragma unroll
    for (int off = 8; off < 64; off <<= 1) s += __shfl_xor(s, off);
    const float rs = 1.f / s;

    const int hh = lane >> 3;
    float4 acc = {0.f, 0.f, 0.f, 0.f};
    for (int eb = beg; eb < end; eb += 8) {
        int e = eb + esub;
        int src_l = 0;
        float alpha_l = 0.f;
        if (e < end) {
            src_l = csr_src[e];
            float ev = alS[src_l * 8 + h] + aDh;
            ev = ev > 0.f ? ev : 0.2f * ev;
            alpha_l = __expf(fminf(ev, 30.f)) * rs;
        }
        int cnt = end - eb; if (cnt > 8) cnt = 8;
        for (int j = 0; j < cnt; ++j) {
            int src = __shfl(src_l, j * 8);
            float alpha = __shfl(alpha_l, j * 8 + hh);
            const __half2* hp = (const __half2*)(xh + ((size_t)src << 8) + lane * 4);
            float2 f0 = __half22float2(hp[0]);
            float2 f1 = __half22float2(hp[1]);
            acc.x += f0.x * alpha;
            acc.y += f0.y * alpha;
            acc.z += f1.x * alpha;
            acc.w += f1.y * alpha;
        }
    }
    const float4 bv = *(const float4*)&bias[lane * 4];
    float4 o;
    o.x = acc.x + bv.x; o.y = acc.y + bv.y; o.z = acc.z + bv.z; o.w = acc.w + bv.w;
    if (do_elu) {
        o.x = o.x > 0.f ? o.x : expm1f(o.x);
        o.y = o.y > 0.f ? o.y : expm1f(o.y);
        o.z = o.z > 0.f ? o.z : expm1f(o.z);
        o.w = o.w > 0.f ? o.w : expm1f(o.w);
    }
    __half2* op = (__half2*)(out + ((size_t)d << 8) + lane * 4);
    op[0] = __floats2half2_rn(o.x, o.y);
    op[1] = __floats2half2_rn(o.z, o.w);
}

// H=1, C=40. One wave per node; chunk-of-64 alpha precompute + broadcast gather.
__global__ __launch_bounds__(256) void node_aggr1_k(
    const int* __restrict__ rowptr, const int* __restrict__ csr_src,
    const float* __restrict__ alS, const float* __restrict__ alD,
    const float* __restrict__ x, const float* __restrict__ bias,
    float* __restrict__ out, int N) {
    int wid = (blockIdx.x * 256 + threadIdx.x) >> 6;
    int lane = threadIdx.x & 63;
    if (wid >= N) return;
    const int d = wid;
    const int beg = rowptr[d], end = rowptr[d + 1];
    const float aD = alD[d];

    // sweep 1: direct-exp sum, lane-parallel
    float s = 0.f;
    for (int e = beg + lane; e < end; e += 64) {
        int src = csr_src[e];
        float ev = alS[src] + aD;
        ev = ev > 0.f ? ev : 0.2f * ev;
        s += __expf(fminf(ev, 30.f));
    }
    #pragma unroll
    for (int off = 1; off < 64; off <<= 1) s += __shfl_xor(s, off);
    const float rs = 1.f / s;

    // sweep 2: chunks of 64 edges; alpha computed once per edge across lanes
    float acc = 0.f;
    for (int eb = beg; eb < end; eb += 64) {
        int e = eb + lane;
        int src_l = 0;
        float alpha_l = 0.f;
        if (e < end) {
            src_l = csr_src[e];
            float ev = alS[src_l] + aD;
            ev = ev > 0.f ? ev : 0.2f * ev;
            alpha_l = __expf(fminf(ev, 30.f)) * rs;
        }
        int cnt = end - eb; if (cnt > 64) cnt = 64;
        for (int j = 0; j < cnt; ++j) {
            int src = __shfl(src_l, j);
            float alpha = __shfl(alpha_l, j);
            if (lane < 40) acc += x[(size_t)src * 40 + lane] * alpha;
        }
    }
    if (lane < 40) out[(size_t)d * 40 + lane] = acc + bias[lane];
}

extern "C" void kernel_launch(void* const* d_in, const int* in_sizes, int n_in,
                              void* d_out, int out_size, void* d_ws, size_t ws_size,
                              hipStream_t stream) {
    const float* feat = (const float*)d_in[0];
    const int*   ei   = (const int*)d_in[1];
    const float* W0   = (const float*)d_in[2];
    const float* a0s  = (const float*)d_in[3];
    const float* a0d  = (const float*)d_in[4];
    const float* b0   = (const float*)d_in[5];
    const float* W1   = (const float*)d_in[6];
    const float* a1s  = (const float*)d_in[7];
    const float* a1d  = (const float*)d_in[8];
    const float* b1   = (const float*)d_in[9];
    const float* W2   = (const float*)d_in[10];
    const float* a2s  = (const float*)d_in[11];
    const float* a2d  = (const float*)d_in[12];
    const float* b2   = (const float*)d_in[13];
    float* out = (float*)d_out;

    const int N = in_sizes[0] / 128;   // 100000
    const int E = in_sizes[1] / 2;     // 1600000
    const int Etot = E + N;

    // workspace layout (~132 MB total)
    __half* hbuf = (__half*)d_ws;                     // N*256 fp16 (aggr out / gemm A)
    __half* xh   = hbuf + (size_t)N * 256;            // N*256 fp16 (gemm out, layers 0/1)
    float*  x2   = (float*)(xh + (size_t)N * 256);    // N*40 fp32 (layer-2 gemm out)
    float*  alS  = x2 + (size_t)N * 40;               // N*8
    float*  alD  = alS + (size_t)N * 8;               // N*8
    int* deg      = (int*)(alD + (size_t)N * 8);      // N
    int* rowptr   = deg + N;                          // N+1
    int* cursor   = rowptr + N + 1;                   // N
    int* partials = cursor + N;                       // 512
    int* csr_src  = partials + 512;                   // Etot
    int* flag     = csr_src + Etot;                   // 1

    const int nbN    = (N + 255) / 256;
    const int nb_e   = (Etot + 255) / 256;
    const int nb_nw  = (N + 3) / 4;
    const int nb_nh8 = (N * 8 + 255) / 256;

    // ---- CSR build (once, reused by all 3 layers) ----
    detect64_k<<<1, 1, 0, stream>>>(ei, 512, flag);
    hipMemsetAsync(deg, 0, (size_t)N * 4, stream);
    deg_k<<<nb_e, 256, 0, stream>>>(ei, flag, deg, E, Etot, N);
    scan1_k<<<nbN, 256, 0, stream>>>(deg, rowptr, partials, N);
    scan2_k<<<1, 512, 0, stream>>>(partials, nbN);
    scan3_k<<<nbN, 256, 0, stream>>>(rowptr, cursor, partials, N, Etot);
    scatter_k<<<nb_e, 256, 0, stream>>>(ei, flag, cursor, csr_src, E, Etot, N);

    const int mb = (N + 127) / 128;

    // ---------- Layer 0: Fin=128, H=8, C=32 (fp32 A, 3-pass bf16) ----------
    mfma_gemm_k<128, 2, 2, __half><<<dim3(2, mb), 256, 0, stream>>>(feat, W0, xh, N, 128, 256);
    al8_f16_k<<<nb_nh8, 256, 0, stream>>>(xh, a0s, a0d, alS, alD, N);
    node_aggr8_k<<<nb_nw, 256, 0, stream>>>(rowptr, csr_src, alS, alD, xh, b0,
                                            hbuf, N, 1);   // h1 -> hbuf fp16 (ELU fused)

    // ---------- Layer 1: Fin=256, H=8, C=32 (fp16 A, 2-pass f16) ----------
    mfma_gemm_f16_k<128, 2, 2, __half><<<dim3(2, mb), 256, 0, stream>>>(hbuf, W1, xh, N, 256, 256);
    al8_f16_k<<<nb_nh8, 256, 0, stream>>>(xh, a1s, a1d, alS, alD, N);
    node_aggr8_k<<<nb_nw, 256, 0, stream>>>(rowptr, csr_src, alS, alD, xh, b1,
                                            hbuf, N, 1);   // h2 -> hbuf fp16 (ELU fused)

    // ---------- Layer 2: Fin=256, H=1, C=40 (fp16 A, 2-pass f16) ----------
    mfma_gemm_f16_k<64, 4, 1, float><<<dim3(1, mb), 256, 0, stream>>>(hbuf, W2, x2, N, 256, 40);
    al1_k<<<nbN, 256, 0, stream>>>(x2, a2s, a2d, alS, alD, N);
    node_aggr1_k<<<nb_nw, 256, 0, stream>>>(rowptr, csr_src, alS, alD, x2, b2,
                                            out, N);       // bias fused, direct to out
}

// Round 8
// 968.690 us; speedup vs baseline: 6.9827x; 1.0310x over previous
//
#include <hip/hip_runtime.h>
#include <hip/hip_bf16.h>
#include <hip/hip_fp16.h>
#include <math.h>

typedef __attribute__((ext_vector_type(8))) short short8;
typedef __attribute__((ext_vector_type(8))) _Float16 half8;
typedef __attribute__((ext_vector_type(4))) float f32x4;
typedef unsigned short ushort_t;
struct __align__(8) us4 { ushort_t x, y, z, w; };

// round-to-nearest-even fp32 -> bf16
__device__ __forceinline__ ushort_t f2bf(float f) {
    unsigned u = __float_as_uint(f);
    u += 0x7FFFu + ((u >> 16) & 1u);
    return (ushort_t)(u >> 16);
}
__device__ __forceinline__ float bf2f(ushort_t h) {
    return __uint_as_float(((unsigned)h) << 16);
}

__device__ __forceinline__ void store_out(float* p, float v) { *p = v; }
__device__ __forceinline__ void store_out(__half* p, float v) { *p = __float2half(v); }

// ---- detect whether edge_index is int64 (odd int32 words all zero) ----
__global__ void detect64_k(const int* __restrict__ ei, int n_check, int* __restrict__ flag) {
    if (blockIdx.x == 0 && threadIdx.x == 0) {
        int zeros = 0;
        for (int i = 0; i < n_check; ++i) zeros += (ei[2 * i + 1] == 0) ? 1 : 0;
        *flag = (zeros >= n_check - 2) ? 1 : 0;
    }
}

__device__ __forceinline__ void edge_sd(const int* __restrict__ ei, int e, int E,
                                        int is64, int N, int& s_, int& d_) {
    if (e >= E) { s_ = d_ = e - E; return; }   // self-loops appended
    int s, d;
    if (is64) { s = ei[2 * e]; d = ei[2 * (E + e)]; }
    else      { s = ei[e];     d = ei[E + e]; }
    s_ = ((unsigned)s < (unsigned)N) ? s : 0;
    d_ = ((unsigned)d < (unsigned)N) ? d : 0;
}

// ================= CSR construction =================
__global__ void deg_k(const int* __restrict__ ei, const int* __restrict__ flag,
                      int* __restrict__ deg, int E, int Etot, int N) {
    int e = blockIdx.x * 256 + threadIdx.x;
    if (e >= Etot) return;
    int s_, d_;
    edge_sd(ei, e, E, *flag, N, s_, d_);
    atomicAdd(&deg[d_], 1);
}

__global__ void scan1_k(const int* __restrict__ deg, int* __restrict__ rowptr,
                        int* __restrict__ partials, int N) {
    __shared__ int tmp[256];
    int tx = threadIdx.x, i = blockIdx.x * 256 + tx;
    int v = (i < N) ? deg[i] : 0;
    tmp[tx] = v;
    __syncthreads();
    for (int off = 1; off < 256; off <<= 1) {
        int t = (tx >= off) ? tmp[tx - off] : 0;
        __syncthreads();
        tmp[tx] += t;
        __syncthreads();
    }
    if (i < N) rowptr[i] = tmp[tx] - v;
    if (tx == 255) partials[blockIdx.x] = tmp[255];
}

__global__ void scan2_k(int* __restrict__ partials, int nb) {
    __shared__ int tmp[512];
    int tx = threadIdx.x;
    int v = (tx < nb) ? partials[tx] : 0;
    tmp[tx] = v;
    __syncthreads();
    for (int off = 1; off < 512; off <<= 1) {
        int t = (tx >= off) ? tmp[tx - off] : 0;
        __syncthreads();
        tmp[tx] += t;
        __syncthreads();
    }
    if (tx < nb) partials[tx] = tmp[tx];
}

__global__ void scan3_k(int* __restrict__ rowptr, int* __restrict__ cursor,
                        const int* __restrict__ partials, int N, int Etot) {
    int i = blockIdx.x * 256 + threadIdx.x;
    if (i < N) {
        int off = (blockIdx.x > 0) ? partials[blockIdx.x - 1] : 0;
        int v = rowptr[i] + off;
        rowptr[i] = v;
        cursor[i] = v;
    }
    if (i == 0) rowptr[N] = Etot;
}

__global__ void scatter_k(const int* __restrict__ ei, const int* __restrict__ flag,
                          int* __restrict__ cursor, int* __restrict__ csr_src,
                          int E, int Etot, int N) {
    int e = blockIdx.x * 256 + threadIdx.x;
    if (e >= Etot) return;
    int s_, d_;
    edge_sd(ei, e, E, *flag, N, s_, d_);
    int pos = atomicAdd(&cursor[d_], 1);
    csr_src[pos] = s_;
}

// ================= split-bf16 MFMA GEMM (fp32 A; layer 0) =================
template <int BN, int WMCNT, int WNCNT, typename TOUT>
__global__ __launch_bounds__(256) void mfma_gemm_k(const float* __restrict__ A,
                                                   const float* __restrict__ B,
                                                   TOUT* __restrict__ C,
                                                   int N, int K, int M) {
    constexpr int BM = 128;
    constexpr int PAD = 40;
    constexpr int WMX = BM / WMCNT;
    constexpr int WNX = BN / WNCNT;
    constexpr int FM = WMX / 16, FN = WNX / 16;

    __shared__ ushort_t Ah[BM * PAD], Al[BM * PAD];
    __shared__ ushort_t Bh[BN * PAD], Bl[BN * PAD];

    const int tx = threadIdx.x;
    const int wave = tx >> 6, lane = tx & 63;
    const int quad = lane >> 4, l16 = lane & 15;
    const int br = blockIdx.y * BM, bc = blockIdx.x * BN;
    const int wm = (wave / WNCNT) * WMX;
    const int wn = (wave % WNCNT) * WNX;

    f32x4 acc[FM][FN] = {};

    for (int k0 = 0; k0 < K; k0 += 32) {
        #pragma unroll
        for (int r = 0; r < 4; ++r) {
            int i = r * 256 + tx;
            int m = i >> 3, k4 = (i & 7) * 4;
            int gr = br + m;
            float4 v = make_float4(0.f, 0.f, 0.f, 0.f);
            if (gr < N) v = *(const float4*)&A[(size_t)gr * K + k0 + k4];
            us4 h, l;
            h.x = f2bf(v.x); l.x = f2bf(v.x - bf2f(h.x));
            h.y = f2bf(v.y); l.y = f2bf(v.y - bf2f(h.y));
            h.z = f2bf(v.z); l.z = f2bf(v.z - bf2f(h.z));
            h.w = f2bf(v.w); l.w = f2bf(v.w - bf2f(h.w));
            *(us4*)&Ah[m * PAD + k4] = h;
            *(us4*)&Al[m * PAD + k4] = l;
        }
        #pragma unroll
        for (int r = 0; r < BN / 32; ++r) {
            int i = r * 256 + tx;
            int k = i & 31;
            int n4 = (i >> 5) * 4;
            const float* bp = &B[(size_t)(k0 + k) * M + bc + n4];
            float4 v = *(const float4*)bp;
            ushort_t h0 = f2bf(v.x), h1 = f2bf(v.y), h2 = f2bf(v.z), h3 = f2bf(v.w);
            Bh[(n4 + 0) * PAD + k] = h0;  Bl[(n4 + 0) * PAD + k] = f2bf(v.x - bf2f(h0));
            Bh[(n4 + 1) * PAD + k] = h1;  Bl[(n4 + 1) * PAD + k] = f2bf(v.y - bf2f(h1));
            Bh[(n4 + 2) * PAD + k] = h2;  Bl[(n4 + 2) * PAD + k] = f2bf(v.z - bf2f(h2));
            Bh[(n4 + 3) * PAD + k] = h3;  Bl[(n4 + 3) * PAD + k] = f2bf(v.w - bf2f(h3));
        }
        __syncthreads();

        short8 afh[FM], afl[FM];
        #pragma unroll
        for (int mi = 0; mi < FM; ++mi) {
            int row = wm + mi * 16 + l16;
            afh[mi] = *(const short8*)&Ah[row * PAD + quad * 8];
            afl[mi] = *(const short8*)&Al[row * PAD + quad * 8];
        }
        #pragma unroll
        for (int ni = 0; ni < FN; ++ni) {
            int row = wn + ni * 16 + l16;
            short8 bfh = *(const short8*)&Bh[row * PAD + quad * 8];
            short8 bfl = *(const short8*)&Bl[row * PAD + quad * 8];
            #pragma unroll
            for (int mi = 0; mi < FM; ++mi) {
                acc[mi][ni] = __builtin_amdgcn_mfma_f32_16x16x32_bf16(afh[mi], bfh, acc[mi][ni], 0, 0, 0);
                acc[mi][ni] = __builtin_amdgcn_mfma_f32_16x16x32_bf16(afh[mi], bfl, acc[mi][ni], 0, 0, 0);
                acc[mi][ni] = __builtin_amdgcn_mfma_f32_16x16x32_bf16(afl[mi], bfh, acc[mi][ni], 0, 0, 0);
            }
        }
        __syncthreads();
    }

    #pragma unroll
    for (int mi = 0; mi < FM; ++mi) {
        #pragma unroll
        for (int ni = 0; ni < FN; ++ni) {
            int gc = bc + wn + ni * 16 + l16;
            if (gc >= M) continue;
            #pragma unroll
            for (int r = 0; r < 4; ++r) {
                int gr = br + wm + mi * 16 + quad * 4 + r;
                if (gr < N) store_out(&C[(size_t)gr * M + gc], acc[mi][ni][r]);
            }
        }
    }
}

// ======== fp16-A 2-pass MFMA GEMM (layers 1/2): A fp16 native, B fp16 hi/lo ========
template <int BN, int WMCNT, int WNCNT, typename TOUT>
__global__ __launch_bounds__(256) void mfma_gemm_f16_k(const __half* __restrict__ A,
                                                       const float* __restrict__ B,
                                                       TOUT* __restrict__ C,
                                                       int N, int K, int M) {
    constexpr int BM = 128;
    constexpr int PAD = 40;
    constexpr int WMX = BM / WMCNT;
    constexpr int WNX = BN / WNCNT;
    constexpr int FM = WMX / 16, FN = WNX / 16;

    __shared__ ushort_t Ah[BM * PAD];
    __shared__ ushort_t Bh[BN * PAD], Bl[BN * PAD];

    const int tx = threadIdx.x;
    const int wave = tx >> 6, lane = tx & 63;
    const int quad = lane >> 4, l16 = lane & 15;
    const int br = blockIdx.y * BM, bc = blockIdx.x * BN;
    const int wm = (wave / WNCNT) * WMX;
    const int wn = (wave % WNCNT) * WNX;

    f32x4 acc[FM][FN] = {};

    for (int k0 = 0; k0 < K; k0 += 32) {
        #pragma unroll
        for (int r = 0; r < 2; ++r) {
            int i = r * 256 + tx;
            int m = i >> 2, k8 = (i & 3) * 8;
            int gr = br + m;
            short8 v = {};
            if (gr < N) v = *(const short8*)&A[(size_t)gr * K + k0 + k8];
            *(short8*)&Ah[m * PAD + k8] = v;
        }
        #pragma unroll
        for (int r = 0; r < BN / 32; ++r) {
            int i = r * 256 + tx;
            int k = i & 31;
            int n4 = (i >> 5) * 4;
            const float* bp = &B[(size_t)(k0 + k) * M + bc + n4];
            float4 v = *(const float4*)bp;
            __half h0 = __float2half(v.x), h1 = __float2half(v.y);
            __half h2 = __float2half(v.z), h3 = __float2half(v.w);
            Bh[(n4 + 0) * PAD + k] = __half_as_ushort(h0);
            Bh[(n4 + 1) * PAD + k] = __half_as_ushort(h1);
            Bh[(n4 + 2) * PAD + k] = __half_as_ushort(h2);
            Bh[(n4 + 3) * PAD + k] = __half_as_ushort(h3);
            Bl[(n4 + 0) * PAD + k] = __half_as_ushort(__float2half(v.x - __half2float(h0)));
            Bl[(n4 + 1) * PAD + k] = __half_as_ushort(__float2half(v.y - __half2float(h1)));
            Bl[(n4 + 2) * PAD + k] = __half_as_ushort(__float2half(v.z - __half2float(h2)));
            Bl[(n4 + 3) * PAD + k] = __half_as_ushort(__float2half(v.w - __half2float(h3)));
        }
        __syncthreads();

        half8 af[FM];
        #pragma unroll
        for (int mi = 0; mi < FM; ++mi) {
            int row = wm + mi * 16 + l16;
            af[mi] = *(const half8*)&Ah[row * PAD + quad * 8];
        }
        #pragma unroll
        for (int ni = 0; ni < FN; ++ni) {
            int row = wn + ni * 16 + l16;
            half8 bfh = *(const half8*)&Bh[row * PAD + quad * 8];
            half8 bfl = *(const half8*)&Bl[row * PAD + quad * 8];
            #pragma unroll
            for (int mi = 0; mi < FM; ++mi) {
                acc[mi][ni] = __builtin_amdgcn_mfma_f32_16x16x32_f16(af[mi], bfh, acc[mi][ni], 0, 0, 0);
                acc[mi][ni] = __builtin_amdgcn_mfma_f32_16x16x32_f16(af[mi], bfl, acc[mi][ni], 0, 0, 0);
            }
        }
        __syncthreads();
    }

    #pragma unroll
    for (int mi = 0; mi < FM; ++mi) {
        #pragma unroll
        for (int ni = 0; ni < FN; ++ni) {
            int gc = bc + wn + ni * 16 + l16;
            if (gc >= M) continue;
            #pragma unroll
            for (int r = 0; r < 4; ++r) {
                int gr = br + wm + mi * 16 + quad * 4 + r;
                if (gr < N) store_out(&C[(size_t)gr * M + gc], acc[mi][ni][r]);
            }
        }
    }
}

// ---- per-node attention logits from fp16 x (H=8, C=32) ----
__global__ void al8_f16_k(const __half* __restrict__ xh, const float* __restrict__ a_s,
                          const float* __restrict__ a_d, float* __restrict__ alS,
                          float* __restrict__ alD, int N) {
    int idx = blockIdx.x * 256 + threadIdx.x;
    if (idx >= N * 8) return;
    int n = idx >> 3, h = idx & 7;
    const __half2* hp = (const __half2*)(xh + (size_t)n * 256 + h * 32);
    const float* as = a_s + h * 32;
    const float* ad = a_d + h * 32;
    float s1 = 0.f, s2 = 0.f;
    #pragma unroll
    for (int c2 = 0; c2 < 16; ++c2) {
        float2 f = __half22float2(hp[c2]);
        s1 += f.x * as[2 * c2] + f.y * as[2 * c2 + 1];
        s2 += f.x * ad[2 * c2] + f.y * ad[2 * c2 + 1];
    }
    alS[idx] = s1;
    alD[idx] = s2;
}

// ---- fp32 logits (layer 2, H=1, C=40) ----
__global__ void al1_k(const float* __restrict__ x, const float* __restrict__ a_s,
                      const float* __restrict__ a_d, float* __restrict__ alS,
                      float* __restrict__ alD, int N) {
    int n = blockIdx.x * 256 + threadIdx.x;
    if (n >= N) return;
    const float* xp = x + (size_t)n * 40;
    float s1 = 0.f, s2 = 0.f;
    for (int c = 0; c < 40; ++c) {
        float v = xp[c];
        s1 += v * a_s[c];
        s2 += v * a_d[c];
    }
    alS[n] = s1;
    alD[n] = s2;
}

// ================= fused per-node softmax + aggregation =================
// H=8, C=32 (HC=256). One wave per destination node. fp16 gather, fp16 out.
// Sweep 1 caches (src, exp) per chunk in registers (deg<=64 fast path);
// sweep 2 broadcasts from the cache — no re-read, no re-exp.
__global__ __launch_bounds__(256) void node_aggr8_k(
    const int* __restrict__ rowptr, const int* __restrict__ csr_src,
    const float* __restrict__ alS, const float* __restrict__ alD,
    const __half* __restrict__ xh, const float* __restrict__ bias,
    __half* __restrict__ out, int N, int do_elu) {
    int wid = (blockIdx.x * 256 + threadIdx.x) >> 6;
    int lane = threadIdx.x & 63;
    if (wid >= N) return;
    const int d = wid;
    const int beg = rowptr[d], end = rowptr[d + 1];
    const int deg = end - beg;

    const int h = lane & 7, esub = lane >> 3;
    const float aDh = alD[d * 8 + h];

    constexpr int CH = 8;                 // cached chunks of 8 edges (deg<=64)
    float evc[CH]; int srcc[CH];
    const int nch = (deg + 7) >> 3;
    const int cch = nch < CH ? nch : CH;

    float s = 0.f;
    for (int c = 0; c < cch; ++c) {
        int e = beg + c * 8 + esub;
        float ex = 0.f; int src = 0;
        if (e < end) {
            src = csr_src[e];
            float ev = alS[src * 8 + h] + aDh;
            ev = ev > 0.f ? ev : 0.2f * ev;
            ex = __expf(fminf(ev, 30.f));
        }
        srcc[c] = src; evc[c] = ex;
        s += ex;
    }
    for (int c = CH; c < nch; ++c) {      // overflow (deg>64): recompute path
        int e = beg + c * 8 + esub;
        if (e < end) {
            int src = csr_src[e];
            float ev = alS[src * 8 + h] + aDh;
            ev = ev > 0.f ? ev : 0.2f * ev;
            s += __expf(fminf(ev, 30.f));
        }
    }
    #pragma unroll
    for (int off = 8; off < 64; off <<= 1) s += __shfl_xor(s, off);

    const int hh = lane >> 3;             // head owned in gather phase
    const float rs = __shfl(1.f / s, hh); // lane 'hh' has h==hh
    float4 acc = {0.f, 0.f, 0.f, 0.f};

    for (int c = 0; c < cch; ++c) {
        int base = beg + c * 8;
        int cnt = end - base; if (cnt > 8) cnt = 8;
        for (int j = 0; j < cnt; ++j) {
            int src = __shfl(srcc[c], j * 8);
            float alpha = __shfl(evc[c], j * 8 + hh) * rs;
            float2 raw = *(const float2*)(xh + ((size_t)src << 8) + lane * 4);
            float2 f0 = __half22float2(*(const __half2*)&raw.x);
            float2 f1 = __half22float2(*(const __half2*)&raw.y);
            acc.x += f0.x * alpha;
            acc.y += f0.y * alpha;
            acc.z += f1.x * alpha;
            acc.w += f1.y * alpha;
        }
    }
    for (int c = CH; c < nch; ++c) {      // overflow gather: recompute alphas
        int base = beg + c * 8;
        int e = base + esub;
        int src_l = 0; float ex_l = 0.f;
        if (e < end) {
            src_l = csr_src[e];
            float ev = alS[src_l * 8 + h] + aDh;
            ev = ev > 0.f ? ev : 0.2f * ev;
            ex_l = __expf(fminf(ev, 30.f));
        }
        int cnt = end - base; if (cnt > 8) cnt = 8;
        for (int j = 0; j < cnt; ++j) {
            int src = __shfl(src_l, j * 8);
            float alpha = __shfl(ex_l, j * 8 + hh) * rs;
            float2 raw = *(const float2*)(xh + ((size_t)src << 8) + lane * 4);
            float2 f0 = __half22float2(*(const __half2*)&raw.x);
            float2 f1 = __half22float2(*(const __half2*)&raw.y);
            acc.x += f0.x * alpha;
            acc.y += f0.y * alpha;
            acc.z += f1.x * alpha;
            acc.w += f1.y * alpha;
        }
    }

    const float4 bv = *(const float4*)&bias[lane * 4];
    float4 o;
    o.x = acc.x + bv.x; o.y = acc.y + bv.y; o.z = acc.z + bv.z; o.w = acc.w + bv.w;
    if (do_elu) {
        o.x = o.x > 0.f ? o.x : expm1f(o.x);
        o.y = o.y > 0.f ? o.y : expm1f(o.y);
        o.z = o.z > 0.f ? o.z : expm1f(o.z);
        o.w = o.w > 0.f ? o.w : expm1f(o.w);
    }
    __half2* op = (__half2*)(out + ((size_t)d << 8) + lane * 4);
    op[0] = __floats2half2_rn(o.x, o.y);
    op[1] = __floats2half2_rn(o.z, o.w);
}

// H=1, C=40. One wave per node; first 64 edges cached from sweep 1.
__global__ __launch_bounds__(256) void node_aggr1_k(
    const int* __restrict__ rowptr, const int* __restrict__ csr_src,
    const float* __restrict__ alS, const float* __restrict__ alD,
    const float* __restrict__ x, const float* __restrict__ bias,
    float* __restrict__ out, int N) {
    int wid = (blockIdx.x * 256 + threadIdx.x) >> 6;
    int lane = threadIdx.x & 63;
    if (wid >= N) return;
    const int d = wid;
    const int beg = rowptr[d], end = rowptr[d + 1];
    const float aD = alD[d];

    // sweep 1: cache first chunk (deg<=64 covers ~all nodes)
    int src0 = 0; float ex0 = 0.f;
    {
        int e = beg + lane;
        if (e < end) {
            src0 = csr_src[e];
            float ev = alS[src0] + aD;
            ev = ev > 0.f ? ev : 0.2f * ev;
            ex0 = __expf(fminf(ev, 30.f));
        }
    }
    float s = ex0;
    for (int e = beg + 64 + lane; e < end; e += 64) {
        int src = csr_src[e];
        float ev = alS[src] + aD;
        ev = ev > 0.f ? ev : 0.2f * ev;
        s += __expf(fminf(ev, 30.f));
    }
    #pragma unroll
    for (int off = 1; off < 64; off <<= 1) s += __shfl_xor(s, off);
    const float rs = 1.f / s;

    float acc = 0.f;
    // cached chunk
    {
        int cnt = end - beg; if (cnt > 64) cnt = 64;
        for (int j = 0; j < cnt; ++j) {
            int src = __shfl(src0, j);
            float alpha = __shfl(ex0, j) * rs;
            if (lane < 40) acc += x[(size_t)src * 40 + lane] * alpha;
        }
    }
    // overflow chunks
    for (int eb = beg + 64; eb < end; eb += 64) {
        int e = eb + lane;
        int src_l = 0; float ex_l = 0.f;
        if (e < end) {
            src_l = csr_src[e];
            float ev = alS[src_l] + aD;
            ev = ev > 0.f ? ev : 0.2f * ev;
            ex_l = __expf(fminf(ev, 30.f));
        }
        int cnt = end - eb; if (cnt > 64) cnt = 64;
        for (int j = 0; j < cnt; ++j) {
            int src = __shfl(src_l, j);
            float alpha = __shfl(ex_l, j) * rs;
            if (lane < 40) acc += x[(size_t)src * 40 + lane] * alpha;
        }
    }
    if (lane < 40) out[(size_t)d * 40 + lane] = acc + bias[lane];
}

extern "C" void kernel_launch(void* const* d_in, const int* in_sizes, int n_in,
                              void* d_out, int out_size, void* d_ws, size_t ws_size,
                              hipStream_t stream) {
    const float* feat = (const float*)d_in[0];
    const int*   ei   = (const int*)d_in[1];
    const float* W0   = (const float*)d_in[2];
    const float* a0s  = (const float*)d_in[3];
    const float* a0d  = (const float*)d_in[4];
    const float* b0   = (const float*)d_in[5];
    const float* W1   = (const float*)d_in[6];
    const float* a1s  = (const float*)d_in[7];
    const float* a1d  = (const float*)d_in[8];
    const float* b1   = (const float*)d_in[9];
    const float* W2   = (const float*)d_in[10];
    const float* a2s  = (const float*)d_in[11];
    const float* a2d  = (const float*)d_in[12];
    const float* b2   = (const float*)d_in[13];
    float* out = (float*)d_out;

    const int N = in_sizes[0] / 128;   // 100000
    const int E = in_sizes[1] / 2;     // 1600000
    const int Etot = E + N;

    // workspace layout (~132 MB total)
    __half* hbuf = (__half*)d_ws;                     // N*256 fp16 (aggr out / gemm A)
    __half* xh   = hbuf + (size_t)N * 256;            // N*256 fp16 (gemm out, layers 0/1)
    float*  x2   = (float*)(xh + (size_t)N * 256);    // N*40 fp32 (layer-2 gemm out)
    float*  alS  = x2 + (size_t)N * 40;               // N*8
    float*  alD  = alS + (size_t)N * 8;               // N*8
    int* deg      = (int*)(alD + (size_t)N * 8);      // N
    int* rowptr   = deg + N;                          // N+1
    int* cursor   = rowptr + N + 1;                   // N
    int* partials = cursor + N;                       // 512
    int* csr_src  = partials + 512;                   // Etot
    int* flag     = csr_src + Etot;                   // 1

    const int nbN    = (N + 255) / 256;
    const int nb_e   = (Etot + 255) / 256;
    const int nb_nw  = (N + 3) / 4;
    const int nb_nh8 = (N * 8 + 255) / 256;

    // ---- CSR build (once, reused by all 3 layers) ----
    detect64_k<<<1, 1, 0, stream>>>(ei, 512, flag);
    hipMemsetAsync(deg, 0, (size_t)N * 4, stream);
    deg_k<<<nb_e, 256, 0, stream>>>(ei, flag, deg, E, Etot, N);
    scan1_k<<<nbN, 256, 0, stream>>>(deg, rowptr, partials, N);
    scan2_k<<<1, 512, 0, stream>>>(partials, nbN);
    scan3_k<<<nbN, 256, 0, stream>>>(rowptr, cursor, partials, N, Etot);
    scatter_k<<<nb_e, 256, 0, stream>>>(ei, flag, cursor, csr_src, E, Etot, N);

    const int mb = (N + 127) / 128;

    // ---------- Layer 0: Fin=128, H=8, C=32 (fp32 A, 3-pass bf16) ----------
    mfma_gemm_k<128, 2, 2, __half><<<dim3(2, mb), 256, 0, stream>>>(feat, W0, xh, N, 128, 256);
    al8_f16_k<<<nb_nh8, 256, 0, stream>>>(xh, a0s, a0d, alS, alD, N);
    node_aggr8_k<<<nb_nw, 256, 0, stream>>>(rowptr, csr_src, alS, alD, xh, b0,
                                            hbuf, N, 1);   // h1 -> hbuf fp16 (ELU fused)

    // ---------- Layer 1: Fin=256, H=8, C=32 (fp16 A, 2-pass f16) ----------
    mfma_gemm_f16_k<128, 2, 2, __half><<<dim3(2, mb), 256, 0, stream>>>(hbuf, W1, xh, N, 256, 256);
    al8_f16_k<<<nb_nh8, 256, 0, stream>>>(xh, a1s, a1d, alS, alD, N);
    node_aggr8_k<<<nb_nw, 256, 0, stream>>>(rowptr, csr_src, alS, alD, xh, b1,
                                            hbuf, N, 1);   // h2 -> hbuf fp16 (ELU fused)

    // ---------- Layer 2: Fin=256, H=1, C=40 (fp16 A, 2-pass f16) ----------
    mfma_gemm_f16_k<64, 4, 1, float><<<dim3(1, mb), 256, 0, stream>>>(hbuf, W2, x2, N, 256, 40);
    al1_k<<<nbN, 256, 0, stream>>>(x2, a2s, a2d, alS, alD, N);
    node_aggr1_k<<<nb_nw, 256, 0, stream>>>(rowptr, csr_src, alS, alD, x2, b2,
                                            out, N);       // bias fused, direct to out
}

// Round 9
// 922.906 us; speedup vs baseline: 7.3291x; 1.0496x over previous
//
#include <hip/hip_runtime.h>
#include <hip/hip_bf16.h>
#include <hip/hip_fp16.h>
#include <math.h>

typedef __attribute__((ext_vector_type(8))) short short8;
typedef __attribute__((ext_vector_type(8))) _Float16 half8;
typedef __attribute__((ext_vector_type(4))) float f32x4;
typedef unsigned short ushort_t;
struct __align__(8) us4 { ushort_t x, y, z, w; };

// round-to-nearest-even fp32 -> bf16
__device__ __forceinline__ ushort_t f2bf(float f) {
    unsigned u = __float_as_uint(f);
    u += 0x7FFFu + ((u >> 16) & 1u);
    return (ushort_t)(u >> 16);
}
__device__ __forceinline__ float bf2f(ushort_t h) {
    return __uint_as_float(((unsigned)h) << 16);
}

__device__ __forceinline__ void store_out(float* p, float v) { *p = v; }
__device__ __forceinline__ void store_out(__half* p, float v) { *p = __float2half(v); }

// ---- detect whether edge_index is int64 (odd int32 words all zero) ----
__global__ void detect64_k(const int* __restrict__ ei, int n_check, int* __restrict__ flag) {
    if (blockIdx.x == 0 && threadIdx.x == 0) {
        int zeros = 0;
        for (int i = 0; i < n_check; ++i) zeros += (ei[2 * i + 1] == 0) ? 1 : 0;
        *flag = (zeros >= n_check - 2) ? 1 : 0;
    }
}

__device__ __forceinline__ void edge_sd(const int* __restrict__ ei, int e, int E,
                                        int is64, int N, int& s_, int& d_) {
    if (e >= E) { s_ = d_ = e - E; return; }   // self-loops appended
    int s, d;
    if (is64) { s = ei[2 * e]; d = ei[2 * (E + e)]; }
    else      { s = ei[e];     d = ei[E + e]; }
    s_ = ((unsigned)s < (unsigned)N) ? s : 0;
    d_ = ((unsigned)d < (unsigned)N) ? d : 0;
}

// ================= CSR construction =================
__global__ void deg_k(const int* __restrict__ ei, const int* __restrict__ flag,
                      int* __restrict__ deg, int E, int Etot, int N) {
    int e = blockIdx.x * 256 + threadIdx.x;
    if (e >= Etot) return;
    int s_, d_;
    edge_sd(ei, e, E, *flag, N, s_, d_);
    atomicAdd(&deg[d_], 1);
}

__global__ void scan1_k(const int* __restrict__ deg, int* __restrict__ rowptr,
                        int* __restrict__ partials, int N) {
    __shared__ int tmp[256];
    int tx = threadIdx.x, i = blockIdx.x * 256 + tx;
    int v = (i < N) ? deg[i] : 0;
    tmp[tx] = v;
    __syncthreads();
    for (int off = 1; off < 256; off <<= 1) {
        int t = (tx >= off) ? tmp[tx - off] : 0;
        __syncthreads();
        tmp[tx] += t;
        __syncthreads();
    }
    if (i < N) rowptr[i] = tmp[tx] - v;
    if (tx == 255) partials[blockIdx.x] = tmp[255];
}

__global__ void scan2_k(int* __restrict__ partials, int nb) {
    __shared__ int tmp[512];
    int tx = threadIdx.x;
    int v = (tx < nb) ? partials[tx] : 0;
    tmp[tx] = v;
    __syncthreads();
    for (int off = 1; off < 512; off <<= 1) {
        int t = (tx >= off) ? tmp[tx - off] : 0;
        __syncthreads();
        tmp[tx] += t;
        __syncthreads();
    }
    if (tx < nb) partials[tx] = tmp[tx];
}

__global__ void scan3_k(int* __restrict__ rowptr, int* __restrict__ cursor,
                        const int* __restrict__ partials, int N, int Etot) {
    int i = blockIdx.x * 256 + threadIdx.x;
    if (i < N) {
        int off = (blockIdx.x > 0) ? partials[blockIdx.x - 1] : 0;
        int v = rowptr[i] + off;
        rowptr[i] = v;
        cursor[i] = v;
    }
    if (i == 0) rowptr[N] = Etot;
}

__global__ void scatter_k(const int* __restrict__ ei, const int* __restrict__ flag,
                          int* __restrict__ cursor, int* __restrict__ csr_src,
                          int E, int Etot, int N) {
    int e = blockIdx.x * 256 + threadIdx.x;
    if (e >= Etot) return;
    int s_, d_;
    edge_sd(ei, e, E, *flag, N, s_, d_);
    int pos = atomicAdd(&cursor[d_], 1);
    csr_src[pos] = s_;
}

// ===== fused-logit epilogue helpers (WNX must be 64 -> FN == 4) =====
// LMODE 1: H=8,C=32 (each (node,head) owned by exactly one (block,wave) -> plain store)
// LMODE 2: H=1, M<=64 full row per block -> plain store

// ================= split-bf16 MFMA GEMM (fp32 A; layer 0) =================
template <int BN, int WMCNT, int WNCNT, typename TOUT, int LMODE>
__global__ __launch_bounds__(256) void mfma_gemm_k(const float* __restrict__ A,
                                                   const float* __restrict__ B,
                                                   TOUT* __restrict__ C,
                                                   int N, int K, int M,
                                                   const float* __restrict__ a_s,
                                                   const float* __restrict__ a_d,
                                                   float* __restrict__ alS,
                                                   float* __restrict__ alD) {
    constexpr int BM = 128;
    constexpr int PAD = 40;
    constexpr int WMX = BM / WMCNT;
    constexpr int WNX = BN / WNCNT;
    constexpr int FM = WMX / 16, FN = WNX / 16;
    static_assert(FN == 4, "logit epilogue assumes WNX==64");

    __shared__ ushort_t Ah[BM * PAD], Al[BM * PAD];
    __shared__ ushort_t Bh[BN * PAD], Bl[BN * PAD];

    const int tx = threadIdx.x;
    const int wave = tx >> 6, lane = tx & 63;
    const int quad = lane >> 4, l16 = lane & 15;
    const int br = blockIdx.y * BM, bc = blockIdx.x * BN;
    const int wm = (wave / WNCNT) * WMX;
    const int wn = (wave % WNCNT) * WNX;

    f32x4 acc[FM][FN] = {};

    for (int k0 = 0; k0 < K; k0 += 32) {
        #pragma unroll
        for (int r = 0; r < 4; ++r) {
            int i = r * 256 + tx;
            int m = i >> 3, k4 = (i & 7) * 4;
            int gr = br + m;
            float4 v = make_float4(0.f, 0.f, 0.f, 0.f);
            if (gr < N) v = *(const float4*)&A[(size_t)gr * K + k0 + k4];
            us4 h, l;
            h.x = f2bf(v.x); l.x = f2bf(v.x - bf2f(h.x));
            h.y = f2bf(v.y); l.y = f2bf(v.y - bf2f(h.y));
            h.z = f2bf(v.z); l.z = f2bf(v.z - bf2f(h.z));
            h.w = f2bf(v.w); l.w = f2bf(v.w - bf2f(h.w));
            *(us4*)&Ah[m * PAD + k4] = h;
            *(us4*)&Al[m * PAD + k4] = l;
        }
        #pragma unroll
        for (int r = 0; r < BN / 32; ++r) {
            int i = r * 256 + tx;
            int k = i & 31;
            int n4 = (i >> 5) * 4;
            const float* bp = &B[(size_t)(k0 + k) * M + bc + n4];
            float4 v = make_float4(0.f, 0.f, 0.f, 0.f);
            if (bc + n4 + 3 < M) {
                v = *(const float4*)bp;
            } else {
                if (bc + n4 + 0 < M) v.x = bp[0];
                if (bc + n4 + 1 < M) v.y = bp[1];
                if (bc + n4 + 2 < M) v.z = bp[2];
                if (bc + n4 + 3 < M) v.w = bp[3];
            }
            ushort_t h0 = f2bf(v.x), h1 = f2bf(v.y), h2 = f2bf(v.z), h3 = f2bf(v.w);
            Bh[(n4 + 0) * PAD + k] = h0;  Bl[(n4 + 0) * PAD + k] = f2bf(v.x - bf2f(h0));
            Bh[(n4 + 1) * PAD + k] = h1;  Bl[(n4 + 1) * PAD + k] = f2bf(v.y - bf2f(h1));
            Bh[(n4 + 2) * PAD + k] = h2;  Bl[(n4 + 2) * PAD + k] = f2bf(v.z - bf2f(h2));
            Bh[(n4 + 3) * PAD + k] = h3;  Bl[(n4 + 3) * PAD + k] = f2bf(v.w - bf2f(h3));
        }
        __syncthreads();

        short8 afh[FM], afl[FM];
        #pragma unroll
        for (int mi = 0; mi < FM; ++mi) {
            int row = wm + mi * 16 + l16;
            afh[mi] = *(const short8*)&Ah[row * PAD + quad * 8];
            afl[mi] = *(const short8*)&Al[row * PAD + quad * 8];
        }
        #pragma unroll
        for (int ni = 0; ni < FN; ++ni) {
            int row = wn + ni * 16 + l16;
            short8 bfh = *(const short8*)&Bh[row * PAD + quad * 8];
            short8 bfl = *(const short8*)&Bl[row * PAD + quad * 8];
            #pragma unroll
            for (int mi = 0; mi < FM; ++mi) {
                acc[mi][ni] = __builtin_amdgcn_mfma_f32_16x16x32_bf16(afh[mi], bfh, acc[mi][ni], 0, 0, 0);
                acc[mi][ni] = __builtin_amdgcn_mfma_f32_16x16x32_bf16(afh[mi], bfl, acc[mi][ni], 0, 0, 0);
                acc[mi][ni] = __builtin_amdgcn_mfma_f32_16x16x32_bf16(afl[mi], bfh, acc[mi][ni], 0, 0, 0);
            }
        }
        __syncthreads();
    }

    #pragma unroll
    for (int mi = 0; mi < FM; ++mi) {
        #pragma unroll
        for (int ni = 0; ni < FN; ++ni) {
            int gc = bc + wn + ni * 16 + l16;
            if (gc >= M) continue;
            #pragma unroll
            for (int r = 0; r < 4; ++r) {
                int gr = br + wm + mi * 16 + quad * 4 + r;
                if (gr < N) store_out(&C[(size_t)gr * M + gc], acc[mi][ni][r]);
            }
        }
    }

    // ---- fused logits ----
    float aSv[FN], aDv[FN];
    #pragma unroll
    for (int ni = 0; ni < FN; ++ni) {
        int gc = bc + wn + ni * 16 + l16;
        bool ok = gc < M;
        aSv[ni] = ok ? a_s[gc] : 0.f;
        aDv[ni] = ok ? a_d[gc] : 0.f;
    }
    if (LMODE == 1) {
        #pragma unroll
        for (int mi = 0; mi < FM; ++mi) {
            #pragma unroll
            for (int r = 0; r < 4; ++r) {
                float p1a = acc[mi][0][r] * aSv[0] + acc[mi][1][r] * aSv[1];
                float p1b = acc[mi][2][r] * aSv[2] + acc[mi][3][r] * aSv[3];
                float p2a = acc[mi][0][r] * aDv[0] + acc[mi][1][r] * aDv[1];
                float p2b = acc[mi][2][r] * aDv[2] + acc[mi][3][r] * aDv[3];
                #pragma unroll
                for (int off = 1; off < 16; off <<= 1) {
                    p1a += __shfl_xor(p1a, off);
                    p1b += __shfl_xor(p1b, off);
                    p2a += __shfl_xor(p2a, off);
                    p2b += __shfl_xor(p2b, off);
                }
                if (l16 == 0) {
                    int gr = br + wm + mi * 16 + quad * 4 + r;
                    if (gr < N) {
                        int hb = (bc + wn) >> 5;
                        alS[gr * 8 + hb]     = p1a;
                        alS[gr * 8 + hb + 1] = p1b;
                        alD[gr * 8 + hb]     = p2a;
                        alD[gr * 8 + hb + 1] = p2b;
                    }
                }
            }
        }
    } else {
        #pragma unroll
        for (int mi = 0; mi < FM; ++mi) {
            #pragma unroll
            for (int r = 0; r < 4; ++r) {
                float p1 = acc[mi][0][r] * aSv[0] + acc[mi][1][r] * aSv[1]
                         + acc[mi][2][r] * aSv[2] + acc[mi][3][r] * aSv[3];
                float p2 = acc[mi][0][r] * aDv[0] + acc[mi][1][r] * aDv[1]
                         + acc[mi][2][r] * aDv[2] + acc[mi][3][r] * aDv[3];
                #pragma unroll
                for (int off = 1; off < 16; off <<= 1) {
                    p1 += __shfl_xor(p1, off);
                    p2 += __shfl_xor(p2, off);
                }
                if (l16 == 0) {
                    int gr = br + wm + mi * 16 + quad * 4 + r;
                    if (gr < N) { alS[gr] = p1; alD[gr] = p2; }
                }
            }
        }
    }
}

// ======== fp16-A 2-pass MFMA GEMM (layers 1/2): A fp16 native, B fp16 hi/lo ========
template <int BN, int WMCNT, int WNCNT, typename TOUT, int LMODE>
__global__ __launch_bounds__(256) void mfma_gemm_f16_k(const __half* __restrict__ A,
                                                       const float* __restrict__ B,
                                                       TOUT* __restrict__ C,
                                                       int N, int K, int M,
                                                       const float* __restrict__ a_s,
                                                       const float* __restrict__ a_d,
                                                       float* __restrict__ alS,
                                                       float* __restrict__ alD) {
    constexpr int BM = 128;
    constexpr int PAD = 40;
    constexpr int WMX = BM / WMCNT;
    constexpr int WNX = BN / WNCNT;
    constexpr int FM = WMX / 16, FN = WNX / 16;
    static_assert(FN == 4, "logit epilogue assumes WNX==64");

    __shared__ ushort_t Ah[BM * PAD];
    __shared__ ushort_t Bh[BN * PAD], Bl[BN * PAD];

    const int tx = threadIdx.x;
    const int wave = tx >> 6, lane = tx & 63;
    const int quad = lane >> 4, l16 = lane & 15;
    const int br = blockIdx.y * BM, bc = blockIdx.x * BN;
    const int wm = (wave / WNCNT) * WMX;
    const int wn = (wave % WNCNT) * WNX;

    f32x4 acc[FM][FN] = {};

    for (int k0 = 0; k0 < K; k0 += 32) {
        #pragma unroll
        for (int r = 0; r < 2; ++r) {
            int i = r * 256 + tx;
            int m = i >> 2, k8 = (i & 3) * 8;
            int gr = br + m;
            short8 v = {};
            if (gr < N) v = *(const short8*)&A[(size_t)gr * K + k0 + k8];
            *(short8*)&Ah[m * PAD + k8] = v;
        }
        #pragma unroll
        for (int r = 0; r < BN / 32; ++r) {
            int i = r * 256 + tx;
            int k = i & 31;
            int n4 = (i >> 5) * 4;
            const float* bp = &B[(size_t)(k0 + k) * M + bc + n4];
            float4 v = make_float4(0.f, 0.f, 0.f, 0.f);
            if (bc + n4 + 3 < M) {
                v = *(const float4*)bp;
            } else {
                if (bc + n4 + 0 < M) v.x = bp[0];
                if (bc + n4 + 1 < M) v.y = bp[1];
                if (bc + n4 + 2 < M) v.z = bp[2];
                if (bc + n4 + 3 < M) v.w = bp[3];
            }
            __half h0 = __float2half(v.x), h1 = __float2half(v.y);
            __half h2 = __float2half(v.z), h3 = __float2half(v.w);
            Bh[(n4 + 0) * PAD + k] = __half_as_ushort(h0);
            Bh[(n4 + 1) * PAD + k] = __half_as_ushort(h1);
            Bh[(n4 + 2) * PAD + k] = __half_as_ushort(h2);
            Bh[(n4 + 3) * PAD + k] = __half_as_ushort(h3);
            Bl[(n4 + 0) * PAD + k] = __half_as_ushort(__float2half(v.x - __half2float(h0)));
            Bl[(n4 + 1) * PAD + k] = __half_as_ushort(__float2half(v.y - __half2float(h1)));
            Bl[(n4 + 2) * PAD + k] = __half_as_ushort(__float2half(v.z - __half2float(h2)));
            Bl[(n4 + 3) * PAD + k] = __half_as_ushort(__float2half(v.w - __half2float(h3)));
        }
        __syncthreads();

        half8 af[FM];
        #pragma unroll
        for (int mi = 0; mi < FM; ++mi) {
            int row = wm + mi * 16 + l16;
            af[mi] = *(const half8*)&Ah[row * PAD + quad * 8];
        }
        #pragma unroll
        for (int ni = 0; ni < FN; ++ni) {
            int row = wn + ni * 16 + l16;
            half8 bfh = *(const half8*)&Bh[row * PAD + quad * 8];
            half8 bfl = *(const half8*)&Bl[row * PAD + quad * 8];
            #pragma unroll
            for (int mi = 0; mi < FM; ++mi) {
                acc[mi][ni] = __builtin_amdgcn_mfma_f32_16x16x32_f16(af[mi], bfh, acc[mi][ni], 0, 0, 0);
                acc[mi][ni] = __builtin_amdgcn_mfma_f32_16x16x32_f16(af[mi], bfl, acc[mi][ni], 0, 0, 0);
            }
        }
        __syncthreads();
    }

    #pragma unroll
    for (int mi = 0; mi < FM; ++mi) {
        #pragma unroll
        for (int ni = 0; ni < FN; ++ni) {
            int gc = bc + wn + ni * 16 + l16;
            if (gc >= M) continue;
            #pragma unroll
            for (int r = 0; r < 4; ++r) {
                int gr = br + wm + mi * 16 + quad * 4 + r;
                if (gr < N) store_out(&C[(size_t)gr * M + gc], acc[mi][ni][r]);
            }
        }
    }

    // ---- fused logits ----
    float aSv[FN], aDv[FN];
    #pragma unroll
    for (int ni = 0; ni < FN; ++ni) {
        int gc = bc + wn + ni * 16 + l16;
        bool ok = gc < M;
        aSv[ni] = ok ? a_s[gc] : 0.f;
        aDv[ni] = ok ? a_d[gc] : 0.f;
    }
    if (LMODE == 1) {
        #pragma unroll
        for (int mi = 0; mi < FM; ++mi) {
            #pragma unroll
            for (int r = 0; r < 4; ++r) {
                float p1a = acc[mi][0][r] * aSv[0] + acc[mi][1][r] * aSv[1];
                float p1b = acc[mi][2][r] * aSv[2] + acc[mi][3][r] * aSv[3];
                float p2a = acc[mi][0][r] * aDv[0] + acc[mi][1][r] * aDv[1];
                float p2b = acc[mi][2][r] * aDv[2] + acc[mi][3][r] * aDv[3];
                #pragma unroll
                for (int off = 1; off < 16; off <<= 1) {
                    p1a += __shfl_xor(p1a, off);
                    p1b += __shfl_xor(p1b, off);
                    p2a += __shfl_xor(p2a, off);
                    p2b += __shfl_xor(p2b, off);
                }
                if (l16 == 0) {
                    int gr = br + wm + mi * 16 + quad * 4 + r;
                    if (gr < N) {
                        int hb = (bc + wn) >> 5;
                        alS[gr * 8 + hb]     = p1a;
                        alS[gr * 8 + hb + 1] = p1b;
                        alD[gr * 8 + hb]     = p2a;
                        alD[gr * 8 + hb + 1] = p2b;
                    }
                }
            }
        }
    } else {
        #pragma unroll
        for (int mi = 0; mi < FM; ++mi) {
            #pragma unroll
            for (int r = 0; r < 4; ++r) {
                float p1 = acc[mi][0][r] * aSv[0] + acc[mi][1][r] * aSv[1]
                         + acc[mi][2][r] * aSv[2] + acc[mi][3][r] * aSv[3];
                float p2 = acc[mi][0][r] * aDv[0] + acc[mi][1][r] * aDv[1]
                         + acc[mi][2][r] * aDv[2] + acc[mi][3][r] * aDv[3];
                #pragma unroll
                for (int off = 1; off < 16; off <<= 1) {
                    p1 += __shfl_xor(p1, off);
                    p2 += __shfl_xor(p2, off);
                }
                if (l16 == 0) {
                    int gr = br + wm + mi * 16 + quad * 4 + r;
                    if (gr < N) { alS[gr] = p1; alD[gr] = p2; }
                }
            }
        }
    }
}

// ================= fused per-node softmax + aggregation =================
// H=8, C=32 (HC=256). One wave per node. Sweep 1 caches (src,exp) in regs;
// sweep 2 processes 2 edges/step: lane parity p owns edges j=2t+p, each lane
// loads 16 B (8 halves of channel group lane&31); parity accs merged at end.
__global__ __launch_bounds__(256) void node_aggr8_k(
    const int* __restrict__ rowptr, const int* __restrict__ csr_src,
    const float* __restrict__ alS, const float* __restrict__ alD,
    const __half* __restrict__ xh, const float* __restrict__ bias,
    __half* __restrict__ out, int N, int do_elu) {
    int wid = (blockIdx.x * 256 + threadIdx.x) >> 6;
    int lane = threadIdx.x & 63;
    if (wid >= N) return;
    const int d = wid;
    const int beg = rowptr[d], end = rowptr[d + 1];
    const int deg = end - beg;

    const int h = lane & 7, esub = lane >> 3;
    const float aDh = alD[d * 8 + h];

    constexpr int CH = 8;                 // cached chunks of 8 edges (deg<=64)
    float evc[CH]; int srcc[CH];
    const int nch = (deg + 7) >> 3;
    const int cch = nch < CH ? nch : CH;

    float s = 0.f;
    for (int c = 0; c < cch; ++c) {
        int e = beg + c * 8 + esub;
        float ex = 0.f; int src = 0;
        if (e < end) {
            src = csr_src[e];
            float ev = alS[src * 8 + h] + aDh;
            ev = ev > 0.f ? ev : 0.2f * ev;
            ex = __expf(fminf(ev, 30.f));
        }
        srcc[c] = src; evc[c] = ex;
        s += ex;
    }
    for (int c = CH; c < nch; ++c) {      // overflow (deg>64)
        int e = beg + c * 8 + esub;
        if (e < end) {
            int src = csr_src[e];
            float ev = alS[src * 8 + h] + aDh;
            ev = ev > 0.f ? ev : 0.2f * ev;
            s += __expf(fminf(ev, 30.f));
        }
    }
    #pragma unroll
    for (int off = 8; off < 64; off <<= 1) s += __shfl_xor(s, off);

    const int g = lane & 31;              // channel group: channels g*8..g*8+7
    const int hh = g >> 2;                // head of this channel group
    const int p = lane >> 5;              // edge parity
    const float rs = __shfl(1.f / s, hh);
    float acc[8] = {};

    for (int c = 0; c < cch; ++c) {
        int base = beg + c * 8;
        int cnt = end - base; if (cnt > 8) cnt = 8;
        int steps = (cnt + 1) >> 1;
        for (int t = 0; t < steps; ++t) {
            int j = t * 2 + p;
            int jc = j < cnt ? j : (cnt - 1);
            int src = __shfl(srcc[c], jc * 8);
            float alpha = __shfl(evc[c], jc * 8 + hh) * rs;
            if (j >= cnt) alpha = 0.f;
            const float4 raw = *(const float4*)(xh + ((size_t)src << 8) + g * 8);
            const __half2* hp = (const __half2*)&raw;
            float2 f0 = __half22float2(hp[0]);
            float2 f1 = __half22float2(hp[1]);
            float2 f2 = __half22float2(hp[2]);
            float2 f3 = __half22float2(hp[3]);
            acc[0] += f0.x * alpha; acc[1] += f0.y * alpha;
            acc[2] += f1.x * alpha; acc[3] += f1.y * alpha;
            acc[4] += f2.x * alpha; acc[5] += f2.y * alpha;
            acc[6] += f3.x * alpha; acc[7] += f3.y * alpha;
        }
    }
    for (int c = CH; c < nch; ++c) {      // overflow gather (recompute)
        int base = beg + c * 8;
        int e = base + esub;
        int src_l = 0; float ex_l = 0.f;
        if (e < end) {
            src_l = csr_src[e];
            float ev = alS[src_l * 8 + h] + aDh;
            ev = ev > 0.f ? ev : 0.2f * ev;
            ex_l = __expf(fminf(ev, 30.f));
        }
        int cnt = end - base; if (cnt > 8) cnt = 8;
        int steps = (cnt + 1) >> 1;
        for (int t = 0; t < steps; ++t) {
            int j = t * 2 + p;
            int jc = j < cnt ? j : (cnt - 1);
            int src = __shfl(src_l, jc * 8);
            float alpha = __shfl(ex_l, jc * 8 + hh) * rs;
            if (j >= cnt) alpha = 0.f;
            const float4 raw = *(const float4*)(xh + ((size_t)src << 8) + g * 8);
            const __half2* hp = (const __half2*)&raw;
            float2 f0 = __half22float2(hp[0]);
            float2 f1 = __half22float2(hp[1]);
            float2 f2 = __half22float2(hp[2]);
            float2 f3 = __half22float2(hp[3]);
            acc[0] += f0.x * alpha; acc[1] += f0.y * alpha;
            acc[2] += f1.x * alpha; acc[3] += f1.y * alpha;
            acc[4] += f2.x * alpha; acc[5] += f2.y * alpha;
            acc[6] += f3.x * alpha; acc[7] += f3.y * alpha;
        }
    }

    #pragma unroll
    for (int k = 0; k < 8; ++k) acc[k] += __shfl_xor(acc[k], 32);

    if (p == 0) {
        const float4 bv0 = *(const float4*)&bias[g * 8];
        const float4 bv1 = *(const float4*)&bias[g * 8 + 4];
        float o[8];
        o[0] = acc[0] + bv0.x; o[1] = acc[1] + bv0.y;
        o[2] = acc[2] + bv0.z; o[3] = acc[3] + bv0.w;
        o[4] = acc[4] + bv1.x; o[5] = acc[5] + bv1.y;
        o[6] = acc[6] + bv1.z; o[7] = acc[7] + bv1.w;
        if (do_elu) {
            #pragma unroll
            for (int k = 0; k < 8; ++k) o[k] = o[k] > 0.f ? o[k] : expm1f(o[k]);
        }
        float4 st;
        ((__half2*)&st)[0] = __floats2half2_rn(o[0], o[1]);
        ((__half2*)&st)[1] = __floats2half2_rn(o[2], o[3]);
        ((__half2*)&st)[2] = __floats2half2_rn(o[4], o[5]);
        ((__half2*)&st)[3] = __floats2half2_rn(o[6], o[7]);
        *(float4*)(out + ((size_t)d << 8) + g * 8) = st;
    }
}

// H=1, C=40. One wave per node; fp16 gather; first 64 edges cached.
__global__ __launch_bounds__(256) void node_aggr1_k(
    const int* __restrict__ rowptr, const int* __restrict__ csr_src,
    const float* __restrict__ alS, const float* __restrict__ alD,
    const __half* __restrict__ xh2, const float* __restrict__ bias,
    float* __restrict__ out, int N) {
    int wid = (blockIdx.x * 256 + threadIdx.x) >> 6;
    int lane = threadIdx.x & 63;
    if (wid >= N) return;
    const int d = wid;
    const int beg = rowptr[d], end = rowptr[d + 1];
    const float aD = alD[d];

    int src0 = 0; float ex0 = 0.f;
    {
        int e = beg + lane;
        if (e < end) {
            src0 = csr_src[e];
            float ev = alS[src0] + aD;
            ev = ev > 0.f ? ev : 0.2f * ev;
            ex0 = __expf(fminf(ev, 30.f));
        }
    }
    float s = ex0;
    for (int e = beg + 64 + lane; e < end; e += 64) {
        int src = csr_src[e];
        float ev = alS[src] + aD;
        ev = ev > 0.f ? ev : 0.2f * ev;
        s += __expf(fminf(ev, 30.f));
    }
    #pragma unroll
    for (int off = 1; off < 64; off <<= 1) s += __shfl_xor(s, off);
    const float rs = 1.f / s;

    float acc = 0.f;
    {
        int cnt = end - beg; if (cnt > 64) cnt = 64;
        for (int j = 0; j < cnt; ++j) {
            int src = __shfl(src0, j);
            float alpha = __shfl(ex0, j) * rs;
            if (lane < 40) acc += __half2float(xh2[(size_t)src * 40 + lane]) * alpha;
        }
    }
    for (int eb = beg + 64; eb < end; eb += 64) {
        int e = eb + lane;
        int src_l = 0; float ex_l = 0.f;
        if (e < end) {
            src_l = csr_src[e];
            float ev = alS[src_l] + aD;
            ev = ev > 0.f ? ev : 0.2f * ev;
            ex_l = __expf(fminf(ev, 30.f));
        }
        int cnt = end - eb; if (cnt > 64) cnt = 64;
        for (int j = 0; j < cnt; ++j) {
            int src = __shfl(src_l, j);
            float alpha = __shfl(ex_l, j) * rs;
            if (lane < 40) acc += __half2float(xh2[(size_t)src * 40 + lane]) * alpha;
        }
    }
    if (lane < 40) out[(size_t)d * 40 + lane] = acc + bias[lane];
}

extern "C" void kernel_launch(void* const* d_in, const int* in_sizes, int n_in,
                              void* d_out, int out_size, void* d_ws, size_t ws_size,
                              hipStream_t stream) {
    const float* feat = (const float*)d_in[0];
    const int*   ei   = (const int*)d_in[1];
    const float* W0   = (const float*)d_in[2];
    const float* a0s  = (const float*)d_in[3];
    const float* a0d  = (const float*)d_in[4];
    const float* b0   = (const float*)d_in[5];
    const float* W1   = (const float*)d_in[6];
    const float* a1s  = (const float*)d_in[7];
    const float* a1d  = (const float*)d_in[8];
    const float* b1   = (const float*)d_in[9];
    const float* W2   = (const float*)d_in[10];
    const float* a2s  = (const float*)d_in[11];
    const float* a2d  = (const float*)d_in[12];
    const float* b2   = (const float*)d_in[13];
    float* out = (float*)d_out;

    const int N = in_sizes[0] / 128;   // 100000
    const int E = in_sizes[1] / 2;     // 1600000
    const int Etot = E + N;

    // workspace layout (~125 MB total)
    __half* hbuf = (__half*)d_ws;                     // N*256 fp16 (aggr out / gemm A)
    __half* xh   = hbuf + (size_t)N * 256;            // N*256 fp16 (gemm out, layers 0/1)
    __half* x2h  = xh + (size_t)N * 256;              // N*40 fp16 (layer-2 gemm out)
    float*  alS  = (float*)(x2h + (size_t)N * 40);    // N*8
    float*  alD  = alS + (size_t)N * 8;               // N*8
    int* deg      = (int*)(alD + (size_t)N * 8);      // N
    int* rowptr   = deg + N;                          // N+1
    int* cursor   = rowptr + N + 1;                   // N
    int* partials = cursor + N;                       // 512
    int* csr_src  = partials + 512;                   // Etot
    int* flag     = csr_src + Etot;                   // 1

    const int nbN    = (N + 255) / 256;
    const int nb_e   = (Etot + 255) / 256;
    const int nb_nw  = (N + 3) / 4;

    // ---- CSR build (once, reused by all 3 layers) ----
    detect64_k<<<1, 1, 0, stream>>>(ei, 512, flag);
    hipMemsetAsync(deg, 0, (size_t)N * 4, stream);
    deg_k<<<nb_e, 256, 0, stream>>>(ei, flag, deg, E, Etot, N);
    scan1_k<<<nbN, 256, 0, stream>>>(deg, rowptr, partials, N);
    scan2_k<<<1, 512, 0, stream>>>(partials, nbN);
    scan3_k<<<nbN, 256, 0, stream>>>(rowptr, cursor, partials, N, Etot);
    scatter_k<<<nb_e, 256, 0, stream>>>(ei, flag, cursor, csr_src, E, Etot, N);

    const int mb = (N + 127) / 128;

    // ---------- Layer 0: Fin=128, H=8, C=32 (fp32 A, 3-pass bf16, fused logits) ----------
    mfma_gemm_k<128, 2, 2, __half, 1><<<dim3(2, mb), 256, 0, stream>>>(
        feat, W0, xh, N, 128, 256, a0s, a0d, alS, alD);
    node_aggr8_k<<<nb_nw, 256, 0, stream>>>(rowptr, csr_src, alS, alD, xh, b0,
                                            hbuf, N, 1);   // h1 -> hbuf fp16 (ELU fused)

    // ---------- Layer 1: Fin=256, H=8, C=32 (fp16 A, 2-pass f16, fused logits) ----------
    mfma_gemm_f16_k<128, 2, 2, __half, 1><<<dim3(2, mb), 256, 0, stream>>>(
        hbuf, W1, xh, N, 256, 256, a1s, a1d, alS, alD);
    node_aggr8_k<<<nb_nw, 256, 0, stream>>>(rowptr, csr_src, alS, alD, xh, b1,
                                            hbuf, N, 1);   // h2 -> hbuf fp16 (ELU fused)

    // ---------- Layer 2: Fin=256, H=1, C=40 (fp16 A, fused logits, fp16 x2) ----------
    mfma_gemm_f16_k<64, 4, 1, __half, 2><<<dim3(1, mb), 256, 0, stream>>>(
        hbuf, W2, x2h, N, 256, 40, a2s, a2d, alS, alD);
    node_aggr1_k<<<nb_nw, 256, 0, stream>>>(rowptr, csr_src, alS, alD, x2h, b2,
                                            out, N);       // bias fused, direct to out
}

// Round 10
// 888.965 us; speedup vs baseline: 7.6089x; 1.0382x over previous
//
#include <hip/hip_runtime.h>
#include <hip/hip_bf16.h>
#include <hip/hip_fp16.h>
#include <math.h>

typedef __attribute__((ext_vector_type(8))) short short8;
typedef __attribute__((ext_vector_type(8))) _Float16 half8;
typedef __attribute__((ext_vector_type(4))) float f32x4;
typedef unsigned short ushort_t;
struct __align__(8) us4 { ushort_t x, y, z, w; };

// round-to-nearest-even fp32 -> bf16
__device__ __forceinline__ ushort_t f2bf(float f) {
    unsigned u = __float_as_uint(f);
    u += 0x7FFFu + ((u >> 16) & 1u);
    return (ushort_t)(u >> 16);
}
__device__ __forceinline__ float bf2f(ushort_t h) {
    return __uint_as_float(((unsigned)h) << 16);
}

__device__ __forceinline__ void store_out(float* p, float v) { *p = v; }
__device__ __forceinline__ void store_out(__half* p, float v) { *p = __float2half(v); }

// ---- detect whether edge_index is int64 (odd int32 words all zero) ----
__global__ void detect64_k(const int* __restrict__ ei, int n_check, int* __restrict__ flag) {
    if (blockIdx.x == 0 && threadIdx.x == 0) {
        int zeros = 0;
        for (int i = 0; i < n_check; ++i) zeros += (ei[2 * i + 1] == 0) ? 1 : 0;
        *flag = (zeros >= n_check - 2) ? 1 : 0;
    }
}

__device__ __forceinline__ void edge_sd(const int* __restrict__ ei, int e, int E,
                                        int is64, int N, int& s_, int& d_) {
    if (e >= E) { s_ = d_ = e - E; return; }   // self-loops appended
    int s, d;
    if (is64) { s = ei[2 * e]; d = ei[2 * (E + e)]; }
    else      { s = ei[e];     d = ei[E + e]; }
    s_ = ((unsigned)s < (unsigned)N) ? s : 0;
    d_ = ((unsigned)d < (unsigned)N) ? d : 0;
}

// ================= CSR construction =================
__global__ void deg_k(const int* __restrict__ ei, const int* __restrict__ flag,
                      int* __restrict__ deg, int E, int Etot, int N) {
    int e = blockIdx.x * 256 + threadIdx.x;
    if (e >= Etot) return;
    int s_, d_;
    edge_sd(ei, e, E, *flag, N, s_, d_);
    atomicAdd(&deg[d_], 1);
}

__global__ void scan1_k(const int* __restrict__ deg, int* __restrict__ rowptr,
                        int* __restrict__ partials, int N) {
    __shared__ int tmp[256];
    int tx = threadIdx.x, i = blockIdx.x * 256 + tx;
    int v = (i < N) ? deg[i] : 0;
    tmp[tx] = v;
    __syncthreads();
    for (int off = 1; off < 256; off <<= 1) {
        int t = (tx >= off) ? tmp[tx - off] : 0;
        __syncthreads();
        tmp[tx] += t;
        __syncthreads();
    }
    if (i < N) rowptr[i] = tmp[tx] - v;
    if (tx == 255) partials[blockIdx.x] = tmp[255];
}

__global__ void scan2_k(int* __restrict__ partials, int nb) {
    __shared__ int tmp[512];
    int tx = threadIdx.x;
    int v = (tx < nb) ? partials[tx] : 0;
    tmp[tx] = v;
    __syncthreads();
    for (int off = 1; off < 512; off <<= 1) {
        int t = (tx >= off) ? tmp[tx - off] : 0;
        __syncthreads();
        tmp[tx] += t;
        __syncthreads();
    }
    if (tx < nb) partials[tx] = tmp[tx];
}

__global__ void scan3_k(int* __restrict__ rowptr, int* __restrict__ cursor,
                        const int* __restrict__ partials, int N, int Etot) {
    int i = blockIdx.x * 256 + threadIdx.x;
    if (i < N) {
        int off = (blockIdx.x > 0) ? partials[blockIdx.x - 1] : 0;
        int v = rowptr[i] + off;
        rowptr[i] = v;
        cursor[i] = v;
    }
    if (i == 0) rowptr[N] = Etot;
}

__global__ void scatter_k(const int* __restrict__ ei, const int* __restrict__ flag,
                          int* __restrict__ cursor, int* __restrict__ csr_src,
                          int E, int Etot, int N) {
    int e = blockIdx.x * 256 + threadIdx.x;
    if (e >= Etot) return;
    int s_, d_;
    edge_sd(ei, e, E, *flag, N, s_, d_);
    int pos = atomicAdd(&cursor[d_], 1);
    csr_src[pos] = s_;
}

// ===== weight pre-split (transposed [n][k], zero-padded to Mp rows) =====
__global__ void splitw_bf16_k(const float* __restrict__ W, ushort_t* __restrict__ Wh,
                              ushort_t* __restrict__ Wl, int K, int M, int Mp) {
    int i = blockIdx.x * 256 + threadIdx.x;
    if (i >= Mp * K) return;
    int n = i / K, k = i - n * K;
    float v = (n < M) ? W[(size_t)k * M + n] : 0.f;
    ushort_t h = f2bf(v);
    Wh[i] = h;
    Wl[i] = f2bf(v - bf2f(h));
}

__global__ void splitw_f16_k(const float* __restrict__ W, ushort_t* __restrict__ Wh,
                             ushort_t* __restrict__ Wl, int K, int M, int Mp) {
    int i = blockIdx.x * 256 + threadIdx.x;
    if (i >= Mp * K) return;
    int n = i / K, k = i - n * K;
    float v = (n < M) ? W[(size_t)k * M + n] : 0.f;
    __half h = __float2half(v);
    Wh[i] = __half_as_ushort(h);
    Wl[i] = __half_as_ushort(__float2half(v - __half2float(h)));
}

// ================= split-bf16 MFMA GEMM (fp32 A; layer 0) =================
// B pre-split/transposed: BhT/BlT [Mp][K] bf16 bits.
template <int BN, int WMCNT, int WNCNT, typename TOUT, int LMODE>
__global__ __launch_bounds__(256) void mfma_gemm_k(const float* __restrict__ A,
                                                   const ushort_t* __restrict__ BhT,
                                                   const ushort_t* __restrict__ BlT,
                                                   TOUT* __restrict__ C,
                                                   int N, int K, int M,
                                                   const float* __restrict__ a_s,
                                                   const float* __restrict__ a_d,
                                                   float* __restrict__ alS,
                                                   float* __restrict__ alD) {
    constexpr int BM = 128;
    constexpr int PAD = 40;
    constexpr int WMX = BM / WMCNT;
    constexpr int WNX = BN / WNCNT;
    constexpr int FM = WMX / 16, FN = WNX / 16;
    static_assert(FN == 4, "logit epilogue assumes WNX==64");

    __shared__ ushort_t Ah[BM * PAD], Al[BM * PAD];
    __shared__ ushort_t Bh[BN * PAD], Bl[BN * PAD];

    const int tx = threadIdx.x;
    const int wave = tx >> 6, lane = tx & 63;
    const int quad = lane >> 4, l16 = lane & 15;
    const int br = blockIdx.y * BM, bc = blockIdx.x * BN;
    const int wm = (wave / WNCNT) * WMX;
    const int wn = (wave % WNCNT) * WNX;

    f32x4 acc[FM][FN] = {};

    for (int k0 = 0; k0 < K; k0 += 32) {
        #pragma unroll
        for (int r = 0; r < 4; ++r) {
            int i = r * 256 + tx;
            int m = i >> 3, k4 = (i & 7) * 4;
            int gr = br + m;
            float4 v = make_float4(0.f, 0.f, 0.f, 0.f);
            if (gr < N) v = *(const float4*)&A[(size_t)gr * K + k0 + k4];
            us4 h, l;
            h.x = f2bf(v.x); l.x = f2bf(v.x - bf2f(h.x));
            h.y = f2bf(v.y); l.y = f2bf(v.y - bf2f(h.y));
            h.z = f2bf(v.z); l.z = f2bf(v.z - bf2f(h.z));
            h.w = f2bf(v.w); l.w = f2bf(v.w - bf2f(h.w));
            *(us4*)&Ah[m * PAD + k4] = h;
            *(us4*)&Al[m * PAD + k4] = l;
        }
        // B staging: pure 16B copies from pre-split transposed weights
        #pragma unroll
        for (int r = 0; r < BN / 64; ++r) {
            int i = r * 256 + tx;
            int n = i >> 2, k8 = (i & 3) * 8;
            *(short8*)&Bh[n * PAD + k8] = *(const short8*)&BhT[(size_t)(bc + n) * K + k0 + k8];
            *(short8*)&Bl[n * PAD + k8] = *(const short8*)&BlT[(size_t)(bc + n) * K + k0 + k8];
        }
        __syncthreads();

        short8 afh[FM], afl[FM];
        #pragma unroll
        for (int mi = 0; mi < FM; ++mi) {
            int row = wm + mi * 16 + l16;
            afh[mi] = *(const short8*)&Ah[row * PAD + quad * 8];
            afl[mi] = *(const short8*)&Al[row * PAD + quad * 8];
        }
        #pragma unroll
        for (int ni = 0; ni < FN; ++ni) {
            int row = wn + ni * 16 + l16;
            short8 bfh = *(const short8*)&Bh[row * PAD + quad * 8];
            short8 bfl = *(const short8*)&Bl[row * PAD + quad * 8];
            #pragma unroll
            for (int mi = 0; mi < FM; ++mi) {
                acc[mi][ni] = __builtin_amdgcn_mfma_f32_16x16x32_bf16(afh[mi], bfh, acc[mi][ni], 0, 0, 0);
                acc[mi][ni] = __builtin_amdgcn_mfma_f32_16x16x32_bf16(afh[mi], bfl, acc[mi][ni], 0, 0, 0);
                acc[mi][ni] = __builtin_amdgcn_mfma_f32_16x16x32_bf16(afl[mi], bfh, acc[mi][ni], 0, 0, 0);
            }
        }
        __syncthreads();
    }

    #pragma unroll
    for (int mi = 0; mi < FM; ++mi) {
        #pragma unroll
        for (int ni = 0; ni < FN; ++ni) {
            int gc = bc + wn + ni * 16 + l16;
            if (gc >= M) continue;
            #pragma unroll
            for (int r = 0; r < 4; ++r) {
                int gr = br + wm + mi * 16 + quad * 4 + r;
                if (gr < N) store_out(&C[(size_t)gr * M + gc], acc[mi][ni][r]);
            }
        }
    }

    // ---- fused logits ----
    float aSv[FN], aDv[FN];
    #pragma unroll
    for (int ni = 0; ni < FN; ++ni) {
        int gc = bc + wn + ni * 16 + l16;
        bool ok = gc < M;
        aSv[ni] = ok ? a_s[gc] : 0.f;
        aDv[ni] = ok ? a_d[gc] : 0.f;
    }
    if (LMODE == 1) {
        #pragma unroll
        for (int mi = 0; mi < FM; ++mi) {
            #pragma unroll
            for (int r = 0; r < 4; ++r) {
                float p1a = acc[mi][0][r] * aSv[0] + acc[mi][1][r] * aSv[1];
                float p1b = acc[mi][2][r] * aSv[2] + acc[mi][3][r] * aSv[3];
                float p2a = acc[mi][0][r] * aDv[0] + acc[mi][1][r] * aDv[1];
                float p2b = acc[mi][2][r] * aDv[2] + acc[mi][3][r] * aDv[3];
                #pragma unroll
                for (int off = 1; off < 16; off <<= 1) {
                    p1a += __shfl_xor(p1a, off);
                    p1b += __shfl_xor(p1b, off);
                    p2a += __shfl_xor(p2a, off);
                    p2b += __shfl_xor(p2b, off);
                }
                if (l16 == 0) {
                    int gr = br + wm + mi * 16 + quad * 4 + r;
                    if (gr < N) {
                        int hb = (bc + wn) >> 5;
                        alS[gr * 8 + hb]     = p1a;
                        alS[gr * 8 + hb + 1] = p1b;
                        alD[gr * 8 + hb]     = p2a;
                        alD[gr * 8 + hb + 1] = p2b;
                    }
                }
            }
        }
    } else {
        #pragma unroll
        for (int mi = 0; mi < FM; ++mi) {
            #pragma unroll
            for (int r = 0; r < 4; ++r) {
                float p1 = acc[mi][0][r] * aSv[0] + acc[mi][1][r] * aSv[1]
                         + acc[mi][2][r] * aSv[2] + acc[mi][3][r] * aSv[3];
                float p2 = acc[mi][0][r] * aDv[0] + acc[mi][1][r] * aDv[1]
                         + acc[mi][2][r] * aDv[2] + acc[mi][3][r] * aDv[3];
                #pragma unroll
                for (int off = 1; off < 16; off <<= 1) {
                    p1 += __shfl_xor(p1, off);
                    p2 += __shfl_xor(p2, off);
                }
                if (l16 == 0) {
                    int gr = br + wm + mi * 16 + quad * 4 + r;
                    if (gr < N) { alS[gr] = p1; alD[gr] = p2; }
                }
            }
        }
    }
}

// ======== fp16-A 2-pass MFMA GEMM (layers 1/2): A fp16, B pre-split fp16 hi/lo ========
template <int BN, int WMCNT, int WNCNT, typename TOUT, int LMODE>
__global__ __launch_bounds__(256) void mfma_gemm_f16_k(const __half* __restrict__ A,
                                                       const ushort_t* __restrict__ BhT,
                                                       const ushort_t* __restrict__ BlT,
                                                       TOUT* __restrict__ C,
                                                       int N, int K, int M,
                                                       const float* __restrict__ a_s,
                                                       const float* __restrict__ a_d,
                                                       float* __restrict__ alS,
                                                       float* __restrict__ alD) {
    constexpr int BM = 128;
    constexpr int PAD = 40;
    constexpr int WMX = BM / WMCNT;
    constexpr int WNX = BN / WNCNT;
    constexpr int FM = WMX / 16, FN = WNX / 16;
    static_assert(FN == 4, "logit epilogue assumes WNX==64");

    __shared__ ushort_t Ah[BM * PAD];
    __shared__ ushort_t Bh[BN * PAD], Bl[BN * PAD];

    const int tx = threadIdx.x;
    const int wave = tx >> 6, lane = tx & 63;
    const int quad = lane >> 4, l16 = lane & 15;
    const int br = blockIdx.y * BM, bc = blockIdx.x * BN;
    const int wm = (wave / WNCNT) * WMX;
    const int wn = (wave % WNCNT) * WNX;

    f32x4 acc[FM][FN] = {};

    for (int k0 = 0; k0 < K; k0 += 32) {
        #pragma unroll
        for (int r = 0; r < 2; ++r) {
            int i = r * 256 + tx;
            int m = i >> 2, k8 = (i & 3) * 8;
            int gr = br + m;
            short8 v = {};
            if (gr < N) v = *(const short8*)&A[(size_t)gr * K + k0 + k8];
            *(short8*)&Ah[m * PAD + k8] = v;
        }
        #pragma unroll
        for (int r = 0; r < BN / 64; ++r) {
            int i = r * 256 + tx;
            int n = i >> 2, k8 = (i & 3) * 8;
            *(short8*)&Bh[n * PAD + k8] = *(const short8*)&BhT[(size_t)(bc + n) * K + k0 + k8];
            *(short8*)&Bl[n * PAD + k8] = *(const short8*)&BlT[(size_t)(bc + n) * K + k0 + k8];
        }
        __syncthreads();

        half8 af[FM];
        #pragma unroll
        for (int mi = 0; mi < FM; ++mi) {
            int row = wm + mi * 16 + l16;
            af[mi] = *(const half8*)&Ah[row * PAD + quad * 8];
        }
        #pragma unroll
        for (int ni = 0; ni < FN; ++ni) {
            int row = wn + ni * 16 + l16;
            half8 bfh = *(const half8*)&Bh[row * PAD + quad * 8];
            half8 bfl = *(const half8*)&Bl[row * PAD + quad * 8];
            #pragma unroll
            for (int mi = 0; mi < FM; ++mi) {
                acc[mi][ni] = __builtin_amdgcn_mfma_f32_16x16x32_f16(af[mi], bfh, acc[mi][ni], 0, 0, 0);
                acc[mi][ni] = __builtin_amdgcn_mfma_f32_16x16x32_f16(af[mi], bfl, acc[mi][ni], 0, 0, 0);
            }
        }
        __syncthreads();
    }

    #pragma unroll
    for (int mi = 0; mi < FM; ++mi) {
        #pragma unroll
        for (int ni = 0; ni < FN; ++ni) {
            int gc = bc + wn + ni * 16 + l16;
            if (gc >= M) continue;
            #pragma unroll
            for (int r = 0; r < 4; ++r) {
                int gr = br + wm + mi * 16 + quad * 4 + r;
                if (gr < N) store_out(&C[(size_t)gr * M + gc], acc[mi][ni][r]);
            }
        }
    }

    // ---- fused logits ----
    float aSv[FN], aDv[FN];
    #pragma unroll
    for (int ni = 0; ni < FN; ++ni) {
        int gc = bc + wn + ni * 16 + l16;
        bool ok = gc < M;
        aSv[ni] = ok ? a_s[gc] : 0.f;
        aDv[ni] = ok ? a_d[gc] : 0.f;
    }
    if (LMODE == 1) {
        #pragma unroll
        for (int mi = 0; mi < FM; ++mi) {
            #pragma unroll
            for (int r = 0; r < 4; ++r) {
                float p1a = acc[mi][0][r] * aSv[0] + acc[mi][1][r] * aSv[1];
                float p1b = acc[mi][2][r] * aSv[2] + acc[mi][3][r] * aSv[3];
                float p2a = acc[mi][0][r] * aDv[0] + acc[mi][1][r] * aDv[1];
                float p2b = acc[mi][2][r] * aDv[2] + acc[mi][3][r] * aDv[3];
                #pragma unroll
                for (int off = 1; off < 16; off <<= 1) {
                    p1a += __shfl_xor(p1a, off);
                    p1b += __shfl_xor(p1b, off);
                    p2a += __shfl_xor(p2a, off);
                    p2b += __shfl_xor(p2b, off);
                }
                if (l16 == 0) {
                    int gr = br + wm + mi * 16 + quad * 4 + r;
                    if (gr < N) {
                        int hb = (bc + wn) >> 5;
                        alS[gr * 8 + hb]     = p1a;
                        alS[gr * 8 + hb + 1] = p1b;
                        alD[gr * 8 + hb]     = p2a;
                        alD[gr * 8 + hb + 1] = p2b;
                    }
                }
            }
        }
    } else {
        #pragma unroll
        for (int mi = 0; mi < FM; ++mi) {
            #pragma unroll
            for (int r = 0; r < 4; ++r) {
                float p1 = acc[mi][0][r] * aSv[0] + acc[mi][1][r] * aSv[1]
                         + acc[mi][2][r] * aSv[2] + acc[mi][3][r] * aSv[3];
                float p2 = acc[mi][0][r] * aDv[0] + acc[mi][1][r] * aDv[1]
                         + acc[mi][2][r] * aDv[2] + acc[mi][3][r] * aDv[3];
                #pragma unroll
                for (int off = 1; off < 16; off <<= 1) {
                    p1 += __shfl_xor(p1, off);
                    p2 += __shfl_xor(p2, off);
                }
                if (l16 == 0) {
                    int gr = br + wm + mi * 16 + quad * 4 + r;
                    if (gr < N) { alS[gr] = p1; alD[gr] = p2; }
                }
            }
        }
    }
}

// ================= fused per-node softmax + aggregation =================
// H=8, C=32. One wave per node. Sweep 1 caches (src,exp); sweep 2: 2 edges/step
// (lane parity), 16 B loads, packed-fp16 FMA accumulate (alpha<=1 so bounded).
__global__ __launch_bounds__(256) void node_aggr8_k(
    const int* __restrict__ rowptr, const int* __restrict__ csr_src,
    const float* __restrict__ alS, const float* __restrict__ alD,
    const __half* __restrict__ xh, const float* __restrict__ bias,
    __half* __restrict__ out, int N, int do_elu) {
    int wid = (blockIdx.x * 256 + threadIdx.x) >> 6;
    int lane = threadIdx.x & 63;
    if (wid >= N) return;
    const int d = wid;
    const int beg = rowptr[d], end = rowptr[d + 1];
    const int deg = end - beg;

    const int h = lane & 7, esub = lane >> 3;
    const float aDh = alD[d * 8 + h];

    constexpr int CH = 8;                 // cached chunks of 8 edges (deg<=64)
    float evc[CH]; int srcc[CH];
    const int nch = (deg + 7) >> 3;
    const int cch = nch < CH ? nch : CH;

    float s = 0.f;
    for (int c = 0; c < cch; ++c) {
        int e = beg + c * 8 + esub;
        float ex = 0.f; int src = 0;
        if (e < end) {
            src = csr_src[e];
            float ev = alS[src * 8 + h] + aDh;
            ev = ev > 0.f ? ev : 0.2f * ev;
            ex = __expf(fminf(ev, 30.f));
        }
        srcc[c] = src; evc[c] = ex;
        s += ex;
    }
    for (int c = CH; c < nch; ++c) {      // overflow (deg>64)
        int e = beg + c * 8 + esub;
        if (e < end) {
            int src = csr_src[e];
            float ev = alS[src * 8 + h] + aDh;
            ev = ev > 0.f ? ev : 0.2f * ev;
            s += __expf(fminf(ev, 30.f));
        }
    }
    #pragma unroll
    for (int off = 8; off < 64; off <<= 1) s += __shfl_xor(s, off);

    const int g = lane & 31;              // channel group: channels g*8..g*8+7
    const int hh = g >> 2;                // head of this channel group
    const int p = lane >> 5;              // edge parity
    const float rs = __shfl(1.f / s, hh);
    __half2 hacc[4] = {};

    for (int c = 0; c < cch; ++c) {
        int base = beg + c * 8;
        int cnt = end - base; if (cnt > 8) cnt = 8;
        int steps = (cnt + 1) >> 1;
        for (int t = 0; t < steps; ++t) {
            int j = t * 2 + p;
            int jc = j < cnt ? j : (cnt - 1);
            int src = __shfl(srcc[c], jc * 8);
            float af = __shfl(evc[c], jc * 8 + hh) * rs;
            if (j >= cnt) af = 0.f;
            __half2 a2 = __float2half2_rn(af);
            const float4 raw = *(const float4*)(xh + ((size_t)src << 8) + g * 8);
            const __half2* hp = (const __half2*)&raw;
            hacc[0] = __hfma2(hp[0], a2, hacc[0]);
            hacc[1] = __hfma2(hp[1], a2, hacc[1]);
            hacc[2] = __hfma2(hp[2], a2, hacc[2]);
            hacc[3] = __hfma2(hp[3], a2, hacc[3]);
        }
    }
    for (int c = CH; c < nch; ++c) {      // overflow gather (recompute)
        int base = beg + c * 8;
        int e = base + esub;
        int src_l = 0; float ex_l = 0.f;
        if (e < end) {
            src_l = csr_src[e];
            float ev = alS[src_l * 8 + h] + aDh;
            ev = ev > 0.f ? ev : 0.2f * ev;
            ex_l = __expf(fminf(ev, 30.f));
        }
        int cnt = end - base; if (cnt > 8) cnt = 8;
        int steps = (cnt + 1) >> 1;
        for (int t = 0; t < steps; ++t) {
            int j = t * 2 + p;
            int jc = j < cnt ? j : (cnt - 1);
            int src = __shfl(src_l, jc * 8);
            float af = __shfl(ex_l, jc * 8 + hh) * rs;
            if (j >= cnt) af = 0.f;
            __half2 a2 = __float2half2_rn(af);
            const float4 raw = *(const float4*)(xh + ((size_t)src << 8) + g * 8);
            const __half2* hp = (const __half2*)&raw;
            hacc[0] = __hfma2(hp[0], a2, hacc[0]);
            hacc[1] = __hfma2(hp[1], a2, hacc[1]);
            hacc[2] = __hfma2(hp[2], a2, hacc[2]);
            hacc[3] = __hfma2(hp[3], a2, hacc[3]);
        }
    }

    // merge parity halves (lane ^ 32)
    #pragma unroll
    for (int k = 0; k < 4; ++k) {
        int vi = __shfl_xor(*(int*)&hacc[k], 32);
        hacc[k] = __hadd2(hacc[k], *(__half2*)&vi);
    }

    if (p == 0) {
        float2 f0 = __half22float2(hacc[0]);
        float2 f1 = __half22float2(hacc[1]);
        float2 f2 = __half22float2(hacc[2]);
        float2 f3 = __half22float2(hacc[3]);
        const float4 bv0 = *(const float4*)&bias[g * 8];
        const float4 bv1 = *(const float4*)&bias[g * 8 + 4];
        float o[8];
        o[0] = f0.x + bv0.x; o[1] = f0.y + bv0.y;
        o[2] = f1.x + bv0.z; o[3] = f1.y + bv0.w;
        o[4] = f2.x + bv1.x; o[5] = f2.y + bv1.y;
        o[6] = f3.x + bv1.z; o[7] = f3.y + bv1.w;
        if (do_elu) {
            #pragma unroll
            for (int k = 0; k < 8; ++k) o[k] = o[k] > 0.f ? o[k] : expm1f(o[k]);
        }
        float4 st;
        ((__half2*)&st)[0] = __floats2half2_rn(o[0], o[1]);
        ((__half2*)&st)[1] = __floats2half2_rn(o[2], o[3]);
        ((__half2*)&st)[2] = __floats2half2_rn(o[4], o[5]);
        ((__half2*)&st)[3] = __floats2half2_rn(o[6], o[7]);
        *(float4*)(out + ((size_t)d << 8) + g * 8) = st;
    }
}

// H=1, C=40. One wave per node; fp16 gather; fp32 accumulate (feeds output).
__global__ __launch_bounds__(256) void node_aggr1_k(
    const int* __restrict__ rowptr, const int* __restrict__ csr_src,
    const float* __restrict__ alS, const float* __restrict__ alD,
    const __half* __restrict__ xh2, const float* __restrict__ bias,
    float* __restrict__ out, int N) {
    int wid = (blockIdx.x * 256 + threadIdx.x) >> 6;
    int lane = threadIdx.x & 63;
    if (wid >= N) return;
    const int d = wid;
    const int beg = rowptr[d], end = rowptr[d + 1];
    const float aD = alD[d];

    int src0 = 0; float ex0 = 0.f;
    {
        int e = beg + lane;
        if (e < end) {
            src0 = csr_src[e];
            float ev = alS[src0] + aD;
            ev = ev > 0.f ? ev : 0.2f * ev;
            ex0 = __expf(fminf(ev, 30.f));
        }
    }
    float s = ex0;
    for (int e = beg + 64 + lane; e < end; e += 64) {
        int src = csr_src[e];
        float ev = alS[src] + aD;
        ev = ev > 0.f ? ev : 0.2f * ev;
        s += __expf(fminf(ev, 30.f));
    }
    #pragma unroll
    for (int off = 1; off < 64; off <<= 1) s += __shfl_xor(s, off);
    const float rs = 1.f / s;

    float acc = 0.f;
    {
        int cnt = end - beg; if (cnt > 64) cnt = 64;
        for (int j = 0; j < cnt; ++j) {
            int src = __shfl(src0, j);
            float alpha = __shfl(ex0, j) * rs;
            if (lane < 40) acc += __half2float(xh2[(size_t)src * 40 + lane]) * alpha;
        }
    }
    for (int eb = beg + 64; eb < end; eb += 64) {
        int e = eb + lane;
        int src_l = 0; float ex_l = 0.f;
        if (e < end) {
            src_l = csr_src[e];
            float ev = alS[src_l] + aD;
            ev = ev > 0.f ? ev : 0.2f * ev;
            ex_l = __expf(fminf(ev, 30.f));
        }
        int cnt = end - eb; if (cnt > 64) cnt = 64;
        for (int j = 0; j < cnt; ++j) {
            int src = __shfl(src_l, j);
            float alpha = __shfl(ex_l, j) * rs;
            if (lane < 40) acc += __half2float(xh2[(size_t)src * 40 + lane]) * alpha;
        }
    }
    if (lane < 40) out[(size_t)d * 40 + lane] = acc + bias[lane];
}

extern "C" void kernel_launch(void* const* d_in, const int* in_sizes, int n_in,
                              void* d_out, int out_size, void* d_ws, size_t ws_size,
                              hipStream_t stream) {
    const float* feat = (const float*)d_in[0];
    const int*   ei   = (const int*)d_in[1];
    const float* W0   = (const float*)d_in[2];
    const float* a0s  = (const float*)d_in[3];
    const float* a0d  = (const float*)d_in[4];
    const float* b0   = (const float*)d_in[5];
    const float* W1   = (const float*)d_in[6];
    const float* a1s  = (const float*)d_in[7];
    const float* a1d  = (const float*)d_in[8];
    const float* b1   = (const float*)d_in[9];
    const float* W2   = (const float*)d_in[10];
    const float* a2s  = (const float*)d_in[11];
    const float* a2d  = (const float*)d_in[12];
    const float* b2   = (const float*)d_in[13];
    float* out = (float*)d_out;

    const int N = in_sizes[0] / 128;   // 100000
    const int E = in_sizes[1] / 2;     // 1600000
    const int Etot = E + N;

    // workspace layout (~126 MB total)
    __half* hbuf = (__half*)d_ws;                     // N*256 fp16 (aggr out / gemm A)
    __half* xh   = hbuf + (size_t)N * 256;            // N*256 fp16 (gemm out, layers 0/1)
    __half* x2h  = xh + (size_t)N * 256;              // N*40 fp16 (layer-2 gemm out)
    float*  alS  = (float*)(x2h + (size_t)N * 40);    // N*8
    float*  alD  = alS + (size_t)N * 8;               // N*8
    int* deg      = (int*)(alD + (size_t)N * 8);      // N
    int* rowptr   = deg + N;                          // N+1
    int* cursor   = rowptr + N + 1;                   // N
    int* partials = cursor + N;                       // 512
    int* csr_src  = partials + 512;                   // Etot
    int* flag     = csr_src + Etot;                   // 1
    // pre-split transposed weights (16B aligned)
    uintptr_t wsp = ((uintptr_t)(flag + 1) + 15) & ~(uintptr_t)15;
    ushort_t* w0h = (ushort_t*)wsp;                   // 256*128
    ushort_t* w0l = w0h + 256 * 128;
    ushort_t* w1h = w0l + 256 * 128;                  // 256*256
    ushort_t* w1l = w1h + 256 * 256;
    ushort_t* w2h = w1l + 256 * 256;                  // 64*256
    ushort_t* w2l = w2h + 64 * 256;

    const int nbN    = (N + 255) / 256;
    const int nb_e   = (Etot + 255) / 256;
    const int nb_nw  = (N + 3) / 4;

    // ---- CSR build + weight pre-split (reused by all layers) ----
    detect64_k<<<1, 1, 0, stream>>>(ei, 512, flag);
    hipMemsetAsync(deg, 0, (size_t)N * 4, stream);
    deg_k<<<nb_e, 256, 0, stream>>>(ei, flag, deg, E, Etot, N);
    scan1_k<<<nbN, 256, 0, stream>>>(deg, rowptr, partials, N);
    scan2_k<<<1, 512, 0, stream>>>(partials, nbN);
    scan3_k<<<nbN, 256, 0, stream>>>(rowptr, cursor, partials, N, Etot);
    scatter_k<<<nb_e, 256, 0, stream>>>(ei, flag, cursor, csr_src, E, Etot, N);
    splitw_bf16_k<<<128, 256, 0, stream>>>(W0, w0h, w0l, 128, 256, 256);
    splitw_f16_k<<<256, 256, 0, stream>>>(W1, w1h, w1l, 256, 256, 256);
    splitw_f16_k<<<64, 256, 0, stream>>>(W2, w2h, w2l, 256, 40, 64);

    const int mb = (N + 127) / 128;

    // ---------- Layer 0: Fin=128, H=8, C=32 (fp32 A, 3-pass bf16, fused logits) ----------
    mfma_gemm_k<128, 2, 2, __half, 1><<<dim3(2, mb), 256, 0, stream>>>(
        feat, w0h, w0l, xh, N, 128, 256, a0s, a0d, alS, alD);
    node_aggr8_k<<<nb_nw, 256, 0, stream>>>(rowptr, csr_src, alS, alD, xh, b0,
                                            hbuf, N, 1);   // h1 -> hbuf fp16 (ELU fused)

    // ---------- Layer 1: Fin=256, H=8, C=32 (fp16 A, 2-pass f16, fused logits) ----------
    mfma_gemm_f16_k<128, 2, 2, __half, 1><<<dim3(2, mb), 256, 0, stream>>>(
        hbuf, w1h, w1l, xh, N, 256, 256, a1s, a1d, alS, alD);
    node_aggr8_k<<<nb_nw, 256, 0, stream>>>(rowptr, csr_src, alS, alD, xh, b1,
                                            hbuf, N, 1);   // h2 -> hbuf fp16 (ELU fused)

    // ---------- Layer 2: Fin=256, H=1, C=40 (fp16 A, fused logits, fp16 x2) ----------
    mfma_gemm_f16_k<64, 4, 1, __half, 2><<<dim3(1, mb), 256, 0, stream>>>(
        hbuf, w2h, w2l, x2h, N, 256, 40, a2s, a2d, alS, alD);
    node_aggr1_k<<<nb_nw, 256, 0, stream>>>(rowptr, csr_src, alS, alD, x2h, b2,
                                            out, N);       // bias fused, direct to out
}

// Round 11
// 879.309 us; speedup vs baseline: 7.6925x; 1.0110x over previous
//
#include <hip/hip_runtime.h>
#include <hip/hip_bf16.h>
#include <hip/hip_fp16.h>
#include <math.h>

typedef __attribute__((ext_vector_type(8))) short short8;
typedef __attribute__((ext_vector_type(8))) _Float16 half8;
typedef __attribute__((ext_vector_type(4))) float f32x4;
typedef unsigned short ushort_t;
struct __align__(8) us4 { ushort_t x, y, z, w; };

// round-to-nearest-even fp32 -> bf16
__device__ __forceinline__ ushort_t f2bf(float f) {
    unsigned u = __float_as_uint(f);
    u += 0x7FFFu + ((u >> 16) & 1u);
    return (ushort_t)(u >> 16);
}
__device__ __forceinline__ float bf2f(ushort_t h) {
    return __uint_as_float(((unsigned)h) << 16);
}

__device__ __forceinline__ void store_out(float* p, float v) { *p = v; }
__device__ __forceinline__ void store_out(__half* p, float v) { *p = __float2half(v); }

// ---- detect whether edge_index is int64 (odd int32 words all zero) ----
__global__ void detect64_k(const int* __restrict__ ei, int n_check, int* __restrict__ flag) {
    if (blockIdx.x == 0 && threadIdx.x == 0) {
        int zeros = 0;
        for (int i = 0; i < n_check; ++i) zeros += (ei[2 * i + 1] == 0) ? 1 : 0;
        *flag = (zeros >= n_check - 2) ? 1 : 0;
    }
}

__device__ __forceinline__ void edge_sd(const int* __restrict__ ei, int e, int E,
                                        int is64, int N, int& s_, int& d_) {
    if (e >= E) { s_ = d_ = e - E; return; }   // self-loops appended
    int s, d;
    if (is64) { s = ei[2 * e]; d = ei[2 * (E + e)]; }
    else      { s = ei[e];     d = ei[E + e]; }
    s_ = ((unsigned)s < (unsigned)N) ? s : 0;
    d_ = ((unsigned)d < (unsigned)N) ? d : 0;
}

// ================= CSR construction =================
__global__ void deg_k(const int* __restrict__ ei, const int* __restrict__ flag,
                      int* __restrict__ deg, int E, int Etot, int N) {
    int e = blockIdx.x * 256 + threadIdx.x;
    if (e >= Etot) return;
    int s_, d_;
    edge_sd(ei, e, E, *flag, N, s_, d_);
    atomicAdd(&deg[d_], 1);
}

__global__ void scan1_k(const int* __restrict__ deg, int* __restrict__ rowptr,
                        int* __restrict__ partials, int N) {
    __shared__ int tmp[256];
    int tx = threadIdx.x, i = blockIdx.x * 256 + tx;
    int v = (i < N) ? deg[i] : 0;
    tmp[tx] = v;
    __syncthreads();
    for (int off = 1; off < 256; off <<= 1) {
        int t = (tx >= off) ? tmp[tx - off] : 0;
        __syncthreads();
        tmp[tx] += t;
        __syncthreads();
    }
    if (i < N) rowptr[i] = tmp[tx] - v;
    if (tx == 255) partials[blockIdx.x] = tmp[255];
}

__global__ void scan2_k(int* __restrict__ partials, int nb) {
    __shared__ int tmp[512];
    int tx = threadIdx.x;
    int v = (tx < nb) ? partials[tx] : 0;
    tmp[tx] = v;
    __syncthreads();
    for (int off = 1; off < 512; off <<= 1) {
        int t = (tx >= off) ? tmp[tx - off] : 0;
        __syncthreads();
        tmp[tx] += t;
        __syncthreads();
    }
    if (tx < nb) partials[tx] = tmp[tx];
}

__global__ void scan3_k(int* __restrict__ rowptr, int* __restrict__ cursor,
                        const int* __restrict__ partials, int N, int Etot) {
    int i = blockIdx.x * 256 + threadIdx.x;
    if (i < N) {
        int off = (blockIdx.x > 0) ? partials[blockIdx.x - 1] : 0;
        int v = rowptr[i] + off;
        rowptr[i] = v;
        cursor[i] = v;
    }
    if (i == 0) rowptr[N] = Etot;
}

__global__ void scatter_k(const int* __restrict__ ei, const int* __restrict__ flag,
                          int* __restrict__ cursor, int* __restrict__ csr_src,
                          int E, int Etot, int N) {
    int e = blockIdx.x * 256 + threadIdx.x;
    if (e >= Etot) return;
    int s_, d_;
    edge_sd(ei, e, E, *flag, N, s_, d_);
    int pos = atomicAdd(&cursor[d_], 1);
    csr_src[pos] = s_;
}

// ===== weight pre-split (transposed [n][k], zero-padded to Mp rows) =====
__global__ void splitw_bf16_k(const float* __restrict__ W, ushort_t* __restrict__ Wh,
                              ushort_t* __restrict__ Wl, int K, int M, int Mp) {
    int i = blockIdx.x * 256 + threadIdx.x;
    if (i >= Mp * K) return;
    int n = i / K, k = i - n * K;
    float v = (n < M) ? W[(size_t)k * M + n] : 0.f;
    ushort_t h = f2bf(v);
    Wh[i] = h;
    Wl[i] = f2bf(v - bf2f(h));
}

__global__ void splitw_f16_k(const float* __restrict__ W, ushort_t* __restrict__ Wh,
                             ushort_t* __restrict__ Wl, int K, int M, int Mp) {
    int i = blockIdx.x * 256 + threadIdx.x;
    if (i >= Mp * K) return;
    int n = i / K, k = i - n * K;
    float v = (n < M) ? W[(size_t)k * M + n] : 0.f;
    __half h = __float2half(v);
    Wh[i] = __half_as_ushort(h);
    Wl[i] = __half_as_ushort(__float2half(v - __half2float(h)));
}

// ================= split-bf16 MFMA GEMM (fp32 A; layer 0) =================
// B pre-split/transposed: BhT/BlT [Mp][K] bf16 bits.
template <int BN, int WMCNT, int WNCNT, typename TOUT, int LMODE>
__global__ __launch_bounds__(256) void mfma_gemm_k(const float* __restrict__ A,
                                                   const ushort_t* __restrict__ BhT,
                                                   const ushort_t* __restrict__ BlT,
                                                   TOUT* __restrict__ C,
                                                   int N, int K, int M,
                                                   const float* __restrict__ a_s,
                                                   const float* __restrict__ a_d,
                                                   float* __restrict__ alS,
                                                   float* __restrict__ alD) {
    constexpr int BM = 128;
    constexpr int PAD = 40;
    constexpr int WMX = BM / WMCNT;
    constexpr int WNX = BN / WNCNT;
    constexpr int FM = WMX / 16, FN = WNX / 16;
    static_assert(FN == 4, "logit epilogue assumes WNX==64");

    __shared__ ushort_t Ah[BM * PAD], Al[BM * PAD];
    __shared__ ushort_t Bh[BN * PAD], Bl[BN * PAD];

    const int tx = threadIdx.x;
    const int wave = tx >> 6, lane = tx & 63;
    const int quad = lane >> 4, l16 = lane & 15;
    const int br = blockIdx.y * BM, bc = blockIdx.x * BN;
    const int wm = (wave / WNCNT) * WMX;
    const int wn = (wave % WNCNT) * WNX;

    f32x4 acc[FM][FN] = {};

    for (int k0 = 0; k0 < K; k0 += 32) {
        #pragma unroll
        for (int r = 0; r < 4; ++r) {
            int i = r * 256 + tx;
            int m = i >> 3, k4 = (i & 7) * 4;
            int gr = br + m;
            float4 v = make_float4(0.f, 0.f, 0.f, 0.f);
            if (gr < N) v = *(const float4*)&A[(size_t)gr * K + k0 + k4];
            us4 h, l;
            h.x = f2bf(v.x); l.x = f2bf(v.x - bf2f(h.x));
            h.y = f2bf(v.y); l.y = f2bf(v.y - bf2f(h.y));
            h.z = f2bf(v.z); l.z = f2bf(v.z - bf2f(h.z));
            h.w = f2bf(v.w); l.w = f2bf(v.w - bf2f(h.w));
            *(us4*)&Ah[m * PAD + k4] = h;
            *(us4*)&Al[m * PAD + k4] = l;
        }
        // B staging: pure 16B copies from pre-split transposed weights
        #pragma unroll
        for (int r = 0; r < BN / 64; ++r) {
            int i = r * 256 + tx;
            int n = i >> 2, k8 = (i & 3) * 8;
            *(short8*)&Bh[n * PAD + k8] = *(const short8*)&BhT[(size_t)(bc + n) * K + k0 + k8];
            *(short8*)&Bl[n * PAD + k8] = *(const short8*)&BlT[(size_t)(bc + n) * K + k0 + k8];
        }
        __syncthreads();

        short8 afh[FM], afl[FM];
        #pragma unroll
        for (int mi = 0; mi < FM; ++mi) {
            int row = wm + mi * 16 + l16;
            afh[mi] = *(const short8*)&Ah[row * PAD + quad * 8];
            afl[mi] = *(const short8*)&Al[row * PAD + quad * 8];
        }
        #pragma unroll
        for (int ni = 0; ni < FN; ++ni) {
            int row = wn + ni * 16 + l16;
            short8 bfh = *(const short8*)&Bh[row * PAD + quad * 8];
            short8 bfl = *(const short8*)&Bl[row * PAD + quad * 8];
            #pragma unroll
            for (int mi = 0; mi < FM; ++mi) {
                acc[mi][ni] = __builtin_amdgcn_mfma_f32_16x16x32_bf16(afh[mi], bfh, acc[mi][ni], 0, 0, 0);
                acc[mi][ni] = __builtin_amdgcn_mfma_f32_16x16x32_bf16(afh[mi], bfl, acc[mi][ni], 0, 0, 0);
                acc[mi][ni] = __builtin_amdgcn_mfma_f32_16x16x32_bf16(afl[mi], bfh, acc[mi][ni], 0, 0, 0);
            }
        }
        __syncthreads();
    }

    #pragma unroll
    for (int mi = 0; mi < FM; ++mi) {
        #pragma unroll
        for (int ni = 0; ni < FN; ++ni) {
            int gc = bc + wn + ni * 16 + l16;
            if (gc >= M) continue;
            #pragma unroll
            for (int r = 0; r < 4; ++r) {
                int gr = br + wm + mi * 16 + quad * 4 + r;
                if (gr < N) store_out(&C[(size_t)gr * M + gc], acc[mi][ni][r]);
            }
        }
    }

    // ---- fused logits ----
    float aSv[FN], aDv[FN];
    #pragma unroll
    for (int ni = 0; ni < FN; ++ni) {
        int gc = bc + wn + ni * 16 + l16;
        bool ok = gc < M;
        aSv[ni] = ok ? a_s[gc] : 0.f;
        aDv[ni] = ok ? a_d[gc] : 0.f;
    }
    if (LMODE == 1) {
        #pragma unroll
        for (int mi = 0; mi < FM; ++mi) {
            #pragma unroll
            for (int r = 0; r < 4; ++r) {
                float p1a = acc[mi][0][r] * aSv[0] + acc[mi][1][r] * aSv[1];
                float p1b = acc[mi][2][r] * aSv[2] + acc[mi][3][r] * aSv[3];
                float p2a = acc[mi][0][r] * aDv[0] + acc[mi][1][r] * aDv[1];
                float p2b = acc[mi][2][r] * aDv[2] + acc[mi][3][r] * aDv[3];
                #pragma unroll
                for (int off = 1; off < 16; off <<= 1) {
                    p1a += __shfl_xor(p1a, off);
                    p1b += __shfl_xor(p1b, off);
                    p2a += __shfl_xor(p2a, off);
                    p2b += __shfl_xor(p2b, off);
                }
                if (l16 == 0) {
                    int gr = br + wm + mi * 16 + quad * 4 + r;
                    if (gr < N) {
                        int hb = (bc + wn) >> 5;
                        alS[gr * 8 + hb]     = p1a;
                        alS[gr * 8 + hb + 1] = p1b;
                        alD[gr * 8 + hb]     = p2a;
                        alD[gr * 8 + hb + 1] = p2b;
                    }
                }
            }
        }
    } else {
        #pragma unroll
        for (int mi = 0; mi < FM; ++mi) {
            #pragma unroll
            for (int r = 0; r < 4; ++r) {
                float p1 = acc[mi][0][r] * aSv[0] + acc[mi][1][r] * aSv[1]
                         + acc[mi][2][r] * aSv[2] + acc[mi][3][r] * aSv[3];
                float p2 = acc[mi][0][r] * aDv[0] + acc[mi][1][r] * aDv[1]
                         + acc[mi][2][r] * aDv[2] + acc[mi][3][r] * aDv[3];
                #pragma unroll
                for (int off = 1; off < 16; off <<= 1) {
                    p1 += __shfl_xor(p1, off);
                    p2 += __shfl_xor(p2, off);
                }
                if (l16 == 0) {
                    int gr = br + wm + mi * 16 + quad * 4 + r;
                    if (gr < N) { alS[gr] = p1; alD[gr] = p2; }
                }
            }
        }
    }
}

// ======== fp16-A 2-pass MFMA GEMM (layers 1/2): A fp16, B pre-split fp16 hi/lo ========
template <int BN, int WMCNT, int WNCNT, typename TOUT, int LMODE>
__global__ __launch_bounds__(256) void mfma_gemm_f16_k(const __half* __restrict__ A,
                                                       const ushort_t* __restrict__ BhT,
                                                       const ushort_t* __restrict__ BlT,
                                                       TOUT* __restrict__ C,
                                                       int N, int K, int M,
                                                       const float* __restrict__ a_s,
                                                       const float* __restrict__ a_d,
                                                       float* __restrict__ alS,
                                                       float* __restrict__ alD) {
    constexpr int BM = 128;
    constexpr int PAD = 40;
    constexpr int WMX = BM / WMCNT;
    constexpr int WNX = BN / WNCNT;
    constexpr int FM = WMX / 16, FN = WNX / 16;
    static_assert(FN == 4, "logit epilogue assumes WNX==64");

    __shared__ ushort_t Ah[BM * PAD];
    __shared__ ushort_t Bh[BN * PAD], Bl[BN * PAD];

    const int tx = threadIdx.x;
    const int wave = tx >> 6, lane = tx & 63;
    const int quad = lane >> 4, l16 = lane & 15;
    const int br = blockIdx.y * BM, bc = blockIdx.x * BN;
    const int wm = (wave / WNCNT) * WMX;
    const int wn = (wave % WNCNT) * WNX;

    f32x4 acc[FM][FN] = {};

    for (int k0 = 0; k0 < K; k0 += 32) {
        #pragma unroll
        for (int r = 0; r < 2; ++r) {
            int i = r * 256 + tx;
            int m = i >> 2, k8 = (i & 3) * 8;
            int gr = br + m;
            short8 v = {};
            if (gr < N) v = *(const short8*)&A[(size_t)gr * K + k0 + k8];
            *(short8*)&Ah[m * PAD + k8] = v;
        }
        #pragma unroll
        for (int r = 0; r < BN / 64; ++r) {
            int i = r * 256 + tx;
            int n = i >> 2, k8 = (i & 3) * 8;
            *(short8*)&Bh[n * PAD + k8] = *(const short8*)&BhT[(size_t)(bc + n) * K + k0 + k8];
            *(short8*)&Bl[n * PAD + k8] = *(const short8*)&BlT[(size_t)(bc + n) * K + k0 + k8];
        }
        __syncthreads();

        half8 af[FM];
        #pragma unroll
        for (int mi = 0; mi < FM; ++mi) {
            int row = wm + mi * 16 + l16;
            af[mi] = *(const half8*)&Ah[row * PAD + quad * 8];
        }
        #pragma unroll
        for (int ni = 0; ni < FN; ++ni) {
            int row = wn + ni * 16 + l16;
            half8 bfh = *(const half8*)&Bh[row * PAD + quad * 8];
            half8 bfl = *(const half8*)&Bl[row * PAD + quad * 8];
            #pragma unroll
            for (int mi = 0; mi < FM; ++mi) {
                acc[mi][ni] = __builtin_amdgcn_mfma_f32_16x16x32_f16(af[mi], bfh, acc[mi][ni], 0, 0, 0);
                acc[mi][ni] = __builtin_amdgcn_mfma_f32_16x16x32_f16(af[mi], bfl, acc[mi][ni], 0, 0, 0);
            }
        }
        __syncthreads();
    }

    #pragma unroll
    for (int mi = 0; mi < FM; ++mi) {
        #pragma unroll
        for (int ni = 0; ni < FN; ++ni) {
            int gc = bc + wn + ni * 16 + l16;
            if (gc >= M) continue;
            #pragma unroll
            for (int r = 0; r < 4; ++r) {
                int gr = br + wm + mi * 16 + quad * 4 + r;
                if (gr < N) store_out(&C[(size_t)gr * M + gc], acc[mi][ni][r]);
            }
        }
    }

    // ---- fused logits ----
    float aSv[FN], aDv[FN];
    #pragma unroll
    for (int ni = 0; ni < FN; ++ni) {
        int gc = bc + wn + ni * 16 + l16;
        bool ok = gc < M;
        aSv[ni] = ok ? a_s[gc] : 0.f;
        aDv[ni] = ok ? a_d[gc] : 0.f;
    }
    if (LMODE == 1) {
        #pragma unroll
        for (int mi = 0; mi < FM; ++mi) {
            #pragma unroll
            for (int r = 0; r < 4; ++r) {
                float p1a = acc[mi][0][r] * aSv[0] + acc[mi][1][r] * aSv[1];
                float p1b = acc[mi][2][r] * aSv[2] + acc[mi][3][r] * aSv[3];
                float p2a = acc[mi][0][r] * aDv[0] + acc[mi][1][r] * aDv[1];
                float p2b = acc[mi][2][r] * aDv[2] + acc[mi][3][r] * aDv[3];
                #pragma unroll
                for (int off = 1; off < 16; off <<= 1) {
                    p1a += __shfl_xor(p1a, off);
                    p1b += __shfl_xor(p1b, off);
                    p2a += __shfl_xor(p2a, off);
                    p2b += __shfl_xor(p2b, off);
                }
                if (l16 == 0) {
                    int gr = br + wm + mi * 16 + quad * 4 + r;
                    if (gr < N) {
                        int hb = (bc + wn) >> 5;
                        alS[gr * 8 + hb]     = p1a;
                        alS[gr * 8 + hb + 1] = p1b;
                        alD[gr * 8 + hb]     = p2a;
                        alD[gr * 8 + hb + 1] = p2b;
                    }
                }
            }
        }
    } else {
        #pragma unroll
        for (int mi = 0; mi < FM; ++mi) {
            #pragma unroll
            for (int r = 0; r < 4; ++r) {
                float p1 = acc[mi][0][r] * aSv[0] + acc[mi][1][r] * aSv[1]
                         + acc[mi][2][r] * aSv[2] + acc[mi][3][r] * aSv[3];
                float p2 = acc[mi][0][r] * aDv[0] + acc[mi][1][r] * aDv[1]
                         + acc[mi][2][r] * aDv[2] + acc[mi][3][r] * aDv[3];
                #pragma unroll
                for (int off = 1; off < 16; off <<= 1) {
                    p1 += __shfl_xor(p1, off);
                    p2 += __shfl_xor(p2, off);
                }
                if (l16 == 0) {
                    int gr = br + wm + mi * 16 + quad * 4 + r;
                    if (gr < N) { alS[gr] = p1; alD[gr] = p2; }
                }
            }
        }
    }
}

// ================= fused per-node softmax + aggregation =================
// H=8, C=32. One wave per node. Sweep 1 writes (src, exp[8]) to LDS; sweep 2
// is a flat pair-step loop with an explicit 4-deep software pipeline of the
// 16 B gather loads (clamped duplicate issues beyond T are alpha-masked and
// hit L1). This targets memory-latency pacing, not VALU (R9/R10 evidence).
__global__ __launch_bounds__(256) void node_aggr8_k(
    const int* __restrict__ rowptr, const int* __restrict__ csr_src,
    const float* __restrict__ alS, const float* __restrict__ alD,
    const __half* __restrict__ xh, const float* __restrict__ bias,
    __half* __restrict__ out, int N, int do_elu) {
    __shared__ int   lsrc[4][64];
    __shared__ float lexp[4][64 * 8];
    const int wv = threadIdx.x >> 6;
    int wid = (blockIdx.x * 256 + threadIdx.x) >> 6;
    int lane = threadIdx.x & 63;
    if (wid >= N) return;
    const int d = wid;
    const int beg = rowptr[d], end = rowptr[d + 1];
    const int deg = end - beg;
    const int dcap = deg < 64 ? deg : 64;

    const int h = lane & 7, esub = lane >> 3;
    const float aDh = alD[d * 8 + h];

    const int nch = (deg + 7) >> 3;
    const int cch = nch < 8 ? nch : 8;

    // sweep 1: exp sums + LDS cache of (src, exp per head)
    float s = 0.f;
    for (int c = 0; c < cch; ++c) {
        int sl = c * 8 + esub;
        int e = beg + sl;
        if (e < end) {
            int src = csr_src[e];
            float ev = alS[src * 8 + h] + aDh;
            ev = ev > 0.f ? ev : 0.2f * ev;
            float ex = __expf(fminf(ev, 30.f));
            if (h == 0) lsrc[wv][sl] = src;
            lexp[wv][sl * 8 + h] = ex;
            s += ex;
        }
    }
    for (int c = 8; c < nch; ++c) {      // overflow (deg>64): sum only
        int e = beg + c * 8 + esub;
        if (e < end) {
            int src = csr_src[e];
            float ev = alS[src * 8 + h] + aDh;
            ev = ev > 0.f ? ev : 0.2f * ev;
            s += __expf(fminf(ev, 30.f));
        }
    }
    #pragma unroll
    for (int off = 8; off < 64; off <<= 1) s += __shfl_xor(s, off);

    const int g = lane & 31;              // channel group: channels g*8..g*8+7
    const int hh = g >> 2;                // head of this channel group
    const int p = lane >> 5;              // edge parity
    const float rs = __shfl(1.f / s, hh);

    const int T = (dcap + 1) >> 1;        // pair-steps over cached edges
    float alq[4];
    float4 rq[4];
    __half2 hacc[4] = {};

    // prologue: issue stages 0..3
    #pragma unroll
    for (int i = 0; i < 4; ++i) {
        int e0 = 2 * i + p;
        int idx = e0 < dcap ? e0 : dcap - 1;
        int src = lsrc[wv][idx];
        float al = lexp[wv][idx * 8 + hh] * rs;
        alq[i] = (e0 < dcap) ? al : 0.f;
        rq[i] = *(const float4*)(xh + ((size_t)src << 8) + g * 8);
    }

    #define PROC(i)                                                       \
    {                                                                     \
        float4 raw = rq[i];                                               \
        __half2 a2 = __float2half2_rn(alq[i]);                            \
        int tn = t + 4 + (i);                                             \
        int e0 = 2 * tn + p;                                              \
        int idx = e0 < dcap ? e0 : dcap - 1;                              \
        int srcn = lsrc[wv][idx];                                         \
        float aln = lexp[wv][idx * 8 + hh] * rs;                          \
        alq[i] = (e0 < dcap) ? aln : 0.f;                                 \
        rq[i] = *(const float4*)(xh + ((size_t)srcn << 8) + g * 8);       \
        const __half2* hp = (const __half2*)&raw;                         \
        hacc[0] = __hfma2(hp[0], a2, hacc[0]);                            \
        hacc[1] = __hfma2(hp[1], a2, hacc[1]);                            \
        hacc[2] = __hfma2(hp[2], a2, hacc[2]);                            \
        hacc[3] = __hfma2(hp[3], a2, hacc[3]);                            \
    }
    for (int t = 0; t < T; t += 4) { PROC(0) PROC(1) PROC(2) PROC(3) }
    #undef PROC

    // overflow gather (deg>64): recompute path, 2 edges/step via shuffles
    for (int c = 8; c < nch; ++c) {
        int base = beg + c * 8;
        int e = base + esub;
        int src_l = 0; float ex_l = 0.f;
        if (e < end) {
            src_l = csr_src[e];
            float ev = alS[src_l * 8 + h] + aDh;
            ev = ev > 0.f ? ev : 0.2f * ev;
            ex_l = __expf(fminf(ev, 30.f));
        }
        int cnt = end - base; if (cnt > 8) cnt = 8;
        int steps = (cnt + 1) >> 1;
        for (int t2 = 0; t2 < steps; ++t2) {
            int j = t2 * 2 + p;
            int jc = j < cnt ? j : (cnt - 1);
            int src = __shfl(src_l, jc * 8);
            float af = __shfl(ex_l, jc * 8 + hh) * rs;
            if (j >= cnt) af = 0.f;
            __half2 a2 = __float2half2_rn(af);
            const float4 raw = *(const float4*)(xh + ((size_t)src << 8) + g * 8);
            const __half2* hp = (const __half2*)&raw;
            hacc[0] = __hfma2(hp[0], a2, hacc[0]);
            hacc[1] = __hfma2(hp[1], a2, hacc[1]);
            hacc[2] = __hfma2(hp[2], a2, hacc[2]);
            hacc[3] = __hfma2(hp[3], a2, hacc[3]);
        }
    }

    // merge parity halves (lane ^ 32)
    #pragma unroll
    for (int k = 0; k < 4; ++k) {
        int vi = __shfl_xor(*(int*)&hacc[k], 32);
        hacc[k] = __hadd2(hacc[k], *(__half2*)&vi);
    }

    if (p == 0) {
        float2 f0 = __half22float2(hacc[0]);
        float2 f1 = __half22float2(hacc[1]);
        float2 f2 = __half22float2(hacc[2]);
        float2 f3 = __half22float2(hacc[3]);
        const float4 bv0 = *(const float4*)&bias[g * 8];
        const float4 bv1 = *(const float4*)&bias[g * 8 + 4];
        float o[8];
        o[0] = f0.x + bv0.x; o[1] = f0.y + bv0.y;
        o[2] = f1.x + bv0.z; o[3] = f1.y + bv0.w;
        o[4] = f2.x + bv1.x; o[5] = f2.y + bv1.y;
        o[6] = f3.x + bv1.z; o[7] = f3.y + bv1.w;
        if (do_elu) {
            #pragma unroll
            for (int k = 0; k < 8; ++k) o[k] = o[k] > 0.f ? o[k] : (__expf(o[k]) - 1.f);
        }
        float4 st;
        ((__half2*)&st)[0] = __floats2half2_rn(o[0], o[1]);
        ((__half2*)&st)[1] = __floats2half2_rn(o[2], o[3]);
        ((__half2*)&st)[2] = __floats2half2_rn(o[4], o[5]);
        ((__half2*)&st)[3] = __floats2half2_rn(o[6], o[7]);
        *(float4*)(out + ((size_t)d << 8) + g * 8) = st;
    }
}

// H=1, C=40. One wave per node; fp16 gather; fp32 accumulate (feeds output).
__global__ __launch_bounds__(256) void node_aggr1_k(
    const int* __restrict__ rowptr, const int* __restrict__ csr_src,
    const float* __restrict__ alS, const float* __restrict__ alD,
    const __half* __restrict__ xh2, const float* __restrict__ bias,
    float* __restrict__ out, int N) {
    int wid = (blockIdx.x * 256 + threadIdx.x) >> 6;
    int lane = threadIdx.x & 63;
    if (wid >= N) return;
    const int d = wid;
    const int beg = rowptr[d], end = rowptr[d + 1];
    const float aD = alD[d];

    int src0 = 0; float ex0 = 0.f;
    {
        int e = beg + lane;
        if (e < end) {
            src0 = csr_src[e];
            float ev = alS[src0] + aD;
            ev = ev > 0.f ? ev : 0.2f * ev;
            ex0 = __expf(fminf(ev, 30.f));
        }
    }
    float s = ex0;
    for (int e = beg + 64 + lane; e < end; e += 64) {
        int src = csr_src[e];
        float ev = alS[src] + aD;
        ev = ev > 0.f ? ev : 0.2f * ev;
        s += __expf(fminf(ev, 30.f));
    }
    #pragma unroll
    for (int off = 1; off < 64; off <<= 1) s += __shfl_xor(s, off);
    const float rs = 1.f / s;

    float acc = 0.f;
    {
        int cnt = end - beg; if (cnt > 64) cnt = 64;
        for (int j = 0; j < cnt; ++j) {
            int src = __shfl(src0, j);
            float alpha = __shfl(ex0, j) * rs;
            if (lane < 40) acc += __half2float(xh2[(size_t)src * 40 + lane]) * alpha;
        }
    }
    for (int eb = beg + 64; eb < end; eb += 64) {
        int e = eb + lane;
        int src_l = 0; float ex_l = 0.f;
        if (e < end) {
            src_l = csr_src[e];
            float ev = alS[src_l] + aD;
            ev = ev > 0.f ? ev : 0.2f * ev;
            ex_l = __expf(fminf(ev, 30.f));
        }
        int cnt = end - eb; if (cnt > 64) cnt = 64;
        for (int j = 0; j < cnt; ++j) {
            int src = __shfl(src_l, j);
            float alpha = __shfl(ex_l, j) * rs;
            if (lane < 40) acc += __half2float(xh2[(size_t)src * 40 + lane]) * alpha;
        }
    }
    if (lane < 40) out[(size_t)d * 40 + lane] = acc + bias[lane];
}

extern "C" void kernel_launch(void* const* d_in, const int* in_sizes, int n_in,
                              void* d_out, int out_size, void* d_ws, size_t ws_size,
                              hipStream_t stream) {
    const float* feat = (const float*)d_in[0];
    const int*   ei   = (const int*)d_in[1];
    const float* W0   = (const float*)d_in[2];
    const float* a0s  = (const float*)d_in[3];
    const float* a0d  = (const float*)d_in[4];
    const float* b0   = (const float*)d_in[5];
    const float* W1   = (const float*)d_in[6];
    const float* a1s  = (const float*)d_in[7];
    const float* a1d  = (const float*)d_in[8];
    const float* b1   = (const float*)d_in[9];
    const float* W2   = (const float*)d_in[10];
    const float* a2s  = (const float*)d_in[11];
    const float* a2d  = (const float*)d_in[12];
    const float* b2   = (const float*)d_in[13];
    float* out = (float*)d_out;

    const int N = in_sizes[0] / 128;   // 100000
    const int E = in_sizes[1] / 2;     // 1600000
    const int Etot = E + N;

    // workspace layout (~126 MB total)
    __half* hbuf = (__half*)d_ws;                     // N*256 fp16 (aggr out / gemm A)
    __half* xh   = hbuf + (size_t)N * 256;            // N*256 fp16 (gemm out, layers 0/1)
    __half* x2h  = xh + (size_t)N * 256;              // N*40 fp16 (layer-2 gemm out)
    float*  alS  = (float*)(x2h + (size_t)N * 40);    // N*8
    float*  alD  = alS + (size_t)N * 8;               // N*8
    int* deg      = (int*)(alD + (size_t)N * 8);      // N
    int* rowptr   = deg + N;                          // N+1
    int* cursor   = rowptr + N + 1;                   // N
    int* partials = cursor + N;                       // 512
    int* csr_src  = partials + 512;                   // Etot
    int* flag     = csr_src + Etot;                   // 1
    // pre-split transposed weights (16B aligned)
    uintptr_t wsp = ((uintptr_t)(flag + 1) + 15) & ~(uintptr_t)15;
    ushort_t* w0h = (ushort_t*)wsp;                   // 256*128
    ushort_t* w0l = w0h + 256 * 128;
    ushort_t* w1h = w0l + 256 * 128;                  // 256*256
    ushort_t* w1l = w1h + 256 * 256;
    ushort_t* w2h = w1l + 256 * 256;                  // 64*256
    ushort_t* w2l = w2h + 64 * 256;

    const int nbN    = (N + 255) / 256;
    const int nb_e   = (Etot + 255) / 256;
    const int nb_nw  = (N + 3) / 4;

    // ---- CSR build + weight pre-split (reused by all layers) ----
    detect64_k<<<1, 1, 0, stream>>>(ei, 512, flag);
    hipMemsetAsync(deg, 0, (size_t)N * 4, stream);
    deg_k<<<nb_e, 256, 0, stream>>>(ei, flag, deg, E, Etot, N);
    scan1_k<<<nbN, 256, 0, stream>>>(deg, rowptr, partials, N);
    scan2_k<<<1, 512, 0, stream>>>(partials, nbN);
    scan3_k<<<nbN, 256, 0, stream>>>(rowptr, cursor, partials, N, Etot);
    scatter_k<<<nb_e, 256, 0, stream>>>(ei, flag, cursor, csr_src, E, Etot, N);
    splitw_bf16_k<<<128, 256, 0, stream>>>(W0, w0h, w0l, 128, 256, 256);
    splitw_f16_k<<<256, 256, 0, stream>>>(W1, w1h, w1l, 256, 256, 256);
    splitw_f16_k<<<64, 256, 0, stream>>>(W2, w2h, w2l, 256, 40, 64);

    const int mb = (N + 127) / 128;

    // ---------- Layer 0: Fin=128, H=8, C=32 (fp32 A, 3-pass bf16, fused logits) ----------
    mfma_gemm_k<128, 2, 2, __half, 1><<<dim3(2, mb), 256, 0, stream>>>(
        feat, w0h, w0l, xh, N, 128, 256, a0s, a0d, alS, alD);
    node_aggr8_k<<<nb_nw, 256, 0, stream>>>(rowptr, csr_src, alS, alD, xh, b0,
                                            hbuf, N, 1);   // h1 -> hbuf fp16 (ELU fused)

    // ---------- Layer 1: Fin=256, H=8, C=32 (fp16 A, 2-pass f16, fused logits) ----------
    mfma_gemm_f16_k<128, 2, 2, __half, 1><<<dim3(2, mb), 256, 0, stream>>>(
        hbuf, w1h, w1l, xh, N, 256, 256, a1s, a1d, alS, alD);
    node_aggr8_k<<<nb_nw, 256, 0, stream>>>(rowptr, csr_src, alS, alD, xh, b1,
                                            hbuf, N, 1);   // h2 -> hbuf fp16 (ELU fused)

    // ---------- Layer 2: Fin=256, H=1, C=40 (fp16 A, fused logits, fp16 x2) ----------
    mfma_gemm_f16_k<64, 4, 1, __half, 2><<<dim3(1, mb), 256, 0, stream>>>(
        hbuf, w2h, w2l, x2h, N, 256, 40, a2s, a2d, alS, alD);
    node_aggr1_k<<<nb_nw, 256, 0, stream>>>(rowptr, csr_src, alS, alD, x2h, b2,
                                            out, N);       // bias fused, direct to out
}